// Round 3
// baseline (353.621 us; speedup 1.0000x reference)
//
#include <hip/hip_runtime.h>
#include <math.h>

#define N_NODES 1000
#define T_STEPS 32
#define H_DIM   128
#define E_EDGES 16000
#define ED_DIM  16
#define G_GRAPHS 32
#define EP_EDGES (E_EDGES + N_NODES)
#define NEG_SLOPE 0.2f
#define LN_EPS 1e-5f
#define XT_STRIDE 36   // 34 used cols padded to 36 -> row byte stride 144 = 9*16 (b128-aligned)

// ---------- prep: transpose conv_w [O][I][K] -> wt[k][i][o] (coalesced per-o reads) ----------
__global__ void k_prep_w(const float* __restrict__ conv_w, float* __restrict__ wt) {
    int i = blockIdx.x * 256 + threadIdx.x;
    if (i >= 128 * 128 * 3) return;
    int k = i % 3;
    int hi = (i / 3) % 128;
    int o = i / (3 * 128);
    wt[(k * 128 + hi) * 128 + o] = conv_w[i];
}

// ---------- CSR by dst: counts (int atomics, deterministic) ----------
__global__ void k_count(const int* __restrict__ dst, int* __restrict__ cnt) {
    int e = blockIdx.x * 256 + threadIdx.x;
    if (e < E_EDGES) atomicAdd(&cnt[dst[e]], 1);
}

// ---------- exclusive scan over N=1000 counts (single block) ----------
__global__ void k_scan(const int* __restrict__ cnt, int* __restrict__ offs) {
    __shared__ int sm[1024];
    int t = threadIdx.x;
    sm[t] = (t < N_NODES) ? cnt[t] : 0;
    for (int s = 1; s < 1024; s <<= 1) {
        __syncthreads();
        int a = (t >= s) ? sm[t - s] : 0;
        __syncthreads();
        sm[t] += a;
    }
    __syncthreads();
    if (t < N_NODES) offs[t + 1] = sm[t];
    if (t == 0) offs[0] = 0;
}

// ---------- ordered CSR fill: one wave per node scans dst, ballot-ranked (deterministic) ----------
__global__ void k_fill(const int* __restrict__ dst, const int* __restrict__ offs,
                       int* __restrict__ csr) {
    int n = blockIdx.x;
    int lane = threadIdx.x;  // 64
    int pos = offs[n];
    for (int b = 0; b < E_EDGES; b += 64) {
        int e = b + lane;
        bool m = (e < E_EDGES) && (dst[e] == n);
        unsigned long long mask = __ballot(m);
        if (m) {
            int rank = __popcll(mask & ((1ULL << lane) - 1ULL));
            csr[pos + rank] = e;
        }
        pos += __popcll(mask);
    }
}

// ---------- loop_attr[n] = mean of incoming edge_attr ----------
__global__ void k_loopattr(const float* __restrict__ edge_attr, const int* __restrict__ csr,
                           const int* __restrict__ offs, const int* __restrict__ cnt,
                           float* __restrict__ loop_attr) {
    int n = blockIdx.x;
    int lane = threadIdx.x;           // 64
    int q = lane >> 4, f = lane & 15; // 4-way edge parallel over 16 channels
    int off = offs[n], deg = cnt[n];
    float a = 0.f;
    for (int i = q; i < deg; i += 4) a += edge_attr[csr[off + i] * ED_DIM + f];
    a += __shfl_xor(a, 16);
    a += __shfl_xor(a, 32);
    if (lane < 16) loop_attr[n * ED_DIM + lane] = a / fmaxf((float)deg, 1.0f);
}

// ---------- ee[e][h] = ea[e] @ We, for all E+N edges ----------
__global__ void k_ee(const float* __restrict__ edge_attr, const float* __restrict__ loop_attr,
                     const float* __restrict__ We, float* __restrict__ ee) {
    int e = blockIdx.x * 2 + (threadIdx.x >> 7);
    int h = threadIdx.x & 127;
    if (e >= EP_EDGES) return;
    const float* ea = (e < E_EDGES) ? &edge_attr[e * ED_DIM]
                                    : &loop_attr[(e - E_EDGES) * ED_DIM];
    float acc = 0.f;
#pragma unroll
    for (int f = 0; f < ED_DIM; ++f) acc += ea[f] * We[f * H_DIM + h];
    ee[e * H_DIM + h] = acc;
}

// ---------- fused: conv1d + residual + LN1 + gl/gr GEMMs; transposed-halo LDS, one buffer ----------
__global__ __launch_bounds__(256) void k_temporal(
    const float* __restrict__ x, const float* __restrict__ wt, const float* __restrict__ conv_b,
    const float* __restrict__ ln1_g, const float* __restrict__ ln1_b,
    const float* __restrict__ Wl, const float* __restrict__ Wr,
    float* __restrict__ x1, float* __restrict__ gl, float* __restrict__ gr) {
    __shared__ float xt[H_DIM][XT_STRIDE];  // 18432 B; xt[h][tt] = x[tt-1][h], halo cols 0,33 = 0
    int n = blockIdx.x;
    int tid = threadIdx.x;
    int o = tid & 127, th = tid >> 7;  // thread owns out-channel o, t-range [th*16, th*16+16)

    // phase 1: load x[n] (float4, coalesced) -> transposed LDS with halo
    const float4* xv4 = (const float4*)(x + n * T_STEPS * H_DIM);
    for (int i4 = tid; i4 < T_STEPS * H_DIM / 4; i4 += 256) {
        float4 v = xv4[i4];
        int t = (i4 * 4) >> 7, h = (i4 * 4) & 127;
        xt[h][t + 1] = v.x; xt[h + 1][t + 1] = v.y;
        xt[h + 2][t + 1] = v.z; xt[h + 3][t + 1] = v.w;
    }
    if (tid < 128) { xt[tid][0] = 0.f; xt[tid][33] = 0.f; }
    __syncthreads();

    // phase 2: conv1d K=3 'SAME'. window reads: 4x b128 + 1x b64, broadcast, no bounds checks
    float acc[16];
    float bo = conv_b[o];
#pragma unroll
    for (int j = 0; j < 16; ++j) acc[j] = bo;
    for (int hi = 0; hi < H_DIM; ++hi) {
        float w0 = wt[(0 * 128 + hi) * 128 + o];
        float w1 = wt[(1 * 128 + hi) * 128 + o];
        float w2 = wt[(2 * 128 + hi) * 128 + o];
        const float* row = &xt[hi][th * 16];
        float4 a0 = *(const float4*)(row);
        float4 a1 = *(const float4*)(row + 4);
        float4 a2 = *(const float4*)(row + 8);
        float4 a3 = *(const float4*)(row + 12);
        float2 a4 = *(const float2*)(row + 16);
        float xv[18] = {a0.x, a0.y, a0.z, a0.w, a1.x, a1.y, a1.z, a1.w,
                        a2.x, a2.y, a2.z, a2.w, a3.x, a3.y, a3.z, a3.w, a4.x, a4.y};
#pragma unroll
        for (int j = 0; j < 16; ++j) acc[j] += w0 * xv[j] + w1 * xv[j + 1] + w2 * xv[j + 2];
    }
    __syncthreads();  // all conv reads of xt complete

    // phase 3: residual r = x + y (read old x at halo offset, then write r shifted to col t)
    float r[16];
#pragma unroll
    for (int j = 0; j < 16; ++j) r[j] = xt[o][th * 16 + j + 1] + acc[j];
    __syncthreads();
#pragma unroll
    for (int j = 0; j < 16; ++j) xt[o][th * 16 + j] = r[j];
    __syncthreads();

    // phase 4: LN1 over H per t (4 waves, in-place xt -> x1), also write x1 to global
    int wv = tid >> 6, lane = tid & 63;
    for (int t = wv; t < T_STEPS; t += 4) {
        float r0 = xt[lane][t], r1 = xt[lane + 64][t];
        float s = r0 + r1, s2 = r0 * r0 + r1 * r1;
#pragma unroll
        for (int mm = 1; mm < 64; mm <<= 1) {
            s += __shfl_xor(s, mm);
            s2 += __shfl_xor(s2, mm);
        }
        float mean = s * (1.f / 128.f);
        float var = s2 * (1.f / 128.f) - mean * mean;
        float rs = rsqrtf(var + LN_EPS);
        float o0 = (r0 - mean) * rs * ln1_g[lane] + ln1_b[lane];
        float o1 = (r1 - mean) * rs * ln1_g[lane + 64] + ln1_b[lane + 64];
        xt[lane][t] = o0;
        xt[lane + 64][t] = o1;
        x1[(n * T_STEPS + t) * H_DIM + lane] = o0;
        x1[(n * T_STEPS + t) * H_DIM + lane + 64] = o1;
    }
    __syncthreads();

    // phase 5: gl/gr GEMMs; xt now holds x1 transposed [h][t]. NODE-MAJOR outputs [n][t][h].
    float accl[16], accr[16];
#pragma unroll
    for (int j = 0; j < 16; ++j) { accl[j] = 0.f; accr[j] = 0.f; }
    for (int hi = 0; hi < H_DIM; ++hi) {
        float wl = Wl[hi * H_DIM + o];
        float wr = Wr[hi * H_DIM + o];
        const float* row = &xt[hi][th * 16];
        float4 b0 = *(const float4*)(row);
        float4 b1 = *(const float4*)(row + 4);
        float4 b2 = *(const float4*)(row + 8);
        float4 b3 = *(const float4*)(row + 12);
        float xv[16] = {b0.x, b0.y, b0.z, b0.w, b1.x, b1.y, b1.z, b1.w,
                        b2.x, b2.y, b2.z, b2.w, b3.x, b3.y, b3.z, b3.w};
#pragma unroll
        for (int j = 0; j < 16; ++j) {
            accl[j] += xv[j] * wl;
            accr[j] += xv[j] * wr;
        }
    }
#pragma unroll
    for (int j = 0; j < 16; ++j) {
        int t = th * 16 + j;
        gl[(n * T_STEPS + t) * H_DIM + o] = accl[j];
        gr[(n * T_STEPS + t) * H_DIM + o] = accr[j];
    }
}

// ---------- GATv2: one block per node, ALL 32 graphs; ee read once per edge ----------
// gl/gr layout: [n][g][h] (node-major). Thread (gq=tid>>7, h=tid&127) owns graphs g=2*gi+gq.
__global__ __launch_bounds__(256) void k_gat(
    const float* __restrict__ gl, const float* __restrict__ gr, const float* __restrict__ ee,
    const int* __restrict__ src_arr, const int* __restrict__ csr,
    const int* __restrict__ offs, const int* __restrict__ cnt,
    const float* __restrict__ att, const float* __restrict__ gat_b,
    const float* __restrict__ x1, const float* __restrict__ ln2_g,
    const float* __restrict__ ln2_b, float* __restrict__ out) {
    int n = blockIdx.x;
    int tid = threadIdx.x;
    int h = tid & 127, gq = tid >> 7;

    __shared__ int es[64], ss[64];
    __shared__ float red[4][16][2];

    float attv = att[h];
    float grv[16], m[16], l[16], acc[16];
#pragma unroll
    for (int gi = 0; gi < 16; ++gi) {
        int g = 2 * gi + gq;
        grv[gi] = gr[((size_t)n * G_GRAPHS + g) * H_DIM + h];
        m[gi] = -INFINITY; l[gi] = 0.f; acc[gi] = 0.f;
    }

    int off = offs[n], deg = cnt[n];
    int tot = deg + 1;  // + self-loop (last)

    for (int base = 0; base < tot; base += 64) {
        int c = min(64, tot - base);
        __syncthreads();
        if (tid < c) {
            int i = base + tid;
            int e = (i < deg) ? csr[off + i] : (E_EDGES + n);
            es[tid] = e;
            ss[tid] = (i < deg) ? src_arr[e] : n;
        }
        __syncthreads();
        for (int i = 0; i < c; ++i) {
            int e = es[i], s = ss[i];
            float eev = ee[(size_t)e * H_DIM + h];
            const float* glrow = gl + (size_t)s * G_GRAPHS * H_DIM + h;
            float glv[16];
#pragma unroll
            for (int gi = 0; gi < 16; ++gi) glv[gi] = glrow[(2 * gi + gq) * H_DIM];
#pragma unroll
            for (int gi = 0; gi < 16; ++gi) {
                float sf = glv[gi] + grv[gi] + eev;
                sf = (sf >= 0.f) ? sf : NEG_SLOPE * sf;
                float p = sf * attv;
#pragma unroll
                for (int mm = 1; mm < 32; mm <<= 1) p += __shfl_xor(p, mm);  // reduce over d
                float mn = fmaxf(m[gi], p);
                float sc = __expf(m[gi] - mn);  // exp(-inf)=0 on first iter
                float w = __expf(p - mn);
                l[gi] = l[gi] * sc + w;
                acc[gi] = acc[gi] * sc + w * glv[gi];
                m[gi] = mn;
            }
        }
    }

    // epilogue: residual + LN2, per graph; reduction over 128 h = 2 waves per gq
    int wid = tid >> 6;
    float rv[16];
    float gb = gat_b[h];
    float g2 = ln2_g[h], b2 = ln2_b[h];
#pragma unroll
    for (int gi = 0; gi < 16; ++gi) {
        int g = 2 * gi + gq;
        float ov = acc[gi] / l[gi] + gb;
        rv[gi] = x1[((size_t)n * T_STEPS + g) * H_DIM + h] + ov;
        float s1 = rv[gi], s2v = rv[gi] * rv[gi];
#pragma unroll
        for (int mm = 1; mm < 64; mm <<= 1) {
            s1 += __shfl_xor(s1, mm);
            s2v += __shfl_xor(s2v, mm);
        }
        if ((tid & 63) == 0) { red[wid][gi][0] = s1; red[wid][gi][1] = s2v; }
    }
    __syncthreads();
#pragma unroll
    for (int gi = 0; gi < 16; ++gi) {
        int g = 2 * gi + gq;
        float ts = red[gq * 2][gi][0] + red[gq * 2 + 1][gi][0];
        float ts2 = red[gq * 2][gi][1] + red[gq * 2 + 1][gi][1];
        float mean = ts * (1.f / 128.f);
        float var = ts2 * (1.f / 128.f) - mean * mean;
        float rs = rsqrtf(var + LN_EPS);
        out[((size_t)n * T_STEPS + g) * H_DIM + h] = (rv[gi] - mean) * rs * g2 + b2;
    }
}

extern "C" void kernel_launch(void* const* d_in, const int* in_sizes, int n_in,
                              void* d_out, int out_size, void* d_ws, size_t ws_size,
                              hipStream_t stream) {
    const float* x         = (const float*)d_in[0];
    const int*   ei        = (const int*)d_in[1];
    const float* edge_attr = (const float*)d_in[2];
    const float* conv_w    = (const float*)d_in[3];
    const float* conv_b    = (const float*)d_in[4];
    const float* ln1_g     = (const float*)d_in[5];
    const float* ln1_b     = (const float*)d_in[6];
    const float* Wl        = (const float*)d_in[7];
    const float* Wr        = (const float*)d_in[8];
    const float* We        = (const float*)d_in[9];
    const float* att       = (const float*)d_in[10];
    const float* gat_b     = (const float*)d_in[11];
    const float* ln2_g     = (const float*)d_in[12];
    const float* ln2_b     = (const float*)d_in[13];
    float* out = (float*)d_out;

    const int* src = ei;
    const int* dst = ei + E_EDGES;

    // workspace layout (floats)
    float* wt  = (float*)d_ws;                 // 49152
    float* x1  = wt + 49152;                   // 4,096,000
    float* gl  = x1 + 4096000;                 // 4,096,000  [n][g][h]
    float* gr  = gl + 4096000;                 // 4,096,000  [n][g][h]
    float* eew = gr + 4096000;                 // 2,176,000
    float* la  = eew + 2176000;                // 16,000
    int*   cnt  = (int*)(la + 16000);          // 1000
    int*   offs = cnt + 1000;                  // 1001
    int*   csr  = offs + 1001;                 // 16000

    k_prep_w<<<192, 256, 0, stream>>>(conv_w, wt);
    hipMemsetAsync(cnt, 0, N_NODES * sizeof(int), stream);
    k_count<<<(E_EDGES + 255) / 256, 256, 0, stream>>>(dst, cnt);
    k_scan<<<1, 1024, 0, stream>>>(cnt, offs);
    k_fill<<<N_NODES, 64, 0, stream>>>(dst, offs, csr);
    k_loopattr<<<N_NODES, 64, 0, stream>>>(edge_attr, csr, offs, cnt, la);
    k_ee<<<(EP_EDGES + 1) / 2, 256, 0, stream>>>(edge_attr, la, We, eew);
    k_temporal<<<N_NODES, 256, 0, stream>>>(x, wt, conv_b, ln1_g, ln1_b, Wl, Wr, x1, gl, gr);
    k_gat<<<N_NODES, 256, 0, stream>>>(gl, gr, eew, src, csr, offs, cnt,
                                       att, gat_b, x1, ln2_g, ln2_b, out);
}

// Round 4
// 217.893 us; speedup vs baseline: 1.6229x; 1.6229x over previous
//
#include <hip/hip_runtime.h>
#include <math.h>

#define N_NODES 1000
#define T_STEPS 32
#define H_DIM   128
#define E_EDGES 16000
#define ED_DIM  16
#define G_GRAPHS 32
#define EP_EDGES (E_EDGES + N_NODES)
#define NEG_SLOPE 0.2f
#define LN_EPS 1e-5f
#define XT_STRIDE 36   // 34 used cols padded to 36 -> row byte stride 144 = 9*16 (b128-aligned)

// ---------- prep: transpose conv_w [O][I][K] -> wt[k][i][o] (coalesced per-o reads) ----------
__global__ void k_prep_w(const float* __restrict__ conv_w, float* __restrict__ wt) {
    int i = blockIdx.x * 256 + threadIdx.x;
    if (i >= 128 * 128 * 3) return;
    int k = i % 3;
    int hi = (i / 3) % 128;
    int o = i / (3 * 128);
    wt[(k * 128 + hi) * 128 + o] = conv_w[i];
}

// ---------- CSR by dst: counts (int atomics) ----------
__global__ void k_count(const int* __restrict__ dst, int* __restrict__ cnt) {
    int e = blockIdx.x * 256 + threadIdx.x;
    if (e < E_EDGES) atomicAdd(&cnt[dst[e]], 1);
}

// ---------- exclusive scan over N=1000 counts (single block) ----------
__global__ void k_scan(const int* __restrict__ cnt, int* __restrict__ offs) {
    __shared__ int sm[1024];
    int t = threadIdx.x;
    sm[t] = (t < N_NODES) ? cnt[t] : 0;
    for (int s = 1; s < 1024; s <<= 1) {
        __syncthreads();
        int a = (t >= s) ? sm[t - s] : 0;
        __syncthreads();
        sm[t] += a;
    }
    __syncthreads();
    if (t < N_NODES) offs[t + 1] = sm[t];
    if (t == 0) offs[0] = 0;
}

// ---------- placement: slot via atomic (order nondeterministic; fixed by sort below) ----------
__global__ void k_place(const int* __restrict__ dst, const int* __restrict__ offs,
                        int* __restrict__ cnt2, int* __restrict__ csr) {
    int e = blockIdx.x * 256 + threadIdx.x;
    if (e >= E_EDGES) return;
    int d = dst[e];
    int slot = atomicAdd(&cnt2[d], 1);
    csr[offs[d] + slot] = e;
}

// ---------- per-node: sort CSR segment ascending (deterministic) + loop_attr mean ----------
__global__ __launch_bounds__(64) void k_sortla(
    const float* __restrict__ edge_attr, int* __restrict__ csr,
    const int* __restrict__ offs, const int* __restrict__ cnt,
    float* __restrict__ loop_attr) {
    __shared__ int buf[128];
    int n = blockIdx.x;
    int lane = threadIdx.x;  // 64
    int off = offs[n], deg = cnt[n];

    if (deg <= 64) {
        int v = (lane < deg) ? csr[off + lane] : 0x7FFFFFFF;
        int rank = 0;
#pragma unroll
        for (int j = 0; j < 64; ++j) {
            int vj = __shfl(v, j);
            rank += (vj < v) ? 1 : 0;
        }
        if (lane < deg) buf[rank] = v;
    } else {  // cold path (deg>64 not expected for this input, but stay correct to 128)
        for (int i = lane; i < deg && i < 128; i += 64) buf[i] = csr[off + i];
        __syncthreads();
        if (lane == 0) {
            int dd = deg < 128 ? deg : 128;
            for (int i = 1; i < dd; ++i) {
                int key = buf[i], j = i - 1;
                while (j >= 0 && buf[j] > key) { buf[j + 1] = buf[j]; --j; }
                buf[j + 1] = key;
            }
        }
    }
    __syncthreads();
    if (lane < deg) csr[off + lane] = buf[lane];

    // loop_attr: mean of incoming edge_attr in sorted order
    int q = lane >> 4, f = lane & 15;  // 4-way edge parallel over 16 channels
    float a = 0.f;
    for (int i = q; i < deg; i += 4) a += edge_attr[buf[i] * ED_DIM + f];
    a += __shfl_xor(a, 16);
    a += __shfl_xor(a, 32);
    if (lane < 16) loop_attr[n * ED_DIM + lane] = a / fmaxf((float)deg, 1.0f);
}

// ---------- ee[e][h] = ea[e] @ We, for all E+N edges ----------
__global__ void k_ee(const float* __restrict__ edge_attr, const float* __restrict__ loop_attr,
                     const float* __restrict__ We, float* __restrict__ ee) {
    int e = blockIdx.x * 2 + (threadIdx.x >> 7);
    int h = threadIdx.x & 127;
    if (e >= EP_EDGES) return;
    const float* ea = (e < E_EDGES) ? &edge_attr[e * ED_DIM]
                                    : &loop_attr[(e - E_EDGES) * ED_DIM];
    float acc = 0.f;
#pragma unroll
    for (int f = 0; f < ED_DIM; ++f) acc += ea[f] * We[f * H_DIM + h];
    ee[e * H_DIM + h] = acc;
}

// ---------- fused: conv1d + residual + LN1 + gl/gr GEMMs; transposed-halo LDS, one buffer ----------
__global__ __launch_bounds__(256) void k_temporal(
    const float* __restrict__ x, const float* __restrict__ wt, const float* __restrict__ conv_b,
    const float* __restrict__ ln1_g, const float* __restrict__ ln1_b,
    const float* __restrict__ Wl, const float* __restrict__ Wr,
    float* __restrict__ x1, float* __restrict__ gl, float* __restrict__ gr) {
    __shared__ float xt[H_DIM][XT_STRIDE];  // 18432 B; xt[h][tt] = x[tt-1][h], halo cols 0,33 = 0
    int n = blockIdx.x;
    int tid = threadIdx.x;
    int o = tid & 127, th = tid >> 7;  // thread owns out-channel o, t-range [th*16, th*16+16)

    // phase 1: load x[n] (float4, coalesced) -> transposed LDS with halo
    const float4* xv4 = (const float4*)(x + n * T_STEPS * H_DIM);
    for (int i4 = tid; i4 < T_STEPS * H_DIM / 4; i4 += 256) {
        float4 v = xv4[i4];
        int t = (i4 * 4) >> 7, h = (i4 * 4) & 127;
        xt[h][t + 1] = v.x; xt[h + 1][t + 1] = v.y;
        xt[h + 2][t + 1] = v.z; xt[h + 3][t + 1] = v.w;
    }
    if (tid < 128) { xt[tid][0] = 0.f; xt[tid][33] = 0.f; }
    __syncthreads();

    // phase 2: conv1d K=3 'SAME'. window reads: 4x b128 + 1x b64, broadcast, no bounds checks
    float acc[16];
    float bo = conv_b[o];
#pragma unroll
    for (int j = 0; j < 16; ++j) acc[j] = bo;
    for (int hi = 0; hi < H_DIM; ++hi) {
        float w0 = wt[(0 * 128 + hi) * 128 + o];
        float w1 = wt[(1 * 128 + hi) * 128 + o];
        float w2 = wt[(2 * 128 + hi) * 128 + o];
        const float* row = &xt[hi][th * 16];
        float4 a0 = *(const float4*)(row);
        float4 a1 = *(const float4*)(row + 4);
        float4 a2 = *(const float4*)(row + 8);
        float4 a3 = *(const float4*)(row + 12);
        float2 a4 = *(const float2*)(row + 16);
        float xv[18] = {a0.x, a0.y, a0.z, a0.w, a1.x, a1.y, a1.z, a1.w,
                        a2.x, a2.y, a2.z, a2.w, a3.x, a3.y, a3.z, a3.w, a4.x, a4.y};
#pragma unroll
        for (int j = 0; j < 16; ++j) acc[j] += w0 * xv[j] + w1 * xv[j + 1] + w2 * xv[j + 2];
    }
    __syncthreads();  // all conv reads of xt complete

    // phase 3: residual r = x + y (read old x at halo offset, then write r shifted to col t)
    float r[16];
#pragma unroll
    for (int j = 0; j < 16; ++j) r[j] = xt[o][th * 16 + j + 1] + acc[j];
    __syncthreads();
#pragma unroll
    for (int j = 0; j < 16; ++j) xt[o][th * 16 + j] = r[j];
    __syncthreads();

    // phase 4: LN1 over H per t (4 waves, in-place xt -> x1), also write x1 to global
    int wv = tid >> 6, lane = tid & 63;
    for (int t = wv; t < T_STEPS; t += 4) {
        float r0 = xt[lane][t], r1 = xt[lane + 64][t];
        float s = r0 + r1, s2 = r0 * r0 + r1 * r1;
#pragma unroll
        for (int mm = 1; mm < 64; mm <<= 1) {
            s += __shfl_xor(s, mm);
            s2 += __shfl_xor(s2, mm);
        }
        float mean = s * (1.f / 128.f);
        float var = s2 * (1.f / 128.f) - mean * mean;
        float rs = rsqrtf(var + LN_EPS);
        float o0 = (r0 - mean) * rs * ln1_g[lane] + ln1_b[lane];
        float o1 = (r1 - mean) * rs * ln1_g[lane + 64] + ln1_b[lane + 64];
        xt[lane][t] = o0;
        xt[lane + 64][t] = o1;
        x1[(n * T_STEPS + t) * H_DIM + lane] = o0;
        x1[(n * T_STEPS + t) * H_DIM + lane + 64] = o1;
    }
    __syncthreads();

    // phase 5: gl/gr GEMMs; xt holds x1 transposed [h][t]. GRAPH-MAJOR outputs [g=t][n][h].
    float accl[16], accr[16];
#pragma unroll
    for (int j = 0; j < 16; ++j) { accl[j] = 0.f; accr[j] = 0.f; }
    for (int hi = 0; hi < H_DIM; ++hi) {
        float wl = Wl[hi * H_DIM + o];
        float wr = Wr[hi * H_DIM + o];
        const float* row = &xt[hi][th * 16];
        float4 b0 = *(const float4*)(row);
        float4 b1 = *(const float4*)(row + 4);
        float4 b2 = *(const float4*)(row + 8);
        float4 b3 = *(const float4*)(row + 12);
        float xv[16] = {b0.x, b0.y, b0.z, b0.w, b1.x, b1.y, b1.z, b1.w,
                        b2.x, b2.y, b2.z, b2.w, b3.x, b3.y, b3.z, b3.w};
#pragma unroll
        for (int j = 0; j < 16; ++j) {
            accl[j] += xv[j] * wl;
            accr[j] += xv[j] * wr;
        }
    }
#pragma unroll
    for (int j = 0; j < 16; ++j) {
        int t = th * 16 + j;
        gl[(t * N_NODES + n) * H_DIM + o] = accl[j];
        gr[(t * N_NODES + n) * H_DIM + o] = accr[j];
    }
}

// ---------- GATv2 per (graph, node), g-major blocks: gl slice + ee rows stay L2-resident ----------
__global__ __launch_bounds__(128) void k_gat(
    const float* __restrict__ gl, const float* __restrict__ gr, const float* __restrict__ ee,
    const int* __restrict__ src_arr, const int* __restrict__ csr,
    const int* __restrict__ offs, const int* __restrict__ cnt,
    const float* __restrict__ att, const float* __restrict__ gat_b,
    const float* __restrict__ x1, const float* __restrict__ ln2_g,
    const float* __restrict__ ln2_b, float* __restrict__ out) {
    int bid = blockIdx.x;        // bid = g*N + n: one graph's blocks are contiguous;
    int g = bid / N_NODES;       // bid%8 == n%8 -> each XCD re-reads the SAME nodes' ee rows
    int n = bid - g * N_NODES;   // every g-pass (L2-resident), and gl g-slice is 512KB (L2-fit).
    int tid = threadIdx.x;       // channel h; head k = tid>>5

    __shared__ int es[64], ss[64];
    int off = offs[n], deg = cnt[n];
    int tot = deg + 1;  // + self-loop (last)

    float grv = gr[((size_t)g * N_NODES + n) * H_DIM + tid];
    float attv = att[tid];
    float m = -INFINITY, l = 0.f, acc = 0.f;
    const float* glg = gl + (size_t)g * N_NODES * H_DIM;

    for (int base = 0; base < tot; base += 64) {
        int c = min(64, tot - base);
        __syncthreads();
        if (tid < c) {
            int i = base + tid;
            int e = (i < deg) ? csr[off + i] : (E_EDGES + n);
            es[tid] = e;
            ss[tid] = (i < deg) ? src_arr[e] : n;
        }
        __syncthreads();
        float glv = glg[ss[0] * H_DIM + tid];
        float eev = ee[(size_t)es[0] * H_DIM + tid];
        for (int i = 0; i < c; ++i) {
            float glc = glv, eec = eev;
            if (i + 1 < c) {
                glv = glg[ss[i + 1] * H_DIM + tid];
                eev = ee[(size_t)es[i + 1] * H_DIM + tid];
            }
            float sf = glc + grv + eec;
            sf = (sf >= 0.f) ? sf : NEG_SLOPE * sf;
            float p = sf * attv;
#pragma unroll
            for (int mm = 1; mm < 32; mm <<= 1) p += __shfl_xor(p, mm);  // reduce over d in head
            float mn = fmaxf(m, p);
            float sc = __expf(m - mn);  // exp(-inf)=0 on first iter
            float w = __expf(p - mn);
            l = l * sc + w;
            acc = acc * sc + w * glc;
            m = mn;
        }
    }

    float ov = acc / l + gat_b[tid];
    float rv = x1[((size_t)n * T_STEPS + g) * H_DIM + tid] + ov;

    // LN2 across 128 threads (2 waves)
    __shared__ float red[4];
    float s1 = rv, s2v = rv * rv;
#pragma unroll
    for (int mm = 1; mm < 64; mm <<= 1) {
        s1 += __shfl_xor(s1, mm);
        s2v += __shfl_xor(s2v, mm);
    }
    int wave = tid >> 6, lane = tid & 63;
    if (lane == 0) { red[wave * 2] = s1; red[wave * 2 + 1] = s2v; }
    __syncthreads();
    float ts = red[0] + red[2], ts2 = red[1] + red[3];
    float mean = ts * (1.f / 128.f);
    float var = ts2 * (1.f / 128.f) - mean * mean;
    float rs = rsqrtf(var + LN_EPS);
    out[((size_t)n * T_STEPS + g) * H_DIM + tid] = (rv - mean) * rs * ln2_g[tid] + ln2_b[tid];
}

extern "C" void kernel_launch(void* const* d_in, const int* in_sizes, int n_in,
                              void* d_out, int out_size, void* d_ws, size_t ws_size,
                              hipStream_t stream) {
    const float* x         = (const float*)d_in[0];
    const int*   ei        = (const int*)d_in[1];
    const float* edge_attr = (const float*)d_in[2];
    const float* conv_w    = (const float*)d_in[3];
    const float* conv_b    = (const float*)d_in[4];
    const float* ln1_g     = (const float*)d_in[5];
    const float* ln1_b     = (const float*)d_in[6];
    const float* Wl        = (const float*)d_in[7];
    const float* Wr        = (const float*)d_in[8];
    const float* We        = (const float*)d_in[9];
    const float* att       = (const float*)d_in[10];
    const float* gat_b     = (const float*)d_in[11];
    const float* ln2_g     = (const float*)d_in[12];
    const float* ln2_b     = (const float*)d_in[13];
    float* out = (float*)d_out;

    const int* src = ei;
    const int* dst = ei + E_EDGES;

    // workspace layout (floats)
    float* wt  = (float*)d_ws;                 // 49152
    float* x1  = wt + 49152;                   // 4,096,000  [n][t][h]
    float* gl  = x1 + 4096000;                 // 4,096,000  [g][n][h]
    float* gr  = gl + 4096000;                 // 4,096,000  [g][n][h]
    float* eew = gr + 4096000;                 // 2,176,000
    float* la  = eew + 2176000;                // 16,000
    int*   cnt  = (int*)(la + 16000);          // 1000
    int*   cnt2 = cnt + 1000;                  // 1000
    int*   offs = cnt2 + 1000;                 // 1001
    int*   csr  = offs + 1001;                 // 16000

    k_prep_w<<<192, 256, 0, stream>>>(conv_w, wt);
    hipMemsetAsync(cnt, 0, 2 * N_NODES * sizeof(int), stream);
    k_count<<<(E_EDGES + 255) / 256, 256, 0, stream>>>(dst, cnt);
    k_scan<<<1, 1024, 0, stream>>>(cnt, offs);
    k_place<<<(E_EDGES + 255) / 256, 256, 0, stream>>>(dst, offs, cnt2, csr);
    k_sortla<<<N_NODES, 64, 0, stream>>>(edge_attr, csr, offs, cnt, la);
    k_ee<<<(EP_EDGES + 1) / 2, 256, 0, stream>>>(edge_attr, la, We, eew);
    k_temporal<<<N_NODES, 256, 0, stream>>>(x, wt, conv_b, ln1_g, ln1_b, Wl, Wr, x1, gl, gr);
    k_gat<<<N_NODES * G_GRAPHS, 128, 0, stream>>>(gl, gr, eew, src, csr, offs, cnt,
                                                  att, gat_b, x1, ln2_g, ln2_b, out);
}

// Round 5
// 149.011 us; speedup vs baseline: 2.3731x; 1.4623x over previous
//
#include <hip/hip_runtime.h>
#include <math.h>

#define N_NODES 1000
#define T_STEPS 32
#define H_DIM   128
#define E_EDGES 16000
#define ED_DIM  16
#define G_GRAPHS 32
#define EP_EDGES (E_EDGES + N_NODES)
#define NEG_SLOPE 0.2f
#define LN_EPS 1e-5f

typedef __attribute__((ext_vector_type(8))) short bf16x8;
typedef __attribute__((ext_vector_type(16))) float f32x16;

__device__ inline short f2bf(float f) {  // RNE f32 -> bf16
    unsigned u = __float_as_uint(f);
    u = (u + 0x7FFFu + ((u >> 16) & 1u)) >> 16;
    return (short)u;
}

// ---------- pack conv_w [O][I][K] -> MFMA-B fragments wc[ct(4)][kstep(24)][lane(64)][r(8)] ----------
// consumption: B[kk][o], kk = k*128 + hi; per K-step of 16: hi = hs*16 + (lane>>5)*8 + r, o = ct*32 + (lane&31)
__global__ void k_pack_conv(const float* __restrict__ conv_w, short* __restrict__ wc) {
    int i = blockIdx.x * 256 + threadIdx.x;
    if (i >= 4 * 24 * 64 * 8) return;
    int r = i & 7, lane = (i >> 3) & 63;
    int t = i >> 9;
    int kstep = t % 24, ct = t / 24;
    int k = kstep >> 3, hs = kstep & 7;
    int hi = hs * 16 + ((lane >> 5) << 3) + r;
    int o = ct * 32 + (lane & 31);
    wc[i] = f2bf(conv_w[(o * H_DIM + hi) * 3 + k]);
}

// ---------- pack Wl|Wr [H][H] -> wg[ct(8)][ks(8)][lane(64)][r(8)]; ct 0-3 = Wl cols, 4-7 = Wr ----------
__global__ void k_pack_g(const float* __restrict__ Wl, const float* __restrict__ Wr,
                         short* __restrict__ wg) {
    int i = blockIdx.x * 256 + threadIdx.x;
    if (i >= 8 * 8 * 64 * 8) return;
    int r = i & 7, lane = (i >> 3) & 63;
    int ks = (i >> 9) & 7, ct = i >> 12;
    int hi = ks * 16 + ((lane >> 5) << 3) + r;
    int o = ct * 32 + (lane & 31);
    wg[i] = f2bf(o < H_DIM ? Wl[hi * H_DIM + o] : Wr[hi * H_DIM + o - H_DIM]);
}

// ---------- CSR by dst: counts (int atomics) ----------
__global__ void k_count(const int* __restrict__ dst, int* __restrict__ cnt) {
    int e = blockIdx.x * 256 + threadIdx.x;
    if (e < E_EDGES) atomicAdd(&cnt[dst[e]], 1);
}

// ---------- exclusive scan over N=1000 counts (single block) ----------
__global__ void k_scan(const int* __restrict__ cnt, int* __restrict__ offs) {
    __shared__ int sm[1024];
    int t = threadIdx.x;
    sm[t] = (t < N_NODES) ? cnt[t] : 0;
    for (int s = 1; s < 1024; s <<= 1) {
        __syncthreads();
        int a = (t >= s) ? sm[t - s] : 0;
        __syncthreads();
        sm[t] += a;
    }
    __syncthreads();
    if (t < N_NODES) offs[t + 1] = sm[t];
    if (t == 0) offs[0] = 0;
}

// ---------- placement: slot via atomic (order fixed by sort below) ----------
__global__ void k_place(const int* __restrict__ dst, const int* __restrict__ offs,
                        int* __restrict__ cnt2, int* __restrict__ csr) {
    int e = blockIdx.x * 256 + threadIdx.x;
    if (e >= E_EDGES) return;
    int d = dst[e];
    int slot = atomicAdd(&cnt2[d], 1);
    csr[offs[d] + slot] = e;
}

// ---------- per-node: sort CSR segment ascending (deterministic) + loop_attr mean ----------
__global__ __launch_bounds__(64) void k_sortla(
    const float* __restrict__ edge_attr, int* __restrict__ csr,
    const int* __restrict__ offs, const int* __restrict__ cnt,
    float* __restrict__ loop_attr) {
    __shared__ int buf[128];
    int n = blockIdx.x;
    int lane = threadIdx.x;  // 64
    int off = offs[n], deg = cnt[n];

    if (deg <= 64) {
        int v = (lane < deg) ? csr[off + lane] : 0x7FFFFFFF;
        int rank = 0;
#pragma unroll
        for (int j = 0; j < 64; ++j) {
            int vj = __shfl(v, j);
            rank += (vj < v) ? 1 : 0;
        }
        if (lane < deg) buf[rank] = v;
    } else {  // cold path: deg in (64,128]
        for (int i = lane; i < deg && i < 128; i += 64) buf[i] = csr[off + i];
        __syncthreads();
        if (lane == 0) {
            int dd = deg < 128 ? deg : 128;
            for (int i = 1; i < dd; ++i) {
                int key = buf[i], j = i - 1;
                while (j >= 0 && buf[j] > key) { buf[j + 1] = buf[j]; --j; }
                buf[j + 1] = key;
            }
        }
    }
    __syncthreads();
    if (lane < deg) csr[off + lane] = buf[lane];

    int q = lane >> 4, f = lane & 15;
    float a = 0.f;
    for (int i = q; i < deg; i += 4) a += edge_attr[buf[i] * ED_DIM + f];
    a += __shfl_xor(a, 16);
    a += __shfl_xor(a, 32);
    if (lane < 16) loop_attr[n * ED_DIM + lane] = a / fmaxf((float)deg, 1.0f);
}

// ---------- ee[e][h] = ea[e] @ We, for all E+N edges ----------
__global__ void k_ee(const float* __restrict__ edge_attr, const float* __restrict__ loop_attr,
                     const float* __restrict__ We, float* __restrict__ ee) {
    int e = blockIdx.x * 2 + (threadIdx.x >> 7);
    int h = threadIdx.x & 127;
    if (e >= EP_EDGES) return;
    const float* ea = (e < E_EDGES) ? &edge_attr[e * ED_DIM]
                                    : &loop_attr[(e - E_EDGES) * ED_DIM];
    float acc = 0.f;
#pragma unroll
    for (int f = 0; f < ED_DIM; ++f) acc += ea[f] * We[f * H_DIM + h];
    ee[e * H_DIM + h] = acc;
}

// ---------- fused temporal: conv (MFMA) + residual + LN1 + gl/gr (MFMA), one block/node ----------
// xb row stride 136 shorts = 272 B (16B-aligned rows; 4-way bank alias on A reads, free-ish).
__global__ __launch_bounds__(256) void k_temporal(
    const float* __restrict__ x, const short* __restrict__ wc, const short* __restrict__ wg,
    const float* __restrict__ conv_b, const float* __restrict__ ln1_g,
    const float* __restrict__ ln1_b, float* __restrict__ x1,
    float* __restrict__ gl, float* __restrict__ gr) {
    __shared__ __align__(16) short xb[34 * 136];  // bf16; row r = x[r-1][.], rows 0 & 33 zero
    __shared__ float yb[32 * 132];                // conv output (f32)
    int n = blockIdx.x;
    int tid = threadIdx.x;
    int w = tid >> 6, lane = tid & 63;
    int arow = lane & 31;        // MFMA A row (t)
    int aks = (lane >> 5) << 3;  // k-slice base within 16

    // phase 0: x -> bf16 transposed-in-time LDS with halo rows
    {
        const float4* xs4 = (const float4*)(x + (size_t)n * T_STEPS * H_DIM);
        for (int i4 = tid; i4 < T_STEPS * H_DIM / 4; i4 += 256) {
            float4 v = xs4[i4];
            int t = i4 >> 5, h = (i4 * 4) & 127;
            uint2 pp;
            pp.x = (unsigned)(unsigned short)f2bf(v.x) | ((unsigned)(unsigned short)f2bf(v.y) << 16);
            pp.y = (unsigned)(unsigned short)f2bf(v.z) | ((unsigned)(unsigned short)f2bf(v.w) << 16);
            *(uint2*)&xb[(t + 1) * 136 + h] = pp;
        }
        if (tid < 68) {
            ((unsigned*)xb)[tid] = 0u;
            ((unsigned*)(xb + 33 * 136))[tid] = 0u;
        }
    }
    __syncthreads();

    // phase 1: conv = MFMA GEMM, Y[32][128], K=384 (kk = k*128 + hi); wave owns o-tile 32w
    f32x16 acc = {};
    for (int kk = 0; kk < 3; ++kk) {
#pragma unroll
        for (int hs = 0; hs < 8; ++hs) {
            int kstep = kk * 8 + hs;
            bf16x8 a = *(const bf16x8*)&xb[(arow + kk) * 136 + hs * 16 + aks];
            bf16x8 b = *(const bf16x8*)&wc[((w * 24 + kstep) * 64 + lane) * 8];
            acc = __builtin_amdgcn_mfma_f32_32x32x16_bf16(a, b, acc, 0, 0, 0);
        }
    }
    {
        int oc = w * 32 + (lane & 31);
        float cb = conv_b[oc];
#pragma unroll
        for (int r = 0; r < 16; ++r) {
            int t = (r & 3) + 8 * (r >> 2) + 4 * (lane >> 5);
            yb[t * 132 + oc] = acc[r] + cb;
        }
    }
    __syncthreads();

    // phase 2: residual (x from global, L2-hot) + LN1 -> f32 x1 global + bf16 x1 into xb rows 0..31
    for (int t = w; t < T_STEPS; t += 4) {
        float r0 = x[((size_t)n * T_STEPS + t) * H_DIM + lane] + yb[t * 132 + lane];
        float r1 = x[((size_t)n * T_STEPS + t) * H_DIM + lane + 64] + yb[t * 132 + lane + 64];
        float s = r0 + r1, s2 = r0 * r0 + r1 * r1;
#pragma unroll
        for (int mm = 1; mm < 64; mm <<= 1) {
            s += __shfl_xor(s, mm);
            s2 += __shfl_xor(s2, mm);
        }
        float mean = s * (1.f / 128.f);
        float var = s2 * (1.f / 128.f) - mean * mean;
        float rs = rsqrtf(var + LN_EPS);
        float o0 = (r0 - mean) * rs * ln1_g[lane] + ln1_b[lane];
        float o1 = (r1 - mean) * rs * ln1_g[lane + 64] + ln1_b[lane + 64];
        x1[((size_t)n * T_STEPS + t) * H_DIM + lane] = o0;
        x1[((size_t)n * T_STEPS + t) * H_DIM + lane + 64] = o1;
        xb[t * 136 + lane] = f2bf(o0);
        xb[t * 136 + lane + 64] = f2bf(o1);
    }
    __syncthreads();

    // phase 3: gl/gr = MFMA GEMM [32x128]x[128x256]; wave w owns col-tiles 2w, 2w+1
    f32x16 cl = {}, cr = {};
#pragma unroll
    for (int ks = 0; ks < 8; ++ks) {
        bf16x8 a = *(const bf16x8*)&xb[arow * 136 + ks * 16 + aks];
        bf16x8 b0 = *(const bf16x8*)&wg[(((2 * w) * 8 + ks) * 64 + lane) * 8];
        bf16x8 b1 = *(const bf16x8*)&wg[(((2 * w + 1) * 8 + ks) * 64 + lane) * 8];
        cl = __builtin_amdgcn_mfma_f32_32x32x16_bf16(a, b0, cl, 0, 0, 0);
        cr = __builtin_amdgcn_mfma_f32_32x32x16_bf16(a, b1, cr, 0, 0, 0);
    }
    {
        int o0 = 64 * w + (lane & 31);             // global col in [0,256)
        float* d = (w < 2) ? gl : gr;              // waves 0,1 -> gl; 2,3 -> gr
        int oo0 = (w < 2) ? o0 : o0 - 128;
        int oo1 = oo0 + 32;
#pragma unroll
        for (int r = 0; r < 16; ++r) {
            int t = (r & 3) + 8 * (r >> 2) + 4 * (lane >> 5);
            d[((size_t)t * N_NODES + n) * H_DIM + oo0] = cl[r];
            d[((size_t)t * N_NODES + n) * H_DIM + oo1] = cr[r];
        }
    }
}

// ---------- GATv2 per (graph, node), g-major blocks: gl slice + ee rows stay L2-resident ----------
__global__ __launch_bounds__(128) void k_gat(
    const float* __restrict__ gl, const float* __restrict__ gr, const float* __restrict__ ee,
    const int* __restrict__ src_arr, const int* __restrict__ csr,
    const int* __restrict__ offs, const int* __restrict__ cnt,
    const float* __restrict__ att, const float* __restrict__ gat_b,
    const float* __restrict__ x1, const float* __restrict__ ln2_g,
    const float* __restrict__ ln2_b, float* __restrict__ out) {
    int bid = blockIdx.x;        // bid = g*N + n
    int g = bid / N_NODES;
    int n = bid - g * N_NODES;
    int tid = threadIdx.x;       // channel h; head k = tid>>5

    __shared__ int es[64], ss[64];
    int off = offs[n], deg = cnt[n];
    int tot = deg + 1;  // + self-loop (last)

    float grv = gr[((size_t)g * N_NODES + n) * H_DIM + tid];
    float attv = att[tid];
    float m = -INFINITY, l = 0.f, acc = 0.f;
    const float* glg = gl + (size_t)g * N_NODES * H_DIM;

    for (int base = 0; base < tot; base += 64) {
        int c = min(64, tot - base);
        __syncthreads();
        if (tid < c) {
            int i = base + tid;
            int e = (i < deg) ? csr[off + i] : (E_EDGES + n);
            es[tid] = e;
            ss[tid] = (i < deg) ? src_arr[e] : n;
        }
        __syncthreads();
        float glv = glg[ss[0] * H_DIM + tid];
        float eev = ee[(size_t)es[0] * H_DIM + tid];
        for (int i = 0; i < c; ++i) {
            float glc = glv, eec = eev;
            if (i + 1 < c) {
                glv = glg[ss[i + 1] * H_DIM + tid];
                eev = ee[(size_t)es[i + 1] * H_DIM + tid];
            }
            float sf = glc + grv + eec;
            sf = (sf >= 0.f) ? sf : NEG_SLOPE * sf;
            float p = sf * attv;
#pragma unroll
            for (int mm = 1; mm < 32; mm <<= 1) p += __shfl_xor(p, mm);
            float mn = fmaxf(m, p);
            float sc = __expf(m - mn);
            float wq = __expf(p - mn);
            l = l * sc + wq;
            acc = acc * sc + wq * glc;
            m = mn;
        }
    }

    float ov = acc / l + gat_b[tid];
    float rv = x1[((size_t)n * T_STEPS + g) * H_DIM + tid] + ov;

    __shared__ float red[4];
    float s1 = rv, s2v = rv * rv;
#pragma unroll
    for (int mm = 1; mm < 64; mm <<= 1) {
        s1 += __shfl_xor(s1, mm);
        s2v += __shfl_xor(s2v, mm);
    }
    int wave = tid >> 6, lane = tid & 63;
    if (lane == 0) { red[wave * 2] = s1; red[wave * 2 + 1] = s2v; }
    __syncthreads();
    float ts = red[0] + red[2], ts2 = red[1] + red[3];
    float mean = ts * (1.f / 128.f);
    float var = ts2 * (1.f / 128.f) - mean * mean;
    float rs = rsqrtf(var + LN_EPS);
    out[((size_t)n * T_STEPS + g) * H_DIM + tid] = (rv - mean) * rs * ln2_g[tid] + ln2_b[tid];
}

extern "C" void kernel_launch(void* const* d_in, const int* in_sizes, int n_in,
                              void* d_out, int out_size, void* d_ws, size_t ws_size,
                              hipStream_t stream) {
    const float* x         = (const float*)d_in[0];
    const int*   ei        = (const int*)d_in[1];
    const float* edge_attr = (const float*)d_in[2];
    const float* conv_w    = (const float*)d_in[3];
    const float* conv_b    = (const float*)d_in[4];
    const float* ln1_g     = (const float*)d_in[5];
    const float* ln1_b     = (const float*)d_in[6];
    const float* Wl        = (const float*)d_in[7];
    const float* Wr        = (const float*)d_in[8];
    const float* We        = (const float*)d_in[9];
    const float* att       = (const float*)d_in[10];
    const float* gat_b     = (const float*)d_in[11];
    const float* ln2_g     = (const float*)d_in[12];
    const float* ln2_b     = (const float*)d_in[13];
    float* out = (float*)d_out;

    const int* src = ei;
    const int* dst = ei + E_EDGES;

    // workspace layout
    float* x1  = (float*)d_ws;                 // 4,096,000  [n][t][h]
    float* gl  = x1 + 4096000;                 // 4,096,000  [g][n][h]
    float* gr  = gl + 4096000;                 // 4,096,000  [g][n][h]
    float* eew = gr + 4096000;                 // 2,176,000
    float* la  = eew + 2176000;                // 16,000
    int* ibase = (int*)(la + 16000);
    int* cnt   = ibase;                        // 1000
    int* cnt2  = ibase + 1000;                 // 1000
    int* offs  = ibase + 2000;                 // 1001
    int* csr   = ibase + 3001;                 // 16000 (ends 19001; pad to 19004)
    short* wc  = (short*)(ibase + 19004);      // 49152 shorts (16B aligned)
    short* wg  = wc + 49152;                   // 32768 shorts

    k_pack_conv<<<192, 256, 0, stream>>>(conv_w, wc);
    k_pack_g<<<128, 256, 0, stream>>>(Wl, Wr, wg);
    hipMemsetAsync(cnt, 0, 2 * N_NODES * sizeof(int), stream);
    k_count<<<(E_EDGES + 255) / 256, 256, 0, stream>>>(dst, cnt);
    k_scan<<<1, 1024, 0, stream>>>(cnt, offs);
    k_place<<<(E_EDGES + 255) / 256, 256, 0, stream>>>(dst, offs, cnt2, csr);
    k_sortla<<<N_NODES, 64, 0, stream>>>(edge_attr, csr, offs, cnt, la);
    k_ee<<<(EP_EDGES + 1) / 2, 256, 0, stream>>>(edge_attr, la, We, eew);
    k_temporal<<<N_NODES, 256, 0, stream>>>(x, wc, wg, conv_b, ln1_g, ln1_b, x1, gl, gr);
    k_gat<<<N_NODES * G_GRAPHS, 128, 0, stream>>>(gl, gr, eew, src, csr, offs, cnt,
                                                  att, gat_b, x1, ln2_g, ln2_b, out);
}

// Round 6
// 129.833 us; speedup vs baseline: 2.7237x; 1.1477x over previous
//
#include <hip/hip_runtime.h>
#include <math.h>

#define N_NODES 1000
#define T_STEPS 32
#define H_DIM   128
#define E_EDGES 16000
#define ED_DIM  16
#define G_GRAPHS 32
#define EP_EDGES (E_EDGES + N_NODES)
#define NEG_SLOPE 0.2f
#define LN_EPS 1e-5f

typedef __attribute__((ext_vector_type(8))) short bf16x8;
typedef __attribute__((ext_vector_type(16))) float f32x16;

__device__ inline short f2bf(float f) {  // RNE f32 -> bf16
    unsigned u = __float_as_uint(f);
    u = (u + 0x7FFFu + ((u >> 16) & 1u)) >> 16;
    return (short)u;
}

// ---------- pack conv_w + Wl/Wr into MFMA-B fragment order (one kernel) ----------
// wc[ct(4)][kstep(24)][lane(64)][r(8)]: B[kk][o], kk=k*128+hi; hi=hs*16+(lane>>5)*8+r, o=ct*32+(lane&31)
// wg[ct(8)][ks(8)][lane(64)][r(8)]: ct 0-3 = Wl cols, 4-7 = Wr
__global__ void k_pack(const float* __restrict__ conv_w, const float* __restrict__ Wl,
                       const float* __restrict__ Wr, short* __restrict__ wc,
                       short* __restrict__ wg) {
    int i = blockIdx.x * 256 + threadIdx.x;
    if (i < 4 * 24 * 64 * 8) {
        int r = i & 7, lane = (i >> 3) & 63;
        int t = i >> 9;
        int kstep = t % 24, ct = t / 24;
        int k = kstep >> 3, hs = kstep & 7;
        int hi = hs * 16 + ((lane >> 5) << 3) + r;
        int o = ct * 32 + (lane & 31);
        wc[i] = f2bf(conv_w[(o * H_DIM + hi) * 3 + k]);
    } else {
        int j = i - 4 * 24 * 64 * 8;
        if (j >= 8 * 8 * 64 * 8) return;
        int r = j & 7, lane = (j >> 3) & 63;
        int ks = (j >> 9) & 7, ct = j >> 12;
        int hi = ks * 16 + ((lane >> 5) << 3) + r;
        int o = ct * 32 + (lane & 31);
        wg[j] = f2bf(o < H_DIM ? Wl[hi * H_DIM + o] : Wr[hi * H_DIM + o - H_DIM]);
    }
}

// ---------- count + exclusive scan in ONE block (LDS atomics), also zero cnt2 ----------
__global__ __launch_bounds__(1024) void k_countscan(const int* __restrict__ dst,
                                                    int* __restrict__ cnt, int* __restrict__ cnt2,
                                                    int* __restrict__ offs) {
    __shared__ int sm[1024];
    int t = threadIdx.x;
    sm[t] = 0;
    __syncthreads();
    for (int e = t; e < E_EDGES; e += 1024) atomicAdd(&sm[dst[e]], 1);
    __syncthreads();
    int v = (t < N_NODES) ? sm[t] : 0;
    if (t < N_NODES) { cnt[t] = v; cnt2[t] = 0; }
    __syncthreads();
    sm[t] = v;
    for (int s = 1; s < 1024; s <<= 1) {
        __syncthreads();
        int a = (t >= s) ? sm[t - s] : 0;
        __syncthreads();
        sm[t] += a;
    }
    __syncthreads();
    if (t < N_NODES) offs[t + 1] = sm[t];
    if (t == 0) offs[0] = 0;
}

// ---------- placement: slot via atomic (order fixed by sort below) ----------
__global__ void k_place(const int* __restrict__ dst, const int* __restrict__ offs,
                        int* __restrict__ cnt2, int* __restrict__ csr) {
    int e = blockIdx.x * 256 + threadIdx.x;
    if (e >= E_EDGES) return;
    int d = dst[e];
    int slot = atomicAdd(&cnt2[d], 1);
    csr[offs[d] + slot] = e;
}

// ---------- per-node: sort CSR segment ascending (deterministic) + loop_attr mean ----------
__global__ __launch_bounds__(64) void k_sortla(
    const float* __restrict__ edge_attr, int* __restrict__ csr,
    const int* __restrict__ offs, const int* __restrict__ cnt,
    float* __restrict__ loop_attr) {
    __shared__ int buf[128];
    int n = blockIdx.x;
    int lane = threadIdx.x;  // 64
    int off = offs[n], deg = cnt[n];

    if (deg <= 64) {
        int v = (lane < deg) ? csr[off + lane] : 0x7FFFFFFF;
        int rank = 0;
#pragma unroll
        for (int j = 0; j < 64; ++j) {
            int vj = __shfl(v, j);
            rank += (vj < v) ? 1 : 0;
        }
        if (lane < deg) buf[rank] = v;
    } else {  // cold path: deg in (64,128]
        for (int i = lane; i < deg && i < 128; i += 64) buf[i] = csr[off + i];
        __syncthreads();
        if (lane == 0) {
            int dd = deg < 128 ? deg : 128;
            for (int i = 1; i < dd; ++i) {
                int key = buf[i], j = i - 1;
                while (j >= 0 && buf[j] > key) { buf[j + 1] = buf[j]; --j; }
                buf[j + 1] = key;
            }
        }
    }
    __syncthreads();
    if (lane < deg) csr[off + lane] = buf[lane];

    int q = lane >> 4, f = lane & 15;
    float a = 0.f;
    for (int i = q; i < deg; i += 4) a += edge_attr[buf[i] * ED_DIM + f];
    a += __shfl_xor(a, 16);
    a += __shfl_xor(a, 32);
    if (lane < 16) loop_attr[n * ED_DIM + lane] = a / fmaxf((float)deg, 1.0f);
}

// ---------- ee[e][h] = ea[e] @ We, for all E+N edges ----------
__global__ void k_ee(const float* __restrict__ edge_attr, const float* __restrict__ loop_attr,
                     const float* __restrict__ We, float* __restrict__ ee) {
    int e = blockIdx.x * 2 + (threadIdx.x >> 7);
    int h = threadIdx.x & 127;
    if (e >= EP_EDGES) return;
    const float* ea = (e < E_EDGES) ? &edge_attr[e * ED_DIM]
                                    : &loop_attr[(e - E_EDGES) * ED_DIM];
    float acc = 0.f;
#pragma unroll
    for (int f = 0; f < ED_DIM; ++f) acc += ea[f] * We[f * H_DIM + h];
    ee[e * H_DIM + h] = acc;
}

// ---------- fused temporal: conv (MFMA) + residual + LN1 + gl/gr (MFMA), one block/node ----------
__global__ __launch_bounds__(256) void k_temporal(
    const float* __restrict__ x, const short* __restrict__ wc, const short* __restrict__ wg,
    const float* __restrict__ conv_b, const float* __restrict__ ln1_g,
    const float* __restrict__ ln1_b, float* __restrict__ x1,
    float* __restrict__ gl, float* __restrict__ gr) {
    __shared__ __align__(16) short xb[34 * 136];  // bf16; row r = x[r-1][.], rows 0 & 33 zero
    __shared__ float yb[32 * 132];                // conv output (f32)
    int n = blockIdx.x;
    int tid = threadIdx.x;
    int w = tid >> 6, lane = tid & 63;
    int arow = lane & 31;        // MFMA A row (t)
    int aks = (lane >> 5) << 3;  // k-slice base within 16

    // phase 0: x -> bf16 transposed-in-time LDS with halo rows
    {
        const float4* xs4 = (const float4*)(x + (size_t)n * T_STEPS * H_DIM);
        for (int i4 = tid; i4 < T_STEPS * H_DIM / 4; i4 += 256) {
            float4 v = xs4[i4];
            int t = i4 >> 5, h = (i4 * 4) & 127;
            uint2 pp;
            pp.x = (unsigned)(unsigned short)f2bf(v.x) | ((unsigned)(unsigned short)f2bf(v.y) << 16);
            pp.y = (unsigned)(unsigned short)f2bf(v.z) | ((unsigned)(unsigned short)f2bf(v.w) << 16);
            *(uint2*)&xb[(t + 1) * 136 + h] = pp;
        }
        if (tid < 68) {
            ((unsigned*)xb)[tid] = 0u;
            ((unsigned*)(xb + 33 * 136))[tid] = 0u;
        }
    }
    __syncthreads();

    // phase 1: conv = MFMA GEMM, Y[32][128], K=384 (kk = k*128 + hi); wave owns o-tile 32w
    f32x16 acc = {};
    for (int kk = 0; kk < 3; ++kk) {
#pragma unroll
        for (int hs = 0; hs < 8; ++hs) {
            int kstep = kk * 8 + hs;
            bf16x8 a = *(const bf16x8*)&xb[(arow + kk) * 136 + hs * 16 + aks];
            bf16x8 b = *(const bf16x8*)&wc[((w * 24 + kstep) * 64 + lane) * 8];
            acc = __builtin_amdgcn_mfma_f32_32x32x16_bf16(a, b, acc, 0, 0, 0);
        }
    }
    {
        int oc = w * 32 + (lane & 31);
        float cb = conv_b[oc];
#pragma unroll
        for (int r = 0; r < 16; ++r) {
            int t = (r & 3) + 8 * (r >> 2) + 4 * (lane >> 5);
            yb[t * 132 + oc] = acc[r] + cb;
        }
    }
    __syncthreads();

    // phase 2: residual + LN1 -> f32 x1 global + bf16 x1 into xb rows 0..31
    for (int t = w; t < T_STEPS; t += 4) {
        float r0 = x[((size_t)n * T_STEPS + t) * H_DIM + lane] + yb[t * 132 + lane];
        float r1 = x[((size_t)n * T_STEPS + t) * H_DIM + lane + 64] + yb[t * 132 + lane + 64];
        float s = r0 + r1, s2 = r0 * r0 + r1 * r1;
#pragma unroll
        for (int mm = 1; mm < 64; mm <<= 1) {
            s += __shfl_xor(s, mm);
            s2 += __shfl_xor(s2, mm);
        }
        float mean = s * (1.f / 128.f);
        float var = s2 * (1.f / 128.f) - mean * mean;
        float rs = rsqrtf(var + LN_EPS);
        float o0 = (r0 - mean) * rs * ln1_g[lane] + ln1_b[lane];
        float o1 = (r1 - mean) * rs * ln1_g[lane + 64] + ln1_b[lane + 64];
        x1[((size_t)n * T_STEPS + t) * H_DIM + lane] = o0;
        x1[((size_t)n * T_STEPS + t) * H_DIM + lane + 64] = o1;
        xb[t * 136 + lane] = f2bf(o0);
        xb[t * 136 + lane + 64] = f2bf(o1);
    }
    __syncthreads();

    // phase 3: gl/gr = MFMA GEMM [32x128]x[128x256]; wave w owns col-tiles 2w, 2w+1
    f32x16 cl = {}, cr = {};
#pragma unroll
    for (int ks = 0; ks < 8; ++ks) {
        bf16x8 a = *(const bf16x8*)&xb[arow * 136 + ks * 16 + aks];
        bf16x8 b0 = *(const bf16x8*)&wg[(((2 * w) * 8 + ks) * 64 + lane) * 8];
        bf16x8 b1 = *(const bf16x8*)&wg[(((2 * w + 1) * 8 + ks) * 64 + lane) * 8];
        cl = __builtin_amdgcn_mfma_f32_32x32x16_bf16(a, b0, cl, 0, 0, 0);
        cr = __builtin_amdgcn_mfma_f32_32x32x16_bf16(a, b1, cr, 0, 0, 0);
    }
    {
        int o0 = 64 * w + (lane & 31);             // global col in [0,256)
        float* d = (w < 2) ? gl : gr;              // waves 0,1 -> gl; 2,3 -> gr
        int oo0 = (w < 2) ? o0 : o0 - 128;
        int oo1 = oo0 + 32;
#pragma unroll
        for (int r = 0; r < 16; ++r) {
            int t = (r & 3) + 8 * (r >> 2) + 4 * (lane >> 5);
            d[((size_t)t * N_NODES + n) * H_DIM + oo0] = cl[r];
            d[((size_t)t * N_NODES + n) * H_DIM + oo1] = cr[r];
        }
    }
}

// ---------- GATv2: block = (n, 4 graphs g0+8j); folded 4-way reduce + defer-max softmax ----------
__global__ __launch_bounds__(128) void k_gat(
    const float* __restrict__ gl, const float* __restrict__ gr, const float* __restrict__ ee,
    const int* __restrict__ src_arr, const int* __restrict__ csr,
    const int* __restrict__ offs, const int* __restrict__ cnt,
    const float* __restrict__ att, const float* __restrict__ gat_b,
    const float* __restrict__ x1, const float* __restrict__ ln2_g,
    const float* __restrict__ ln2_b, float* __restrict__ out) {
    int bid = blockIdx.x;        // bid = g0*N + n, g0 in [0,8); graphs g0+8j, j=0..3
    int g0 = bid / N_NODES;
    int n = bid - g0 * N_NODES;
    int tid = threadIdx.x;       // channel h; head k = tid>>5

    __shared__ int es[64], ss[64];
    int off = offs[n], deg = cnt[n];
    int tot = deg + 1;  // + self-loop (last)

    float attv = att[tid];
    const float* glp0 = gl + (size_t)(g0)      * N_NODES * H_DIM;
    const float* glp1 = gl + (size_t)(g0 + 8)  * N_NODES * H_DIM;
    const float* glp2 = gl + (size_t)(g0 + 16) * N_NODES * H_DIM;
    const float* glp3 = gl + (size_t)(g0 + 24) * N_NODES * H_DIM;

    float grv[4], m[4], l[4], ac[4];
#pragma unroll
    for (int j = 0; j < 4; ++j) {
        grv[j] = gr[((size_t)(g0 + 8 * j) * N_NODES + n) * H_DIM + tid];
        m[j] = -INFINITY; l[j] = 0.f; ac[j] = 0.f;
    }

    bool hi16 = (tid & 16) != 0;

    for (int base = 0; base < tot; base += 64) {
        int c = min(64, tot - base);
        __syncthreads();
        if (tid < c) {
            int i = base + tid;
            int e = (i < deg) ? csr[off + i] : (E_EDGES + n);
            es[tid] = e;
            ss[tid] = (i < deg) ? src_arr[e] : n;
        }
        __syncthreads();
        for (int i = 0; i < c; ++i) {
            int e = es[i], s = ss[i];
            int co = s * H_DIM + tid;
            float eev = ee[(size_t)e * H_DIM + tid];
            float gv[4];
            gv[0] = glp0[co]; gv[1] = glp1[co]; gv[2] = glp2[co]; gv[3] = glp3[co];
            float p[4];
#pragma unroll
            for (int j = 0; j < 4; ++j) {
                float sf = gv[j] + grv[j] + eev;
                sf = fmaxf(sf, NEG_SLOPE * sf);  // leaky_relu for slope<1
                p[j] = sf * attv;
            }
            // folded 4-way butterfly reduce over the 32 lanes of each head
            float a0 = p[0] + __shfl_xor(p[0], 16);
            float a1 = p[1] + __shfl_xor(p[1], 16);
            float a2 = p[2] + __shfl_xor(p[2], 16);
            float a3 = p[3] + __shfl_xor(p[3], 16);
            float c01 = hi16 ? a1 : a0;
            float c23 = hi16 ? a3 : a2;
#pragma unroll
            for (int mm = 8; mm >= 1; mm >>= 1) {
                c01 += __shfl_xor(c01, mm);
                c23 += __shfl_xor(c23, mm);
            }
            float x01 = __shfl_xor(c01, 16);
            float x23 = __shfl_xor(c23, 16);
            p[0] = hi16 ? x01 : c01;
            p[1] = hi16 ? c01 : x01;
            p[2] = hi16 ? x23 : c23;
            p[3] = hi16 ? c23 : x23;
            // defer-max online softmax: rescale only when some head's max grows by >8
            bool grow = (p[0] > m[0] + 8.f) | (p[1] > m[1] + 8.f) |
                        (p[2] > m[2] + 8.f) | (p[3] > m[3] + 8.f);
            if (__any(grow)) {
#pragma unroll
                for (int j = 0; j < 4; ++j) {
                    float mn = fmaxf(m[j], p[j]);
                    float sc = __expf(m[j] - mn);
                    float wq = __expf(p[j] - mn);
                    l[j] = l[j] * sc + wq;
                    ac[j] = ac[j] * sc + wq * gv[j];
                    m[j] = mn;
                }
            } else {
#pragma unroll
                for (int j = 0; j < 4; ++j) {
                    float wq = __expf(p[j] - m[j]);
                    l[j] += wq;
                    ac[j] += wq * gv[j];
                }
            }
        }
    }

    // epilogue: residual + LN2 per graph
    __shared__ float red[2][4][2];
    int wave = tid >> 6, lane = tid & 63;
    float rv[4];
    float gb = gat_b[tid], g2 = ln2_g[tid], b2 = ln2_b[tid];
#pragma unroll
    for (int j = 0; j < 4; ++j) {
        int g = g0 + 8 * j;
        float ov = ac[j] / l[j] + gb;
        rv[j] = x1[((size_t)n * T_STEPS + g) * H_DIM + tid] + ov;
        float s1 = rv[j], s2v = rv[j] * rv[j];
#pragma unroll
        for (int mm = 1; mm < 64; mm <<= 1) {
            s1 += __shfl_xor(s1, mm);
            s2v += __shfl_xor(s2v, mm);
        }
        if (lane == 0) { red[wave][j][0] = s1; red[wave][j][1] = s2v; }
    }
    __syncthreads();
#pragma unroll
    for (int j = 0; j < 4; ++j) {
        int g = g0 + 8 * j;
        float ts = red[0][j][0] + red[1][j][0];
        float ts2 = red[0][j][1] + red[1][j][1];
        float mean = ts * (1.f / 128.f);
        float var = ts2 * (1.f / 128.f) - mean * mean;
        float rs = rsqrtf(var + LN_EPS);
        out[((size_t)n * T_STEPS + g) * H_DIM + tid] = (rv[j] - mean) * rs * g2 + b2;
    }
}

extern "C" void kernel_launch(void* const* d_in, const int* in_sizes, int n_in,
                              void* d_out, int out_size, void* d_ws, size_t ws_size,
                              hipStream_t stream) {
    const float* x         = (const float*)d_in[0];
    const int*   ei        = (const int*)d_in[1];
    const float* edge_attr = (const float*)d_in[2];
    const float* conv_w    = (const float*)d_in[3];
    const float* conv_b    = (const float*)d_in[4];
    const float* ln1_g     = (const float*)d_in[5];
    const float* ln1_b     = (const float*)d_in[6];
    const float* Wl        = (const float*)d_in[7];
    const float* Wr        = (const float*)d_in[8];
    const float* We        = (const float*)d_in[9];
    const float* att       = (const float*)d_in[10];
    const float* gat_b     = (const float*)d_in[11];
    const float* ln2_g     = (const float*)d_in[12];
    const float* ln2_b     = (const float*)d_in[13];
    float* out = (float*)d_out;

    const int* src = ei;
    const int* dst = ei + E_EDGES;

    // workspace layout
    float* x1  = (float*)d_ws;                 // 4,096,000  [n][t][h]
    float* gl  = x1 + 4096000;                 // 4,096,000  [g][n][h]
    float* gr  = gl + 4096000;                 // 4,096,000  [g][n][h]
    float* eew = gr + 4096000;                 // 2,176,000
    float* la  = eew + 2176000;                // 16,000
    int* ibase = (int*)(la + 16000);
    int* cnt   = ibase;                        // 1000
    int* cnt2  = ibase + 1000;                 // 1000
    int* offs  = ibase + 2000;                 // 1001
    int* csr   = ibase + 3001;                 // 16000 (ends 19001; pad to 19004)
    short* wc  = (short*)(ibase + 19004);      // 49152 shorts (16B aligned)
    short* wg  = wc + 49152;                   // 32768 shorts

    k_pack<<<320, 256, 0, stream>>>(conv_w, Wl, Wr, wc, wg);
    k_countscan<<<1, 1024, 0, stream>>>(dst, cnt, cnt2, offs);
    k_place<<<(E_EDGES + 255) / 256, 256, 0, stream>>>(dst, offs, cnt2, csr);
    k_sortla<<<N_NODES, 64, 0, stream>>>(edge_attr, csr, offs, cnt, la);
    k_ee<<<(EP_EDGES + 1) / 2, 256, 0, stream>>>(edge_attr, la, We, eew);
    k_temporal<<<N_NODES, 256, 0, stream>>>(x, wc, wg, conv_b, ln1_g, ln1_b, x1, gl, gr);
    k_gat<<<8 * N_NODES, 128, 0, stream>>>(gl, gr, eew, src, csr, offs, cnt,
                                           att, gat_b, x1, ln2_g, ln2_b, out);
}

// Round 7
// 127.510 us; speedup vs baseline: 2.7733x; 1.0182x over previous
//
#include <hip/hip_runtime.h>
#include <math.h>

#define N_NODES 1000
#define T_STEPS 32
#define H_DIM   128
#define E_EDGES 16000
#define ED_DIM  16
#define G_GRAPHS 32
#define EP_EDGES (E_EDGES + N_NODES)
#define NEG_SLOPE 0.2f
#define LN_EPS 1e-5f

typedef __attribute__((ext_vector_type(8))) short bf16x8;
typedef __attribute__((ext_vector_type(16))) float f32x16;
typedef unsigned short u16;

__device__ inline short f2bf(float f) {  // RNE f32 -> bf16
    unsigned u = __float_as_uint(f);
    u = (u + 0x7FFFu + ((u >> 16) & 1u)) >> 16;
    return (short)u;
}
__device__ inline float bf2f(u16 u) { return __uint_as_float(((unsigned)u) << 16); }

// ---------- pack conv_w + Wl/Wr into MFMA-B fragment order (one kernel) ----------
// wc[ct(4)][kstep(24)][lane(64)][r(8)]: B[kk][o], kk=k*128+hi; hi=hs*16+(lane>>5)*8+r, o=ct*32+(lane&31)
// wg[ct(8)][ks(8)][lane(64)][r(8)]: ct 0-3 = Wl cols, 4-7 = Wr
__global__ void k_pack(const float* __restrict__ conv_w, const float* __restrict__ Wl,
                       const float* __restrict__ Wr, short* __restrict__ wc,
                       short* __restrict__ wg) {
    int i = blockIdx.x * 256 + threadIdx.x;
    if (i < 4 * 24 * 64 * 8) {
        int r = i & 7, lane = (i >> 3) & 63;
        int t = i >> 9;
        int kstep = t % 24, ct = t / 24;
        int k = kstep >> 3, hs = kstep & 7;
        int hi = hs * 16 + ((lane >> 5) << 3) + r;
        int o = ct * 32 + (lane & 31);
        wc[i] = f2bf(conv_w[(o * H_DIM + hi) * 3 + k]);
    } else {
        int j = i - 4 * 24 * 64 * 8;
        if (j >= 8 * 8 * 64 * 8) return;
        int r = j & 7, lane = (j >> 3) & 63;
        int ks = (j >> 9) & 7, ct = j >> 12;
        int hi = ks * 16 + ((lane >> 5) << 3) + r;
        int o = ct * 32 + (lane & 31);
        wg[j] = f2bf(o < H_DIM ? Wl[hi * H_DIM + o] : Wr[hi * H_DIM + o - H_DIM]);
    }
}

// ---------- count + exclusive scan in ONE block (LDS atomics), also zero cnt2 ----------
__global__ __launch_bounds__(1024) void k_countscan(const int* __restrict__ dst,
                                                    int* __restrict__ cnt, int* __restrict__ cnt2,
                                                    int* __restrict__ offs) {
    __shared__ int sm[1024];
    int t = threadIdx.x;
    sm[t] = 0;
    __syncthreads();
    for (int e = t; e < E_EDGES; e += 1024) atomicAdd(&sm[dst[e]], 1);
    __syncthreads();
    int v = (t < N_NODES) ? sm[t] : 0;
    if (t < N_NODES) { cnt[t] = v; cnt2[t] = 0; }
    __syncthreads();
    sm[t] = v;
    for (int s = 1; s < 1024; s <<= 1) {
        __syncthreads();
        int a = (t >= s) ? sm[t - s] : 0;
        __syncthreads();
        sm[t] += a;
    }
    __syncthreads();
    if (t < N_NODES) offs[t + 1] = sm[t];
    if (t == 0) offs[0] = 0;
}

// ---------- placement: slot via atomic (order fixed by sort below) ----------
__global__ void k_place(const int* __restrict__ dst, const int* __restrict__ offs,
                        int* __restrict__ cnt2, int* __restrict__ csr) {
    int e = blockIdx.x * 256 + threadIdx.x;
    if (e >= E_EDGES) return;
    int d = dst[e];
    int slot = atomicAdd(&cnt2[d], 1);
    csr[offs[d] + slot] = e;
}

// ---------- per-node: sort CSR segment ascending (deterministic) + loop_attr mean ----------
__global__ __launch_bounds__(64) void k_sortla(
    const float* __restrict__ edge_attr, int* __restrict__ csr,
    const int* __restrict__ offs, const int* __restrict__ cnt,
    float* __restrict__ loop_attr) {
    __shared__ int buf[128];
    int n = blockIdx.x;
    int lane = threadIdx.x;  // 64
    int off = offs[n], deg = cnt[n];

    if (deg <= 64) {
        int v = (lane < deg) ? csr[off + lane] : 0x7FFFFFFF;
        int rank = 0;
#pragma unroll
        for (int j = 0; j < 64; ++j) {
            int vj = __shfl(v, j);
            rank += (vj < v) ? 1 : 0;
        }
        if (lane < deg) buf[rank] = v;
    } else {  // cold path: deg in (64,128]
        for (int i = lane; i < deg && i < 128; i += 64) buf[i] = csr[off + i];
        __syncthreads();
        if (lane == 0) {
            int dd = deg < 128 ? deg : 128;
            for (int i = 1; i < dd; ++i) {
                int key = buf[i], j = i - 1;
                while (j >= 0 && buf[j] > key) { buf[j + 1] = buf[j]; --j; }
                buf[j + 1] = key;
            }
        }
    }
    __syncthreads();
    if (lane < deg) csr[off + lane] = buf[lane];

    int q = lane >> 4, f = lane & 15;
    float a = 0.f;
    for (int i = q; i < deg; i += 4) a += edge_attr[buf[i] * ED_DIM + f];
    a += __shfl_xor(a, 16);
    a += __shfl_xor(a, 32);
    if (lane < 16) loop_attr[n * ED_DIM + lane] = a / fmaxf((float)deg, 1.0f);
}

// ---------- ee[e][h] = ea[e] @ We (bf16 out), for all E+N edges ----------
__global__ void k_ee(const float* __restrict__ edge_attr, const float* __restrict__ loop_attr,
                     const float* __restrict__ We, u16* __restrict__ ee) {
    int e = blockIdx.x * 2 + (threadIdx.x >> 7);
    int h = threadIdx.x & 127;
    if (e >= EP_EDGES) return;
    const float* ea = (e < E_EDGES) ? &edge_attr[e * ED_DIM]
                                    : &loop_attr[(e - E_EDGES) * ED_DIM];
    float acc = 0.f;
#pragma unroll
    for (int f = 0; f < ED_DIM; ++f) acc += ea[f] * We[f * H_DIM + h];
    ee[e * H_DIM + h] = (u16)f2bf(acc);
}

// ---------- fused temporal: conv (MFMA) + residual + LN1 + gl/gr (MFMA, bf16 out) ----------
__global__ __launch_bounds__(256) void k_temporal(
    const float* __restrict__ x, const short* __restrict__ wc, const short* __restrict__ wg,
    const float* __restrict__ conv_b, const float* __restrict__ ln1_g,
    const float* __restrict__ ln1_b, float* __restrict__ x1,
    u16* __restrict__ gl, u16* __restrict__ gr) {
    __shared__ __align__(16) short xb[34 * 136];  // bf16; row r = x[r-1][.], rows 0 & 33 zero
    __shared__ float yb[32 * 132];                // conv output (f32)
    int n = blockIdx.x;
    int tid = threadIdx.x;
    int w = tid >> 6, lane = tid & 63;
    int arow = lane & 31;        // MFMA A row (t)
    int aks = (lane >> 5) << 3;  // k-slice base within 16

    // phase 0: x -> bf16 transposed-in-time LDS with halo rows
    {
        const float4* xs4 = (const float4*)(x + (size_t)n * T_STEPS * H_DIM);
        for (int i4 = tid; i4 < T_STEPS * H_DIM / 4; i4 += 256) {
            float4 v = xs4[i4];
            int t = i4 >> 5, h = (i4 * 4) & 127;
            uint2 pp;
            pp.x = (unsigned)(unsigned short)f2bf(v.x) | ((unsigned)(unsigned short)f2bf(v.y) << 16);
            pp.y = (unsigned)(unsigned short)f2bf(v.z) | ((unsigned)(unsigned short)f2bf(v.w) << 16);
            *(uint2*)&xb[(t + 1) * 136 + h] = pp;
        }
        if (tid < 68) {
            ((unsigned*)xb)[tid] = 0u;
            ((unsigned*)(xb + 33 * 136))[tid] = 0u;
        }
    }
    __syncthreads();

    // phase 1: conv = MFMA GEMM, Y[32][128], K=384 (kk = k*128 + hi); wave owns o-tile 32w
    f32x16 acc = {};
    for (int kk = 0; kk < 3; ++kk) {
#pragma unroll
        for (int hs = 0; hs < 8; ++hs) {
            int kstep = kk * 8 + hs;
            bf16x8 a = *(const bf16x8*)&xb[(arow + kk) * 136 + hs * 16 + aks];
            bf16x8 b = *(const bf16x8*)&wc[((w * 24 + kstep) * 64 + lane) * 8];
            acc = __builtin_amdgcn_mfma_f32_32x32x16_bf16(a, b, acc, 0, 0, 0);
        }
    }
    {
        int oc = w * 32 + (lane & 31);
        float cb = conv_b[oc];
#pragma unroll
        for (int r = 0; r < 16; ++r) {
            int t = (r & 3) + 8 * (r >> 2) + 4 * (lane >> 5);
            yb[t * 132 + oc] = acc[r] + cb;
        }
    }
    __syncthreads();

    // phase 2: residual + LN1 -> f32 x1 global + bf16 x1 into xb rows 0..31
    for (int t = w; t < T_STEPS; t += 4) {
        float r0 = x[((size_t)n * T_STEPS + t) * H_DIM + lane] + yb[t * 132 + lane];
        float r1 = x[((size_t)n * T_STEPS + t) * H_DIM + lane + 64] + yb[t * 132 + lane + 64];
        float s = r0 + r1, s2 = r0 * r0 + r1 * r1;
#pragma unroll
        for (int mm = 1; mm < 64; mm <<= 1) {
            s += __shfl_xor(s, mm);
            s2 += __shfl_xor(s2, mm);
        }
        float mean = s * (1.f / 128.f);
        float var = s2 * (1.f / 128.f) - mean * mean;
        float rs = rsqrtf(var + LN_EPS);
        float o0 = (r0 - mean) * rs * ln1_g[lane] + ln1_b[lane];
        float o1 = (r1 - mean) * rs * ln1_g[lane + 64] + ln1_b[lane + 64];
        x1[((size_t)n * T_STEPS + t) * H_DIM + lane] = o0;
        x1[((size_t)n * T_STEPS + t) * H_DIM + lane + 64] = o1;
        xb[t * 136 + lane] = f2bf(o0);
        xb[t * 136 + lane + 64] = f2bf(o1);
    }
    __syncthreads();

    // phase 3: gl/gr = MFMA GEMM [32x128]x[128x256], bf16 stores [g][n][h]
    f32x16 cl = {}, cr = {};
#pragma unroll
    for (int ks = 0; ks < 8; ++ks) {
        bf16x8 a = *(const bf16x8*)&xb[arow * 136 + ks * 16 + aks];
        bf16x8 b0 = *(const bf16x8*)&wg[(((2 * w) * 8 + ks) * 64 + lane) * 8];
        bf16x8 b1 = *(const bf16x8*)&wg[(((2 * w + 1) * 8 + ks) * 64 + lane) * 8];
        cl = __builtin_amdgcn_mfma_f32_32x32x16_bf16(a, b0, cl, 0, 0, 0);
        cr = __builtin_amdgcn_mfma_f32_32x32x16_bf16(a, b1, cr, 0, 0, 0);
    }
    {
        int o0 = 64 * w + (lane & 31);             // global col in [0,256)
        u16* d = (w < 2) ? gl : gr;                // waves 0,1 -> gl; 2,3 -> gr
        int oo0 = (w < 2) ? o0 : o0 - 128;
        int oo1 = oo0 + 32;
#pragma unroll
        for (int r = 0; r < 16; ++r) {
            int t = (r & 3) + 8 * (r >> 2) + 4 * (lane >> 5);
            d[((size_t)t * N_NODES + n) * H_DIM + oo0] = (u16)f2bf(cl[r]);
            d[((size_t)t * N_NODES + n) * H_DIM + oo1] = (u16)f2bf(cr[r]);
        }
    }
}

// ---------- GATv2: block = (n, 4 graphs g0+8j); bid n-major so XCD == g0 (pinned slices) ----------
__global__ __launch_bounds__(128) void k_gat(
    const u16* __restrict__ gl, const u16* __restrict__ gr, const u16* __restrict__ ee,
    const int* __restrict__ src_arr, const int* __restrict__ csr,
    const int* __restrict__ offs, const int* __restrict__ cnt,
    const float* __restrict__ att, const float* __restrict__ gat_b,
    const float* __restrict__ x1, const float* __restrict__ ln2_g,
    const float* __restrict__ ln2_b, float* __restrict__ out) {
    int bid = blockIdx.x;        // bid = n*8 + g0 -> XCD = bid%8 = g0: gl slices pinned per XCD,
    int g0 = bid & 7;            // ee streamed in n-order exactly once per XCD
    int n = bid >> 3;
    int tid = threadIdx.x;       // channel h; head k = tid>>5

    __shared__ int es[64], ss[64];
    int off = offs[n], deg = cnt[n];
    int tot = deg + 1;  // + self-loop (last)

    float attv = att[tid];
    const u16* glp0 = gl + (size_t)(g0)      * N_NODES * H_DIM + tid;
    const u16* glp1 = gl + (size_t)(g0 + 8)  * N_NODES * H_DIM + tid;
    const u16* glp2 = gl + (size_t)(g0 + 16) * N_NODES * H_DIM + tid;
    const u16* glp3 = gl + (size_t)(g0 + 24) * N_NODES * H_DIM + tid;

    float grv[4], m[4], l[4], ac[4];
#pragma unroll
    for (int j = 0; j < 4; ++j) {
        grv[j] = bf2f(__builtin_nontemporal_load(
            &gr[((size_t)(g0 + 8 * j) * N_NODES + n) * H_DIM + tid]));
        m[j] = -INFINITY; l[j] = 0.f; ac[j] = 0.f;
    }

    bool hi16 = (tid & 16) != 0;

    for (int base = 0; base < tot; base += 64) {
        int c = min(64, tot - base);
        __syncthreads();
        if (tid < c) {
            int i = base + tid;
            int e = (i < deg) ? csr[off + i] : (E_EDGES + n);
            es[tid] = e;
            ss[tid] = (i < deg) ? src_arr[e] : n;
        }
        __syncthreads();
        for (int i = 0; i < c; ++i) {
            int e = es[i], s = ss[i];
            int co = s * H_DIM;
            float eev = bf2f(ee[(size_t)e * H_DIM + tid]);
            float gv[4];
            gv[0] = bf2f(glp0[co]); gv[1] = bf2f(glp1[co]);
            gv[2] = bf2f(glp2[co]); gv[3] = bf2f(glp3[co]);
            float p[4];
#pragma unroll
            for (int j = 0; j < 4; ++j) {
                float sf = gv[j] + grv[j] + eev;
                sf = fmaxf(sf, NEG_SLOPE * sf);  // leaky_relu for slope<1
                p[j] = sf * attv;
            }
            // folded 4-way butterfly reduce over the 32 lanes of each head
            float a0 = p[0] + __shfl_xor(p[0], 16);
            float a1 = p[1] + __shfl_xor(p[1], 16);
            float a2 = p[2] + __shfl_xor(p[2], 16);
            float a3 = p[3] + __shfl_xor(p[3], 16);
            float c01 = hi16 ? a1 : a0;
            float c23 = hi16 ? a3 : a2;
#pragma unroll
            for (int mm = 8; mm >= 1; mm >>= 1) {
                c01 += __shfl_xor(c01, mm);
                c23 += __shfl_xor(c23, mm);
            }
            float x01 = __shfl_xor(c01, 16);
            float x23 = __shfl_xor(c23, 16);
            p[0] = hi16 ? x01 : c01;
            p[1] = hi16 ? c01 : x01;
            p[2] = hi16 ? x23 : c23;
            p[3] = hi16 ? c23 : x23;
            // defer-max online softmax: rescale only when some head's max grows by >8
            bool grow = (p[0] > m[0] + 8.f) | (p[1] > m[1] + 8.f) |
                        (p[2] > m[2] + 8.f) | (p[3] > m[3] + 8.f);
            if (__any(grow)) {
#pragma unroll
                for (int j = 0; j < 4; ++j) {
                    float mn = fmaxf(m[j], p[j]);
                    float sc = __expf(m[j] - mn);
                    float wq = __expf(p[j] - mn);
                    l[j] = l[j] * sc + wq;
                    ac[j] = ac[j] * sc + wq * gv[j];
                    m[j] = mn;
                }
            } else {
#pragma unroll
                for (int j = 0; j < 4; ++j) {
                    float wq = __expf(p[j] - m[j]);
                    l[j] += wq;
                    ac[j] += wq * gv[j];
                }
            }
        }
    }

    // epilogue: residual + LN2 per graph (nontemporal streams)
    __shared__ float red[2][4][2];
    int wave = tid >> 6, lane = tid & 63;
    float rv[4];
    float gb = gat_b[tid], g2 = ln2_g[tid], b2 = ln2_b[tid];
#pragma unroll
    for (int j = 0; j < 4; ++j) {
        int g = g0 + 8 * j;
        float ov = ac[j] / l[j] + gb;
        rv[j] = __builtin_nontemporal_load(&x1[((size_t)n * T_STEPS + g) * H_DIM + tid]) + ov;
        float s1 = rv[j], s2v = rv[j] * rv[j];
#pragma unroll
        for (int mm = 1; mm < 64; mm <<= 1) {
            s1 += __shfl_xor(s1, mm);
            s2v += __shfl_xor(s2v, mm);
        }
        if (lane == 0) { red[wave][j][0] = s1; red[wave][j][1] = s2v; }
    }
    __syncthreads();
#pragma unroll
    for (int j = 0; j < 4; ++j) {
        int g = g0 + 8 * j;
        float ts = red[0][j][0] + red[1][j][0];
        float ts2 = red[0][j][1] + red[1][j][1];
        float mean = ts * (1.f / 128.f);
        float var = ts2 * (1.f / 128.f) - mean * mean;
        float rs = rsqrtf(var + LN_EPS);
        __builtin_nontemporal_store((rv[j] - mean) * rs * g2 + b2,
                                    &out[((size_t)n * T_STEPS + g) * H_DIM + tid]);
    }
}

extern "C" void kernel_launch(void* const* d_in, const int* in_sizes, int n_in,
                              void* d_out, int out_size, void* d_ws, size_t ws_size,
                              hipStream_t stream) {
    const float* x         = (const float*)d_in[0];
    const int*   ei        = (const int*)d_in[1];
    const float* edge_attr = (const float*)d_in[2];
    const float* conv_w    = (const float*)d_in[3];
    const float* conv_b    = (const float*)d_in[4];
    const float* ln1_g     = (const float*)d_in[5];
    const float* ln1_b     = (const float*)d_in[6];
    const float* Wl        = (const float*)d_in[7];
    const float* Wr        = (const float*)d_in[8];
    const float* We        = (const float*)d_in[9];
    const float* att       = (const float*)d_in[10];
    const float* gat_b     = (const float*)d_in[11];
    const float* ln2_g     = (const float*)d_in[12];
    const float* ln2_b     = (const float*)d_in[13];
    float* out = (float*)d_out;

    const int* src = ei;
    const int* dst = ei + E_EDGES;

    // workspace layout
    float* x1   = (float*)d_ws;                 // 4,096,000 f32  [n][t][h]
    u16*   glb  = (u16*)(x1 + 4096000);         // 4,096,000 bf16 [g][n][h]
    u16*   grb  = glb + 4096000;                // 4,096,000 bf16 [g][n][h]
    u16*   eeb  = grb + 4096000;                // 2,176,000 bf16
    float* la   = (float*)(eeb + 2176000);      // 16,000 f32
    int* ibase  = (int*)(la + 16000);
    int* cnt    = ibase;                        // 1000
    int* cnt2   = ibase + 1000;                 // 1000
    int* offs   = ibase + 2000;                 // 1001
    int* csr    = ibase + 3001;                 // 16000 (ends 19001; pad to 19008)
    short* wc   = (short*)(ibase + 19008);      // 49152 shorts (16B aligned)
    short* wg   = wc + 49152;                   // 32768 shorts

    k_pack<<<320, 256, 0, stream>>>(conv_w, Wl, Wr, wc, wg);
    k_countscan<<<1, 1024, 0, stream>>>(dst, cnt, cnt2, offs);
    k_place<<<(E_EDGES + 255) / 256, 256, 0, stream>>>(dst, offs, cnt2, csr);
    k_sortla<<<N_NODES, 64, 0, stream>>>(edge_attr, csr, offs, cnt, la);
    k_ee<<<(EP_EDGES + 1) / 2, 256, 0, stream>>>(edge_attr, la, We, eeb);
    k_temporal<<<N_NODES, 256, 0, stream>>>(x, wc, wg, conv_b, ln1_g, ln1_b, x1, glb, grb);
    k_gat<<<8 * N_NODES, 128, 0, stream>>>(glb, grb, eeb, src, csr, offs, cnt,
                                           att, gat_b, x1, ln2_g, ln2_b, out);
}

// Round 9
// 92.968 us; speedup vs baseline: 3.8037x; 1.3715x over previous
//
#include <hip/hip_runtime.h>
#include <math.h>

#define N_NODES 1000
#define T_STEPS 32
#define H_DIM   128
#define E_EDGES 16000
#define ED_DIM  16
#define G_GRAPHS 32
#define EP_EDGES (E_EDGES + N_NODES)
#define NEG_SLOPE 0.2f
#define LN_EPS 1e-5f

typedef __attribute__((ext_vector_type(8))) short bf16x8;
typedef __attribute__((ext_vector_type(16))) float f32x16;
typedef __attribute__((ext_vector_type(4))) float f32x4;
typedef unsigned short u16;

__device__ inline short f2bf(float f) {  // RNE f32 -> bf16
    unsigned u = __float_as_uint(f);
    u = (u + 0x7FFFu + ((u >> 16) & 1u)) >> 16;
    return (short)u;
}
__device__ inline float bf2f(u16 u) { return __uint_as_float(((unsigned)u) << 16); }
__device__ inline float bflo(unsigned u) { return __uint_as_float(u << 16); }
__device__ inline float bfhi(unsigned u) { return __uint_as_float(u & 0xFFFF0000u); }

// ---------- pack conv_w + Wl/Wr into MFMA-B fragment order (one kernel) ----------
__global__ void k_pack(const float* __restrict__ conv_w, const float* __restrict__ Wl,
                       const float* __restrict__ Wr, short* __restrict__ wc,
                       short* __restrict__ wg) {
    int i = blockIdx.x * 256 + threadIdx.x;
    if (i < 4 * 24 * 64 * 8) {
        int r = i & 7, lane = (i >> 3) & 63;
        int t = i >> 9;
        int kstep = t % 24, ct = t / 24;
        int k = kstep >> 3, hs = kstep & 7;
        int hi = hs * 16 + ((lane >> 5) << 3) + r;
        int o = ct * 32 + (lane & 31);
        wc[i] = f2bf(conv_w[(o * H_DIM + hi) * 3 + k]);
    } else {
        int j = i - 4 * 24 * 64 * 8;
        if (j >= 8 * 8 * 64 * 8) return;
        int r = j & 7, lane = (j >> 3) & 63;
        int ks = (j >> 9) & 7, ct = j >> 12;
        int hi = ks * 16 + ((lane >> 5) << 3) + r;
        int o = ct * 32 + (lane & 31);
        wg[j] = f2bf(o < H_DIM ? Wl[hi * H_DIM + o] : Wr[hi * H_DIM + o - H_DIM]);
    }
}

// ---------- count + exclusive scan in ONE block (LDS atomics), also zero cnt2 ----------
__global__ __launch_bounds__(1024) void k_countscan(const int* __restrict__ dst,
                                                    int* __restrict__ cnt, int* __restrict__ cnt2,
                                                    int* __restrict__ offs) {
    __shared__ int sm[1024];
    int t = threadIdx.x;
    sm[t] = 0;
    __syncthreads();
    for (int e = t; e < E_EDGES; e += 1024) atomicAdd(&sm[dst[e]], 1);
    __syncthreads();
    int v = (t < N_NODES) ? sm[t] : 0;
    if (t < N_NODES) { cnt[t] = v; cnt2[t] = 0; }
    __syncthreads();
    sm[t] = v;
    for (int s = 1; s < 1024; s <<= 1) {
        __syncthreads();
        int a = (t >= s) ? sm[t - s] : 0;
        __syncthreads();
        sm[t] += a;
    }
    __syncthreads();
    if (t < N_NODES) offs[t + 1] = sm[t];
    if (t == 0) offs[0] = 0;
}

// ---------- placement: slot via atomic (order fixed by sort below) ----------
__global__ void k_place(const int* __restrict__ dst, const int* __restrict__ offs,
                        int* __restrict__ cnt2, int* __restrict__ csr) {
    int e = blockIdx.x * 256 + threadIdx.x;
    if (e >= E_EDGES) return;
    int d = dst[e];
    int slot = atomicAdd(&cnt2[d], 1);
    csr[offs[d] + slot] = e;
}

// ---------- per-node: sort CSR segment ascending (deterministic) + loop_attr mean ----------
__global__ __launch_bounds__(64) void k_sortla(
    const float* __restrict__ edge_attr, int* __restrict__ csr,
    const int* __restrict__ offs, const int* __restrict__ cnt,
    float* __restrict__ loop_attr) {
    __shared__ int buf[128];
    int n = blockIdx.x;
    int lane = threadIdx.x;  // 64
    int off = offs[n], deg = cnt[n];

    if (deg <= 64) {
        int v = (lane < deg) ? csr[off + lane] : 0x7FFFFFFF;
        int rank = 0;
#pragma unroll
        for (int j = 0; j < 64; ++j) {
            int vj = __shfl(v, j);
            rank += (vj < v) ? 1 : 0;
        }
        if (lane < deg) buf[rank] = v;
    } else {  // cold path: deg in (64,128]
        for (int i = lane; i < deg && i < 128; i += 64) buf[i] = csr[off + i];
        __syncthreads();
        if (lane == 0) {
            int dd = deg < 128 ? deg : 128;
            for (int i = 1; i < dd; ++i) {
                int key = buf[i], j = i - 1;
                while (j >= 0 && buf[j] > key) { buf[j + 1] = buf[j]; --j; }
                buf[j + 1] = key;
            }
        }
    }
    __syncthreads();
    if (lane < deg) csr[off + lane] = buf[lane];

    int q = lane >> 4, f = lane & 15;
    float a = 0.f;
    for (int i = q; i < deg; i += 4) a += edge_attr[buf[i] * ED_DIM + f];
    a += __shfl_xor(a, 16);
    a += __shfl_xor(a, 32);
    if (lane < 16) loop_attr[n * ED_DIM + lane] = a / fmaxf((float)deg, 1.0f);
}

// ---------- ee[e][h] = ea[e] @ We (bf16 out), for all E+N edges ----------
__global__ void k_ee(const float* __restrict__ edge_attr, const float* __restrict__ loop_attr,
                     const float* __restrict__ We, u16* __restrict__ ee) {
    int e = blockIdx.x * 2 + (threadIdx.x >> 7);
    int h = threadIdx.x & 127;
    if (e >= EP_EDGES) return;
    const float* ea = (e < E_EDGES) ? &edge_attr[e * ED_DIM]
                                    : &loop_attr[(e - E_EDGES) * ED_DIM];
    float acc = 0.f;
#pragma unroll
    for (int f = 0; f < ED_DIM; ++f) acc += ea[f] * We[f * H_DIM + h];
    ee[e * H_DIM + h] = (u16)f2bf(acc);
}

// ---------- fused temporal: conv (MFMA) + residual + LN1 + gl/gr (MFMA, bf16 out) ----------
__global__ __launch_bounds__(256) void k_temporal(
    const float* __restrict__ x, const short* __restrict__ wc, const short* __restrict__ wg,
    const float* __restrict__ conv_b, const float* __restrict__ ln1_g,
    const float* __restrict__ ln1_b, float* __restrict__ x1,
    u16* __restrict__ gl, u16* __restrict__ gr) {
    __shared__ __align__(16) short xb[34 * 136];  // bf16; row r = x[r-1][.], rows 0 & 33 zero
    __shared__ float yb[32 * 132];                // conv output (f32)
    int n = blockIdx.x;
    int tid = threadIdx.x;
    int w = tid >> 6, lane = tid & 63;
    int arow = lane & 31;        // MFMA A row (t)
    int aks = (lane >> 5) << 3;  // k-slice base within 16

    // phase 0: x -> bf16 transposed-in-time LDS with halo rows
    {
        const float4* xs4 = (const float4*)(x + (size_t)n * T_STEPS * H_DIM);
        for (int i4 = tid; i4 < T_STEPS * H_DIM / 4; i4 += 256) {
            float4 v = xs4[i4];
            int t = i4 >> 5, h = (i4 * 4) & 127;
            uint2 pp;
            pp.x = (unsigned)(unsigned short)f2bf(v.x) | ((unsigned)(unsigned short)f2bf(v.y) << 16);
            pp.y = (unsigned)(unsigned short)f2bf(v.z) | ((unsigned)(unsigned short)f2bf(v.w) << 16);
            *(uint2*)&xb[(t + 1) * 136 + h] = pp;
        }
        if (tid < 68) {
            ((unsigned*)xb)[tid] = 0u;
            ((unsigned*)(xb + 33 * 136))[tid] = 0u;
        }
    }
    __syncthreads();

    // phase 1: conv = MFMA GEMM, Y[32][128], K=384 (kk = k*128 + hi); wave owns o-tile 32w
    f32x16 acc = {};
    for (int kk = 0; kk < 3; ++kk) {
#pragma unroll
        for (int hs = 0; hs < 8; ++hs) {
            int kstep = kk * 8 + hs;
            bf16x8 a = *(const bf16x8*)&xb[(arow + kk) * 136 + hs * 16 + aks];
            bf16x8 b = *(const bf16x8*)&wc[((w * 24 + kstep) * 64 + lane) * 8];
            acc = __builtin_amdgcn_mfma_f32_32x32x16_bf16(a, b, acc, 0, 0, 0);
        }
    }
    {
        int oc = w * 32 + (lane & 31);
        float cb = conv_b[oc];
#pragma unroll
        for (int r = 0; r < 16; ++r) {
            int t = (r & 3) + 8 * (r >> 2) + 4 * (lane >> 5);
            yb[t * 132 + oc] = acc[r] + cb;
        }
    }
    __syncthreads();

    // phase 2: residual + LN1 -> f32 x1 global + bf16 x1 into xb rows 0..31
    for (int t = w; t < T_STEPS; t += 4) {
        float r0 = x[((size_t)n * T_STEPS + t) * H_DIM + lane] + yb[t * 132 + lane];
        float r1 = x[((size_t)n * T_STEPS + t) * H_DIM + lane + 64] + yb[t * 132 + lane + 64];
        float s = r0 + r1, s2 = r0 * r0 + r1 * r1;
#pragma unroll
        for (int mm = 1; mm < 64; mm <<= 1) {
            s += __shfl_xor(s, mm);
            s2 += __shfl_xor(s2, mm);
        }
        float mean = s * (1.f / 128.f);
        float var = s2 * (1.f / 128.f) - mean * mean;
        float rs = rsqrtf(var + LN_EPS);
        float o0 = (r0 - mean) * rs * ln1_g[lane] + ln1_b[lane];
        float o1 = (r1 - mean) * rs * ln1_g[lane + 64] + ln1_b[lane + 64];
        x1[((size_t)n * T_STEPS + t) * H_DIM + lane] = o0;
        x1[((size_t)n * T_STEPS + t) * H_DIM + lane + 64] = o1;
        xb[t * 136 + lane] = f2bf(o0);
        xb[t * 136 + lane + 64] = f2bf(o1);
    }
    __syncthreads();

    // phase 3: gl/gr = MFMA GEMM [32x128]x[128x256], bf16 stores [g][n][h]
    f32x16 cl = {}, cr = {};
#pragma unroll
    for (int ks = 0; ks < 8; ++ks) {
        bf16x8 a = *(const bf16x8*)&xb[arow * 136 + ks * 16 + aks];
        bf16x8 b0 = *(const bf16x8*)&wg[(((2 * w) * 8 + ks) * 64 + lane) * 8];
        bf16x8 b1 = *(const bf16x8*)&wg[(((2 * w + 1) * 8 + ks) * 64 + lane) * 8];
        cl = __builtin_amdgcn_mfma_f32_32x32x16_bf16(a, b0, cl, 0, 0, 0);
        cr = __builtin_amdgcn_mfma_f32_32x32x16_bf16(a, b1, cr, 0, 0, 0);
    }
    {
        int o0 = 64 * w + (lane & 31);             // global col in [0,256)
        u16* d = (w < 2) ? gl : gr;                // waves 0,1 -> gl; 2,3 -> gr
        int oo0 = (w < 2) ? o0 : o0 - 128;
        int oo1 = oo0 + 32;
#pragma unroll
        for (int r = 0; r < 16; ++r) {
            int t = (r & 3) + 8 * (r >> 2) + 4 * (lane >> 5);
            d[((size_t)t * N_NODES + n) * H_DIM + oo0] = (u16)f2bf(cl[r]);
            d[((size_t)t * N_NODES + n) * H_DIM + oo1] = (u16)f2bf(cr[r]);
        }
    }
}

// ---------- GATv2: block=(n, 4 graphs g0+8j), lane=(g-slot, head, d-octet) serial-d ----------
// lane tid: gs=tid>>5 (graph slot), k=(tid&31)>>3, d8=tid&7 -> owns h0=k*32+d8*4 .. +3 of graph
// g0+8*gs. Per edge: 8B gl + 8B ee loads, 4-wide elementwise, 3-step shfl reduce over d8 lanes.
__global__ __launch_bounds__(128) void k_gat(
    const u16* __restrict__ gl, const u16* __restrict__ gr, const u16* __restrict__ ee,
    const int* __restrict__ src_arr, const int* __restrict__ csr,
    const int* __restrict__ offs, const int* __restrict__ cnt,
    const float* __restrict__ att, const float* __restrict__ gat_b,
    const float* __restrict__ x1, const float* __restrict__ ln2_g,
    const float* __restrict__ ln2_b, float* __restrict__ out) {
    int bid = blockIdx.x;        // bid = n*8 + g0 -> XCD = bid%8 = g0: gl slices pinned per XCD
    int g0 = bid & 7;
    int n = bid >> 3;
    int tid = threadIdx.x;
    int gs = tid >> 5;
    int r = tid & 31;
    int h0 = ((r >> 3) << 5) + ((r & 7) << 2);  // k*32 + d8*4
    int g = g0 + 8 * gs;

    __shared__ int es[64], ss[64];
    int off = offs[n], deg = cnt[n];
    int tot = deg + 1;  // + self-loop (last)

    // preload per-lane constants
    float4 attv = *(const float4*)&att[h0];
    uint2 gr2 = *(const uint2*)&gr[((size_t)g * N_NODES + n) * H_DIM + h0];
    float gr_0 = bflo(gr2.x), gr_1 = bfhi(gr2.x), gr_2 = bflo(gr2.y), gr_3 = bfhi(gr2.y);

    const u16* glg = gl + (size_t)g * N_NODES * H_DIM + h0;
    const u16* eeh = ee + h0;

    float m = -INFINITY, l = 0.f;
    float ac0 = 0.f, ac1 = 0.f, ac2 = 0.f, ac3 = 0.f;

    for (int base = 0; base < tot; base += 64) {
        int c = min(64, tot - base);
        __syncthreads();
        if (tid < c) {
            int i = base + tid;
            int e = (i < deg) ? csr[off + i] : (E_EDGES + n);
            es[tid] = e;
            ss[tid] = (i < deg) ? src_arr[e] : n;
        }
        __syncthreads();
        uint2 gv2 = *(const uint2*)&glg[(size_t)ss[0] * H_DIM];
        uint2 ev2 = *(const uint2*)&eeh[(size_t)es[0] * H_DIM];
        for (int i = 0; i < c; ++i) {
            uint2 gc = gv2, ec = ev2;
            if (i + 1 < c) {
                gv2 = *(const uint2*)&glg[(size_t)ss[i + 1] * H_DIM];
                ev2 = *(const uint2*)&eeh[(size_t)es[i + 1] * H_DIM];
            }
            float gv0 = bflo(gc.x), gv1 = bfhi(gc.x), gv2f = bflo(gc.y), gv3 = bfhi(gc.y);
            float sf0 = gv0 + gr_0 + bflo(ec.x);
            float sf1 = gv1 + gr_1 + bfhi(ec.x);
            float sf2 = gv2f + gr_2 + bflo(ec.y);
            float sf3 = gv3 + gr_3 + bfhi(ec.y);
            sf0 = fmaxf(sf0, NEG_SLOPE * sf0);
            sf1 = fmaxf(sf1, NEG_SLOPE * sf1);
            sf2 = fmaxf(sf2, NEG_SLOPE * sf2);
            sf3 = fmaxf(sf3, NEG_SLOPE * sf3);
            float p = sf0 * attv.x + sf1 * attv.y + sf2 * attv.z + sf3 * attv.w;
            p += __shfl_xor(p, 1);
            p += __shfl_xor(p, 2);
            p += __shfl_xor(p, 4);
            // defer-max online softmax
            bool grow = p > m + 8.f;
            if (__any(grow)) {
                float mn = fmaxf(m, p);
                float sc = __expf(m - mn);
                float wq = __expf(p - mn);
                l = l * sc + wq;
                ac0 = ac0 * sc + wq * gv0;
                ac1 = ac1 * sc + wq * gv1;
                ac2 = ac2 * sc + wq * gv2f;
                ac3 = ac3 * sc + wq * gv3;
                m = mn;
            } else {
                float wq = __expf(p - m);
                l += wq;
                ac0 += wq * gv0;
                ac1 += wq * gv1;
                ac2 += wq * gv2f;
                ac3 += wq * gv3;
            }
        }
    }

    // epilogue: residual + LN2; reduce over the 32 lanes of this graph slot
    float linv = 1.0f / l;
    float4 gb = *(const float4*)&gat_b[h0];
    float4 xr = *(const float4*)&x1[((size_t)n * T_STEPS + g) * H_DIM + h0];
    float rv0 = xr.x + ac0 * linv + gb.x;
    float rv1 = xr.y + ac1 * linv + gb.y;
    float rv2 = xr.z + ac2 * linv + gb.z;
    float rv3 = xr.w + ac3 * linv + gb.w;
    float s1 = rv0 + rv1 + rv2 + rv3;
    float s2v = rv0 * rv0 + rv1 * rv1 + rv2 * rv2 + rv3 * rv3;
#pragma unroll
    for (int mm = 1; mm < 32; mm <<= 1) {
        s1 += __shfl_xor(s1, mm);
        s2v += __shfl_xor(s2v, mm);
    }
    float mean = s1 * (1.f / 128.f);
    float var = s2v * (1.f / 128.f) - mean * mean;
    float rs = rsqrtf(var + LN_EPS);
    float4 g2 = *(const float4*)&ln2_g[h0];
    float4 b2 = *(const float4*)&ln2_b[h0];
    f32x4 ov;
    ov.x = (rv0 - mean) * rs * g2.x + b2.x;
    ov.y = (rv1 - mean) * rs * g2.y + b2.y;
    ov.z = (rv2 - mean) * rs * g2.z + b2.z;
    ov.w = (rv3 - mean) * rs * g2.w + b2.w;
    __builtin_nontemporal_store(ov, (f32x4*)&out[((size_t)n * T_STEPS + g) * H_DIM + h0]);
}

extern "C" void kernel_launch(void* const* d_in, const int* in_sizes, int n_in,
                              void* d_out, int out_size, void* d_ws, size_t ws_size,
                              hipStream_t stream) {
    const float* x         = (const float*)d_in[0];
    const int*   ei        = (const int*)d_in[1];
    const float* edge_attr = (const float*)d_in[2];
    const float* conv_w    = (const float*)d_in[3];
    const float* conv_b    = (const float*)d_in[4];
    const float* ln1_g     = (const float*)d_in[5];
    const float* ln1_b     = (const float*)d_in[6];
    const float* Wl        = (const float*)d_in[7];
    const float* Wr        = (const float*)d_in[8];
    const float* We        = (const float*)d_in[9];
    const float* att       = (const float*)d_in[10];
    const float* gat_b     = (const float*)d_in[11];
    const float* ln2_g     = (const float*)d_in[12];
    const float* ln2_b     = (const float*)d_in[13];
    float* out = (float*)d_out;

    const int* src = ei;
    const int* dst = ei + E_EDGES;

    // workspace layout
    float* x1   = (float*)d_ws;                 // 4,096,000 f32  [n][t][h]
    u16*   glb  = (u16*)(x1 + 4096000);         // 4,096,000 bf16 [g][n][h]
    u16*   grb  = glb + 4096000;                // 4,096,000 bf16 [g][n][h]
    u16*   eeb  = grb + 4096000;                // 2,176,000 bf16
    float* la   = (float*)(eeb + 2176000);      // 16,000 f32
    int* ibase  = (int*)(la + 16000);
    int* cnt    = ibase;                        // 1000
    int* cnt2   = ibase + 1000;                 // 1000
    int* offs   = ibase + 2000;                 // 1001
    int* csr    = ibase + 3001;                 // 16000 (ends 19001; pad to 19008)
    short* wc   = (short*)(ibase + 19008);      // 49152 shorts (16B aligned)
    short* wg   = wc + 49152;                   // 32768 shorts

    k_pack<<<320, 256, 0, stream>>>(conv_w, Wl, Wr, wc, wg);
    k_countscan<<<1, 1024, 0, stream>>>(dst, cnt, cnt2, offs);
    k_place<<<(E_EDGES + 255) / 256, 256, 0, stream>>>(dst, offs, cnt2, csr);
    k_sortla<<<N_NODES, 64, 0, stream>>>(edge_attr, csr, offs, cnt, la);
    k_ee<<<(EP_EDGES + 1) / 2, 256, 0, stream>>>(edge_attr, la, We, eeb);
    k_temporal<<<N_NODES, 256, 0, stream>>>(x, wc, wg, conv_b, ln1_g, ln1_b, x1, glb, grb);
    k_gat<<<8 * N_NODES, 128, 0, stream>>>(glb, grb, eeb, src, csr, offs, cnt,
                                           att, gat_b, x1, ln2_g, ln2_b, out);
}

// Round 10
// 88.940 us; speedup vs baseline: 3.9760x; 1.0453x over previous
//
#include <hip/hip_runtime.h>
#include <math.h>

#define N_NODES 1000
#define T_STEPS 32
#define H_DIM   128
#define E_EDGES 16000
#define ED_DIM  16
#define G_GRAPHS 32
#define EP_EDGES (E_EDGES + N_NODES)
#define NEG_SLOPE 0.2f
#define LN_EPS 1e-5f

typedef __attribute__((ext_vector_type(8))) short bf16x8;
typedef __attribute__((ext_vector_type(16))) float f32x16;
typedef __attribute__((ext_vector_type(4))) float f32x4;
typedef unsigned short u16;

__device__ inline short f2bf(float f) {  // RNE f32 -> bf16
    unsigned u = __float_as_uint(f);
    u = (u + 0x7FFFu + ((u >> 16) & 1u)) >> 16;
    return (short)u;
}
__device__ inline float bf2f(u16 u) { return __uint_as_float(((unsigned)u) << 16); }
__device__ inline float bflo(unsigned u) { return __uint_as_float(u << 16); }
__device__ inline float bfhi(unsigned u) { return __uint_as_float(u & 0xFFFF0000u); }

// ---------- pack conv_w + Wl/Wr into MFMA-B fragment order (one kernel) ----------
__global__ void k_pack(const float* __restrict__ conv_w, const float* __restrict__ Wl,
                       const float* __restrict__ Wr, short* __restrict__ wc,
                       short* __restrict__ wg) {
    int i = blockIdx.x * 256 + threadIdx.x;
    if (i < 4 * 24 * 64 * 8) {
        int r = i & 7, lane = (i >> 3) & 63;
        int t = i >> 9;
        int kstep = t % 24, ct = t / 24;
        int k = kstep >> 3, hs = kstep & 7;
        int hi = hs * 16 + ((lane >> 5) << 3) + r;
        int o = ct * 32 + (lane & 31);
        wc[i] = f2bf(conv_w[(o * H_DIM + hi) * 3 + k]);
    } else {
        int j = i - 4 * 24 * 64 * 8;
        if (j >= 8 * 8 * 64 * 8) return;
        int r = j & 7, lane = (j >> 3) & 63;
        int ks = (j >> 9) & 7, ct = j >> 12;
        int hi = ks * 16 + ((lane >> 5) << 3) + r;
        int o = ct * 32 + (lane & 31);
        wg[j] = f2bf(o < H_DIM ? Wl[hi * H_DIM + o] : Wr[hi * H_DIM + o - H_DIM]);
    }
}

// ---------- count + exclusive scan in ONE block (LDS atomics), also zero cnt2 ----------
__global__ __launch_bounds__(1024) void k_countscan(const int* __restrict__ dst,
                                                    int* __restrict__ cnt, int* __restrict__ cnt2,
                                                    int* __restrict__ offs) {
    __shared__ int sm[1024];
    int t = threadIdx.x;
    sm[t] = 0;
    __syncthreads();
    for (int e = t; e < E_EDGES; e += 1024) atomicAdd(&sm[dst[e]], 1);
    __syncthreads();
    int v = (t < N_NODES) ? sm[t] : 0;
    if (t < N_NODES) { cnt[t] = v; cnt2[t] = 0; }
    __syncthreads();
    sm[t] = v;
    for (int s = 1; s < 1024; s <<= 1) {
        __syncthreads();
        int a = (t >= s) ? sm[t - s] : 0;
        __syncthreads();
        sm[t] += a;
    }
    __syncthreads();
    if (t < N_NODES) offs[t + 1] = sm[t];
    if (t == 0) offs[0] = 0;
}

// ---------- placement: slot via atomic (order fixed by sort below) ----------
__global__ void k_place(const int* __restrict__ dst, const int* __restrict__ offs,
                        int* __restrict__ cnt2, int* __restrict__ csr) {
    int e = blockIdx.x * 256 + threadIdx.x;
    if (e >= E_EDGES) return;
    int d = dst[e];
    int slot = atomicAdd(&cnt2[d], 1);
    csr[offs[d] + slot] = e;
}

// ---------- per-node: sort CSR segment ascending (deterministic) + loop_attr mean ----------
__global__ __launch_bounds__(64) void k_sortla(
    const float* __restrict__ edge_attr, int* __restrict__ csr,
    const int* __restrict__ offs, const int* __restrict__ cnt,
    float* __restrict__ loop_attr) {
    __shared__ int buf[128];
    int n = blockIdx.x;
    int lane = threadIdx.x;  // 64
    int off = offs[n], deg = cnt[n];

    if (deg <= 64) {
        int v = (lane < deg) ? csr[off + lane] : 0x7FFFFFFF;
        int rank = 0;
#pragma unroll
        for (int j = 0; j < 64; ++j) {
            int vj = __shfl(v, j);
            rank += (vj < v) ? 1 : 0;
        }
        if (lane < deg) buf[rank] = v;
    } else {  // cold path: deg in (64,128]
        for (int i = lane; i < deg && i < 128; i += 64) buf[i] = csr[off + i];
        __syncthreads();
        if (lane == 0) {
            int dd = deg < 128 ? deg : 128;
            for (int i = 1; i < dd; ++i) {
                int key = buf[i], j = i - 1;
                while (j >= 0 && buf[j] > key) { buf[j + 1] = buf[j]; --j; }
                buf[j + 1] = key;
            }
        }
    }
    __syncthreads();
    if (lane < deg) csr[off + lane] = buf[lane];

    int q = lane >> 4, f = lane & 15;
    float a = 0.f;
    for (int i = q; i < deg; i += 4) a += edge_attr[buf[i] * ED_DIM + f];
    a += __shfl_xor(a, 16);
    a += __shfl_xor(a, 32);
    if (lane < 16) loop_attr[n * ED_DIM + lane] = a / fmaxf((float)deg, 1.0f);
}

// ---------- ee[e][h] = ea[e] @ We (bf16 out), for all E+N edges ----------
__global__ void k_ee(const float* __restrict__ edge_attr, const float* __restrict__ loop_attr,
                     const float* __restrict__ We, u16* __restrict__ ee) {
    int e = blockIdx.x * 2 + (threadIdx.x >> 7);
    int h = threadIdx.x & 127;
    if (e >= EP_EDGES) return;
    const float* ea = (e < E_EDGES) ? &edge_attr[e * ED_DIM]
                                    : &loop_attr[(e - E_EDGES) * ED_DIM];
    float acc = 0.f;
#pragma unroll
    for (int f = 0; f < ED_DIM; ++f) acc += ea[f] * We[f * H_DIM + h];
    ee[e * H_DIM + h] = (u16)f2bf(acc);
}

// ---------- fused temporal: conv (MFMA) + residual + LN1 + gl/gr (MFMA, bf16 out) ----------
__global__ __launch_bounds__(256) void k_temporal(
    const float* __restrict__ x, const short* __restrict__ wc, const short* __restrict__ wg,
    const float* __restrict__ conv_b, const float* __restrict__ ln1_g,
    const float* __restrict__ ln1_b, float* __restrict__ x1,
    u16* __restrict__ gl, u16* __restrict__ gr) {
    __shared__ __align__(16) short xb[34 * 136];  // bf16; row r = x[r-1][.], rows 0 & 33 zero
    __shared__ float yb[32 * 132];                // conv output (f32)
    int n = blockIdx.x;
    int tid = threadIdx.x;
    int w = tid >> 6, lane = tid & 63;
    int arow = lane & 31;        // MFMA A row (t)
    int aks = (lane >> 5) << 3;  // k-slice base within 16

    // phase 0: x -> bf16 transposed-in-time LDS with halo rows
    {
        const float4* xs4 = (const float4*)(x + (size_t)n * T_STEPS * H_DIM);
        for (int i4 = tid; i4 < T_STEPS * H_DIM / 4; i4 += 256) {
            float4 v = xs4[i4];
            int t = i4 >> 5, h = (i4 * 4) & 127;
            uint2 pp;
            pp.x = (unsigned)(unsigned short)f2bf(v.x) | ((unsigned)(unsigned short)f2bf(v.y) << 16);
            pp.y = (unsigned)(unsigned short)f2bf(v.z) | ((unsigned)(unsigned short)f2bf(v.w) << 16);
            *(uint2*)&xb[(t + 1) * 136 + h] = pp;
        }
        if (tid < 68) {
            ((unsigned*)xb)[tid] = 0u;
            ((unsigned*)(xb + 33 * 136))[tid] = 0u;
        }
    }
    __syncthreads();

    // phase 1: conv = MFMA GEMM, Y[32][128], K=384 (kk = k*128 + hi); wave owns o-tile 32w
    f32x16 acc = {};
    for (int kk = 0; kk < 3; ++kk) {
#pragma unroll
        for (int hs = 0; hs < 8; ++hs) {
            int kstep = kk * 8 + hs;
            bf16x8 a = *(const bf16x8*)&xb[(arow + kk) * 136 + hs * 16 + aks];
            bf16x8 b = *(const bf16x8*)&wc[((w * 24 + kstep) * 64 + lane) * 8];
            acc = __builtin_amdgcn_mfma_f32_32x32x16_bf16(a, b, acc, 0, 0, 0);
        }
    }
    {
        int oc = w * 32 + (lane & 31);
        float cb = conv_b[oc];
#pragma unroll
        for (int r = 0; r < 16; ++r) {
            int t = (r & 3) + 8 * (r >> 2) + 4 * (lane >> 5);
            yb[t * 132 + oc] = acc[r] + cb;
        }
    }
    __syncthreads();

    // phase 2: residual + LN1 -> f32 x1 global + bf16 x1 into xb rows 0..31
    for (int t = w; t < T_STEPS; t += 4) {
        float r0 = x[((size_t)n * T_STEPS + t) * H_DIM + lane] + yb[t * 132 + lane];
        float r1 = x[((size_t)n * T_STEPS + t) * H_DIM + lane + 64] + yb[t * 132 + lane + 64];
        float s = r0 + r1, s2 = r0 * r0 + r1 * r1;
#pragma unroll
        for (int mm = 1; mm < 64; mm <<= 1) {
            s += __shfl_xor(s, mm);
            s2 += __shfl_xor(s2, mm);
        }
        float mean = s * (1.f / 128.f);
        float var = s2 * (1.f / 128.f) - mean * mean;
        float rs = rsqrtf(var + LN_EPS);
        float o0 = (r0 - mean) * rs * ln1_g[lane] + ln1_b[lane];
        float o1 = (r1 - mean) * rs * ln1_g[lane + 64] + ln1_b[lane + 64];
        x1[((size_t)n * T_STEPS + t) * H_DIM + lane] = o0;
        x1[((size_t)n * T_STEPS + t) * H_DIM + lane + 64] = o1;
        xb[t * 136 + lane] = f2bf(o0);
        xb[t * 136 + lane + 64] = f2bf(o1);
    }
    __syncthreads();

    // phase 3: gl/gr = MFMA GEMM [32x128]x[128x256], bf16 stores [g][n][h]
    f32x16 cl = {}, cr = {};
#pragma unroll
    for (int ks = 0; ks < 8; ++ks) {
        bf16x8 a = *(const bf16x8*)&xb[arow * 136 + ks * 16 + aks];
        bf16x8 b0 = *(const bf16x8*)&wg[(((2 * w) * 8 + ks) * 64 + lane) * 8];
        bf16x8 b1 = *(const bf16x8*)&wg[(((2 * w + 1) * 8 + ks) * 64 + lane) * 8];
        cl = __builtin_amdgcn_mfma_f32_32x32x16_bf16(a, b0, cl, 0, 0, 0);
        cr = __builtin_amdgcn_mfma_f32_32x32x16_bf16(a, b1, cr, 0, 0, 0);
    }
    {
        int o0 = 64 * w + (lane & 31);             // global col in [0,256)
        u16* d = (w < 2) ? gl : gr;                // waves 0,1 -> gl; 2,3 -> gr
        int oo0 = (w < 2) ? o0 : o0 - 128;
        int oo1 = oo0 + 32;
#pragma unroll
        for (int r = 0; r < 16; ++r) {
            int t = (r & 3) + 8 * (r >> 2) + 4 * (lane >> 5);
            d[((size_t)t * N_NODES + n) * H_DIM + oo0] = (u16)f2bf(cl[r]);
            d[((size_t)t * N_NODES + n) * H_DIM + oo1] = (u16)f2bf(cr[r]);
        }
    }
}

// ---------- GATv2: block=(n, 8 graphs q+4j), lane=(g-slot, head, d-octet-of-8) serial-d ----------
// 128 thr: gs=tid>>4 (8 graph slots, g=q+4*gs), r=tid&15: head k=r>>2, octet o8=r&3 ->
// h0=k*32+o8*8 (8 channels/lane). Per edge: 16B gl + 16B ee uint4 loads, 8-wide elementwise +
// serial dot, 2-step shfl reduce over 4 octet-lanes. XCD = bid%8 pins q=XCD&3 + one n-parity:
// 8 gl slices = 2MB/XCD stay L2-resident; ee read once per q (4x total, was 8x).
__global__ __launch_bounds__(128) void k_gat(
    const u16* __restrict__ gl, const u16* __restrict__ gr, const u16* __restrict__ ee,
    const int* __restrict__ src_arr, const int* __restrict__ csr,
    const int* __restrict__ offs, const int* __restrict__ cnt,
    const float* __restrict__ att, const float* __restrict__ gat_b,
    const float* __restrict__ x1, const float* __restrict__ ln2_g,
    const float* __restrict__ ln2_b, float* __restrict__ out) {
    int bid = blockIdx.x;        // bid = n*4 + q
    int q = bid & 3;
    int n = bid >> 2;
    int tid = threadIdx.x;
    int gs = tid >> 4;
    int r = tid & 15;
    int h0 = ((r >> 2) << 5) + ((r & 3) << 3);  // head*32 + octet*8
    int g = q + 4 * gs;

    __shared__ int es[64], ss[64];
    int off = offs[n], deg = cnt[n];
    int tot = deg + 1;  // + self-loop (last)

    // per-lane constants
    float av[8], grv[8];
    {
        float4 a0 = *(const float4*)&att[h0];
        float4 a1 = *(const float4*)&att[h0 + 4];
        av[0] = a0.x; av[1] = a0.y; av[2] = a0.z; av[3] = a0.w;
        av[4] = a1.x; av[5] = a1.y; av[6] = a1.z; av[7] = a1.w;
        uint4 g4 = *(const uint4*)&gr[((size_t)g * N_NODES + n) * H_DIM + h0];
        grv[0] = bflo(g4.x); grv[1] = bfhi(g4.x); grv[2] = bflo(g4.y); grv[3] = bfhi(g4.y);
        grv[4] = bflo(g4.z); grv[5] = bfhi(g4.z); grv[6] = bflo(g4.w); grv[7] = bfhi(g4.w);
    }
    const u16* glg = gl + (size_t)g * N_NODES * H_DIM + h0;
    const u16* eeh = ee + h0;

    float m = -INFINITY, l = 0.f;
    float ac[8] = {0.f, 0.f, 0.f, 0.f, 0.f, 0.f, 0.f, 0.f};

    for (int base = 0; base < tot; base += 64) {
        int c = min(64, tot - base);
        __syncthreads();
        if (tid < c) {
            int i = base + tid;
            int e = (i < deg) ? csr[off + i] : (E_EDGES + n);
            es[tid] = e;
            ss[tid] = (i < deg) ? src_arr[e] : n;
        }
        __syncthreads();
        uint4 gv4 = *(const uint4*)&glg[(size_t)ss[0] * H_DIM];
        uint4 ev4 = *(const uint4*)&eeh[(size_t)es[0] * H_DIM];
        for (int i = 0; i < c; ++i) {
            uint4 gc = gv4, ec = ev4;
            if (i + 1 < c) {
                gv4 = *(const uint4*)&glg[(size_t)ss[i + 1] * H_DIM];
                ev4 = *(const uint4*)&eeh[(size_t)es[i + 1] * H_DIM];
            }
            float gv[8];
            gv[0] = bflo(gc.x); gv[1] = bfhi(gc.x); gv[2] = bflo(gc.y); gv[3] = bfhi(gc.y);
            gv[4] = bflo(gc.z); gv[5] = bfhi(gc.z); gv[6] = bflo(gc.w); gv[7] = bfhi(gc.w);
            float ev[8];
            ev[0] = bflo(ec.x); ev[1] = bfhi(ec.x); ev[2] = bflo(ec.y); ev[3] = bfhi(ec.y);
            ev[4] = bflo(ec.z); ev[5] = bfhi(ec.z); ev[6] = bflo(ec.w); ev[7] = bfhi(ec.w);
            float p = 0.f;
#pragma unroll
            for (int j = 0; j < 8; ++j) {
                float sf = gv[j] + grv[j] + ev[j];
                sf = fmaxf(sf, NEG_SLOPE * sf);  // leaky_relu for slope<1
                p = fmaf(sf, av[j], p);
            }
            p += __shfl_xor(p, 1);
            p += __shfl_xor(p, 2);
            // defer-max online softmax
            bool grow = p > m + 8.f;
            if (__any(grow)) {
                float mn = fmaxf(m, p);
                float sc = __expf(m - mn);
                float wq = __expf(p - mn);
                l = l * sc + wq;
#pragma unroll
                for (int j = 0; j < 8; ++j) ac[j] = ac[j] * sc + wq * gv[j];
                m = mn;
            } else {
                float wq = __expf(p - m);
                l += wq;
#pragma unroll
                for (int j = 0; j < 8; ++j) ac[j] += wq * gv[j];
            }
        }
    }

    // epilogue: residual + LN2; reduce over the 16 lanes of this graph slot (intra-wave)
    float linv = 1.0f / l;
    size_t ob = ((size_t)n * T_STEPS + g) * H_DIM + h0;
    float4 x0 = *(const float4*)&x1[ob];
    float4 x1v = *(const float4*)&x1[ob + 4];
    float4 gb0 = *(const float4*)&gat_b[h0];
    float4 gb1 = *(const float4*)&gat_b[h0 + 4];
    float rv[8];
    rv[0] = x0.x + ac[0] * linv + gb0.x;
    rv[1] = x0.y + ac[1] * linv + gb0.y;
    rv[2] = x0.z + ac[2] * linv + gb0.z;
    rv[3] = x0.w + ac[3] * linv + gb0.w;
    rv[4] = x1v.x + ac[4] * linv + gb1.x;
    rv[5] = x1v.y + ac[5] * linv + gb1.y;
    rv[6] = x1v.z + ac[6] * linv + gb1.z;
    rv[7] = x1v.w + ac[7] * linv + gb1.w;
    float s1 = 0.f, s2v = 0.f;
#pragma unroll
    for (int j = 0; j < 8; ++j) { s1 += rv[j]; s2v += rv[j] * rv[j]; }
#pragma unroll
    for (int mm = 1; mm < 16; mm <<= 1) {
        s1 += __shfl_xor(s1, mm);
        s2v += __shfl_xor(s2v, mm);
    }
    float mean = s1 * (1.f / 128.f);
    float var = s2v * (1.f / 128.f) - mean * mean;
    float rs = rsqrtf(var + LN_EPS);
    float4 g20 = *(const float4*)&ln2_g[h0];
    float4 g21 = *(const float4*)&ln2_g[h0 + 4];
    float4 b20 = *(const float4*)&ln2_b[h0];
    float4 b21 = *(const float4*)&ln2_b[h0 + 4];
    f32x4 o0, o1;
    o0.x = (rv[0] - mean) * rs * g20.x + b20.x;
    o0.y = (rv[1] - mean) * rs * g20.y + b20.y;
    o0.z = (rv[2] - mean) * rs * g20.z + b20.z;
    o0.w = (rv[3] - mean) * rs * g20.w + b20.w;
    o1.x = (rv[4] - mean) * rs * g21.x + b21.x;
    o1.y = (rv[5] - mean) * rs * g21.y + b21.y;
    o1.z = (rv[6] - mean) * rs * g21.z + b21.z;
    o1.w = (rv[7] - mean) * rs * g21.w + b21.w;
    __builtin_nontemporal_store(o0, (f32x4*)&out[ob]);
    __builtin_nontemporal_store(o1, (f32x4*)&out[ob + 4]);
}

extern "C" void kernel_launch(void* const* d_in, const int* in_sizes, int n_in,
                              void* d_out, int out_size, void* d_ws, size_t ws_size,
                              hipStream_t stream) {
    const float* x         = (const float*)d_in[0];
    const int*   ei        = (const int*)d_in[1];
    const float* edge_attr = (const float*)d_in[2];
    const float* conv_w    = (const float*)d_in[3];
    const float* conv_b    = (const float*)d_in[4];
    const float* ln1_g     = (const float*)d_in[5];
    const float* ln1_b     = (const float*)d_in[6];
    const float* Wl        = (const float*)d_in[7];
    const float* Wr        = (const float*)d_in[8];
    const float* We        = (const float*)d_in[9];
    const float* att       = (const float*)d_in[10];
    const float* gat_b     = (const float*)d_in[11];
    const float* ln2_g     = (const float*)d_in[12];
    const float* ln2_b     = (const float*)d_in[13];
    float* out = (float*)d_out;

    const int* src = ei;
    const int* dst = ei + E_EDGES;

    // workspace layout
    float* x1   = (float*)d_ws;                 // 4,096,000 f32  [n][t][h]
    u16*   glb  = (u16*)(x1 + 4096000);         // 4,096,000 bf16 [g][n][h]
    u16*   grb  = glb + 4096000;                // 4,096,000 bf16 [g][n][h]
    u16*   eeb  = grb + 4096000;                // 2,176,000 bf16
    float* la   = (float*)(eeb + 2176000);      // 16,000 f32
    int* ibase  = (int*)(la + 16000);
    int* cnt    = ibase;                        // 1000
    int* cnt2   = ibase + 1000;                 // 1000
    int* offs   = ibase + 2000;                 // 1001
    int* csr    = ibase + 3001;                 // 16000 (ends 19001; pad to 19008)
    short* wc   = (short*)(ibase + 19008);      // 49152 shorts (16B aligned)
    short* wg   = wc + 49152;                   // 32768 shorts

    k_pack<<<320, 256, 0, stream>>>(conv_w, Wl, Wr, wc, wg);
    k_countscan<<<1, 1024, 0, stream>>>(dst, cnt, cnt2, offs);
    k_place<<<(E_EDGES + 255) / 256, 256, 0, stream>>>(dst, offs, cnt2, csr);
    k_sortla<<<N_NODES, 64, 0, stream>>>(edge_attr, csr, offs, cnt, la);
    k_ee<<<(EP_EDGES + 1) / 2, 256, 0, stream>>>(edge_attr, la, We, eeb);
    k_temporal<<<N_NODES, 256, 0, stream>>>(x, wc, wg, conv_b, ln1_g, ln1_b, x1, glb, grb);
    k_gat<<<4 * N_NODES, 128, 0, stream>>>(glb, grb, eeb, src, csr, offs, cnt,
                                           att, gat_b, x1, ln2_g, ln2_b, out);
}

// Round 11
// 84.572 us; speedup vs baseline: 4.1813x; 1.0517x over previous
//
#include <hip/hip_runtime.h>
#include <math.h>

#define N_NODES 1000
#define T_STEPS 32
#define H_DIM   128
#define E_EDGES 16000
#define ED_DIM  16
#define G_GRAPHS 32
#define EP_EDGES (E_EDGES + N_NODES)
#define NEG_SLOPE 0.2f
#define LN_EPS 1e-5f

typedef __attribute__((ext_vector_type(8))) short bf16x8;
typedef __attribute__((ext_vector_type(16))) float f32x16;
typedef __attribute__((ext_vector_type(4))) float f32x4;
typedef __attribute__((ext_vector_type(4))) unsigned u32x4;
typedef unsigned short u16;

__device__ inline short f2bf(float f) {  // RNE f32 -> bf16
    unsigned u = __float_as_uint(f);
    u = (u + 0x7FFFu + ((u >> 16) & 1u)) >> 16;
    return (short)u;
}
__device__ inline float bflo(unsigned u) { return __uint_as_float(u << 16); }
__device__ inline float bfhi(unsigned u) { return __uint_as_float(u & 0xFFFF0000u); }

// ---------- L1: pack weights (blocks 0-79) + full CSR build (block 80, LDS atomics) ----------
__global__ __launch_bounds__(1024) void k_prep(
    const float* __restrict__ conv_w, const float* __restrict__ Wl,
    const float* __restrict__ Wr, const int* __restrict__ dst,
    short* __restrict__ wc, short* __restrict__ wg,
    int* __restrict__ cnt, int* __restrict__ offs, int* __restrict__ csr) {
    int b = blockIdx.x;
    if (b < 80) {
        int i = b * 1024 + threadIdx.x;  // 0..81919
        if (i < 4 * 24 * 64 * 8) {
            int r = i & 7, lane = (i >> 3) & 63;
            int t = i >> 9;
            int kstep = t % 24, ct = t / 24;
            int k = kstep >> 3, hs = kstep & 7;
            int hi = hs * 16 + ((lane >> 5) << 3) + r;
            int o = ct * 32 + (lane & 31);
            wc[i] = f2bf(conv_w[(o * H_DIM + hi) * 3 + k]);
        } else {
            int j = i - 4 * 24 * 64 * 8;  // < 32768
            int r = j & 7, lane = (j >> 3) & 63;
            int ks = (j >> 9) & 7, ct = j >> 12;
            int hi = ks * 16 + ((lane >> 5) << 3) + r;
            int o = ct * 32 + (lane & 31);
            wg[j] = f2bf(o < H_DIM ? Wl[hi * H_DIM + o] : Wr[hi * H_DIM + o - H_DIM]);
        }
        return;
    }
    // block 80: count + exclusive scan + placement, all in one block
    __shared__ int sm[1024];
    __shared__ int sl[1024];
    int t = threadIdx.x;
    sm[t] = 0;
    __syncthreads();
    for (int e = t; e < E_EDGES; e += 1024) atomicAdd(&sm[dst[e]], 1);
    __syncthreads();
    int v = (t < N_NODES) ? sm[t] : 0;
    if (t < N_NODES) cnt[t] = v;
    for (int s = 1; s < 1024; s <<= 1) {
        __syncthreads();
        int a = (t >= s) ? sm[t - s] : 0;
        __syncthreads();
        sm[t] += a;
    }
    __syncthreads();
    if (t < N_NODES) offs[t + 1] = sm[t];
    if (t == 0) offs[0] = 0;
    sl[t] = sm[t] - v;  // exclusive prefix = running slot pointer
    __syncthreads();
    for (int e = t; e < E_EDGES; e += 1024) {
        int d = dst[e];
        int s = atomicAdd(&sl[d], 1);
        csr[s] = e;  // order nondeterministic; sorted in k_graphprep
    }
}

// ---------- L2: per-node CSR sort + loop_attr (LDS) + self-loop ee (blocks 0-999);
//               real-edge ee (blocks 1000-8999) ----------
__global__ __launch_bounds__(256) void k_graphprep(
    const float* __restrict__ edge_attr, const float* __restrict__ We,
    int* __restrict__ csr, const int* __restrict__ offs, const int* __restrict__ cnt,
    u16* __restrict__ ee) {
    int b = blockIdx.x;
    int tid = threadIdx.x;
    if (b < N_NODES) {
        __shared__ int buf[128];
        __shared__ float laf[16];
        int n = b;
        int off = offs[n], deg = cnt[n];
        bool fast = (deg <= 64);
        if (fast) {
            if (tid < 64) {
                int v = (tid < deg) ? csr[off + tid] : 0x7FFFFFFF;
                int rank = 0;
#pragma unroll
                for (int j = 0; j < 64; ++j) {
                    int vj = __shfl(v, j);
                    rank += (vj < v) ? 1 : 0;
                }
                if (tid < deg) buf[rank] = v;
            }
        } else {
            for (int i = tid; i < deg && i < 128; i += 256) buf[i] = csr[off + i];
        }
        __syncthreads();
        if (!fast && tid == 0) {
            int dd = deg < 128 ? deg : 128;
            for (int i = 1; i < dd; ++i) {
                int key = buf[i], j = i - 1;
                while (j >= 0 && buf[j] > key) { buf[j + 1] = buf[j]; --j; }
                buf[j + 1] = key;
            }
        }
        __syncthreads();
        if (tid < deg && tid < 128) csr[off + tid] = buf[tid];
        // loop_attr mean (lanes 0-63), kept in LDS
        if (tid < 64) {
            int q = tid >> 4, f = tid & 15;
            float a = 0.f;
            for (int i = q; i < deg; i += 4) a += edge_attr[buf[i] * ED_DIM + f];
            a += __shfl_xor(a, 16);
            a += __shfl_xor(a, 32);
            if (tid < 16) laf[tid] = a / fmaxf((float)deg, 1.0f);
        }
        __syncthreads();
        if (tid < H_DIM) {
            float acc = 0.f;
#pragma unroll
            for (int f = 0; f < ED_DIM; ++f) acc += laf[f] * We[f * H_DIM + tid];
            ee[(size_t)(E_EDGES + n) * H_DIM + tid] = (u16)f2bf(acc);
        }
    } else {
        int e = (b - N_NODES) * 2 + (tid >> 7);
        int h = tid & 127;
        if (e >= E_EDGES) return;
        const float* ea = &edge_attr[e * ED_DIM];
        float acc = 0.f;
#pragma unroll
        for (int f = 0; f < ED_DIM; ++f) acc += ea[f] * We[f * H_DIM + h];
        ee[(size_t)e * H_DIM + h] = (u16)f2bf(acc);
    }
}

// ---------- fused temporal: conv (MFMA) + residual + LN1 + gl/gr (MFMA, bf16 out) ----------
__global__ __launch_bounds__(256) void k_temporal(
    const float* __restrict__ x, const short* __restrict__ wc, const short* __restrict__ wg,
    const float* __restrict__ conv_b, const float* __restrict__ ln1_g,
    const float* __restrict__ ln1_b, float* __restrict__ x1,
    u16* __restrict__ gl, u16* __restrict__ gr) {
    __shared__ __align__(16) short xb[34 * 136];  // bf16; row r = x[r-1][.], rows 0 & 33 zero
    __shared__ float yb[32 * 132];                // conv output (f32)
    int n = blockIdx.x;
    int tid = threadIdx.x;
    int w = tid >> 6, lane = tid & 63;
    int arow = lane & 31;        // MFMA A row (t)
    int aks = (lane >> 5) << 3;  // k-slice base within 16

    // phase 0: x -> bf16 transposed-in-time LDS with halo rows
    {
        const float4* xs4 = (const float4*)(x + (size_t)n * T_STEPS * H_DIM);
        for (int i4 = tid; i4 < T_STEPS * H_DIM / 4; i4 += 256) {
            float4 v = xs4[i4];
            int t = i4 >> 5, h = (i4 * 4) & 127;
            uint2 pp;
            pp.x = (unsigned)(unsigned short)f2bf(v.x) | ((unsigned)(unsigned short)f2bf(v.y) << 16);
            pp.y = (unsigned)(unsigned short)f2bf(v.z) | ((unsigned)(unsigned short)f2bf(v.w) << 16);
            *(uint2*)&xb[(t + 1) * 136 + h] = pp;
        }
        if (tid < 68) {
            ((unsigned*)xb)[tid] = 0u;
            ((unsigned*)(xb + 33 * 136))[tid] = 0u;
        }
    }
    __syncthreads();

    // phase 1: conv = MFMA GEMM, Y[32][128], K=384 (kk = k*128 + hi); wave owns o-tile 32w
    f32x16 acc = {};
    for (int kk = 0; kk < 3; ++kk) {
#pragma unroll
        for (int hs = 0; hs < 8; ++hs) {
            int kstep = kk * 8 + hs;
            bf16x8 a = *(const bf16x8*)&xb[(arow + kk) * 136 + hs * 16 + aks];
            bf16x8 b = *(const bf16x8*)&wc[((w * 24 + kstep) * 64 + lane) * 8];
            acc = __builtin_amdgcn_mfma_f32_32x32x16_bf16(a, b, acc, 0, 0, 0);
        }
    }
    {
        int oc = w * 32 + (lane & 31);
        float cb = conv_b[oc];
#pragma unroll
        for (int r = 0; r < 16; ++r) {
            int t = (r & 3) + 8 * (r >> 2) + 4 * (lane >> 5);
            yb[t * 132 + oc] = acc[r] + cb;
        }
    }
    __syncthreads();

    // phase 2: residual + LN1 -> f32 x1 global + bf16 x1 into xb rows 0..31
    for (int t = w; t < T_STEPS; t += 4) {
        float r0 = x[((size_t)n * T_STEPS + t) * H_DIM + lane] + yb[t * 132 + lane];
        float r1 = x[((size_t)n * T_STEPS + t) * H_DIM + lane + 64] + yb[t * 132 + lane + 64];
        float s = r0 + r1, s2 = r0 * r0 + r1 * r1;
#pragma unroll
        for (int mm = 1; mm < 64; mm <<= 1) {
            s += __shfl_xor(s, mm);
            s2 += __shfl_xor(s2, mm);
        }
        float mean = s * (1.f / 128.f);
        float var = s2 * (1.f / 128.f) - mean * mean;
        float rs = rsqrtf(var + LN_EPS);
        float o0 = (r0 - mean) * rs * ln1_g[lane] + ln1_b[lane];
        float o1 = (r1 - mean) * rs * ln1_g[lane + 64] + ln1_b[lane + 64];
        x1[((size_t)n * T_STEPS + t) * H_DIM + lane] = o0;
        x1[((size_t)n * T_STEPS + t) * H_DIM + lane + 64] = o1;
        xb[t * 136 + lane] = f2bf(o0);
        xb[t * 136 + lane + 64] = f2bf(o1);
    }
    __syncthreads();

    // phase 3: gl/gr = MFMA GEMM [32x128]x[128x256], bf16 stores [g][n][h]
    f32x16 cl = {}, cr = {};
#pragma unroll
    for (int ks = 0; ks < 8; ++ks) {
        bf16x8 a = *(const bf16x8*)&xb[arow * 136 + ks * 16 + aks];
        bf16x8 b0 = *(const bf16x8*)&wg[(((2 * w) * 8 + ks) * 64 + lane) * 8];
        bf16x8 b1 = *(const bf16x8*)&wg[(((2 * w + 1) * 8 + ks) * 64 + lane) * 8];
        cl = __builtin_amdgcn_mfma_f32_32x32x16_bf16(a, b0, cl, 0, 0, 0);
        cr = __builtin_amdgcn_mfma_f32_32x32x16_bf16(a, b1, cr, 0, 0, 0);
    }
    {
        int o0 = 64 * w + (lane & 31);             // global col in [0,256)
        u16* d = (w < 2) ? gl : gr;                // waves 0,1 -> gl; 2,3 -> gr
        int oo0 = (w < 2) ? o0 : o0 - 128;
        int oo1 = oo0 + 32;
#pragma unroll
        for (int r = 0; r < 16; ++r) {
            int t = (r & 3) + 8 * (r >> 2) + 4 * (lane >> 5);
            d[((size_t)t * N_NODES + n) * H_DIM + oo0] = (u16)f2bf(cl[r]);
            d[((size_t)t * N_NODES + n) * H_DIM + oo1] = (u16)f2bf(cr[r]);
        }
    }
}

// ---------- GATv2: block=(n, 8 graphs q+4j), lane=(g-slot, head, d-octet) serial-d ----------
// Branchless always-rescale online softmax (no __any/branch -> pipelines); ee loads
// nontemporal (pure stream per XCD -> keep gl slices L2-resident).
__global__ __launch_bounds__(128) void k_gat(
    const u16* __restrict__ gl, const u16* __restrict__ gr, const u16* __restrict__ ee,
    const int* __restrict__ src_arr, const int* __restrict__ csr,
    const int* __restrict__ offs, const int* __restrict__ cnt,
    const float* __restrict__ att, const float* __restrict__ gat_b,
    const float* __restrict__ x1, const float* __restrict__ ln2_g,
    const float* __restrict__ ln2_b, float* __restrict__ out) {
    int bid = blockIdx.x;        // bid = n*4 + q
    int q = bid & 3;
    int n = bid >> 2;
    int tid = threadIdx.x;
    int gs = tid >> 4;
    int r = tid & 15;
    int h0 = ((r >> 2) << 5) + ((r & 3) << 3);  // head*32 + octet*8
    int g = q + 4 * gs;

    __shared__ int es[64], ss[64];
    int off = offs[n], deg = cnt[n];
    int tot = deg + 1;  // + self-loop (last)

    // per-lane constants
    float av[8], grv[8];
    {
        float4 a0 = *(const float4*)&att[h0];
        float4 a1 = *(const float4*)&att[h0 + 4];
        av[0] = a0.x; av[1] = a0.y; av[2] = a0.z; av[3] = a0.w;
        av[4] = a1.x; av[5] = a1.y; av[6] = a1.z; av[7] = a1.w;
        u32x4 g4 = *(const u32x4*)&gr[((size_t)g * N_NODES + n) * H_DIM + h0];
        grv[0] = bflo(g4.x); grv[1] = bfhi(g4.x); grv[2] = bflo(g4.y); grv[3] = bfhi(g4.y);
        grv[4] = bflo(g4.z); grv[5] = bfhi(g4.z); grv[6] = bflo(g4.w); grv[7] = bfhi(g4.w);
    }
    const u16* glg = gl + (size_t)g * N_NODES * H_DIM + h0;
    const u16* eeh = ee + h0;

    float m = -INFINITY, l = 0.f;
    float ac[8] = {0.f, 0.f, 0.f, 0.f, 0.f, 0.f, 0.f, 0.f};

    for (int base = 0; base < tot; base += 64) {
        int c = min(64, tot - base);
        __syncthreads();
        if (tid < c) {
            int i = base + tid;
            int e = (i < deg) ? csr[off + i] : (E_EDGES + n);
            es[tid] = e;
            ss[tid] = (i < deg) ? src_arr[e] : n;
        }
        __syncthreads();
        u32x4 gv4 = *(const u32x4*)&glg[(size_t)ss[0] * H_DIM];
        u32x4 ev4 = __builtin_nontemporal_load((const u32x4*)&eeh[(size_t)es[0] * H_DIM]);
        for (int i = 0; i < c; ++i) {
            u32x4 gc = gv4, ec = ev4;
            if (i + 1 < c) {
                gv4 = *(const u32x4*)&glg[(size_t)ss[i + 1] * H_DIM];
                ev4 = __builtin_nontemporal_load((const u32x4*)&eeh[(size_t)es[i + 1] * H_DIM]);
            }
            float gv[8];
            gv[0] = bflo(gc.x); gv[1] = bfhi(gc.x); gv[2] = bflo(gc.y); gv[3] = bfhi(gc.y);
            gv[4] = bflo(gc.z); gv[5] = bfhi(gc.z); gv[6] = bflo(gc.w); gv[7] = bfhi(gc.w);
            float p = 0.f;
#pragma unroll
            for (int j = 0; j < 8; ++j) {
                float evj = (j & 1) ? bfhi(((const unsigned*)&ec)[j >> 1])
                                    : bflo(((const unsigned*)&ec)[j >> 1]);
                float sf = gv[j] + grv[j] + evj;
                sf = fmaxf(sf, NEG_SLOPE * sf);  // leaky_relu for slope<1
                p = fmaf(sf, av[j], p);
            }
            p += __shfl_xor(p, 1);
            p += __shfl_xor(p, 2);
            // branchless online softmax: sc==1.0 exactly when p<=m (same rounding as
            // the guarded fast path); first iter exp(-inf)=0
            float mn = fmaxf(m, p);
            float sc = __expf(m - mn);
            float wq = __expf(p - mn);
            l = l * sc + wq;
#pragma unroll
            for (int j = 0; j < 8; ++j) ac[j] = ac[j] * sc + wq * gv[j];
            m = mn;
        }
    }

    // epilogue: residual + LN2; reduce over the 16 lanes of this graph slot (intra-wave)
    float linv = 1.0f / l;
    size_t ob = ((size_t)n * T_STEPS + g) * H_DIM + h0;
    float4 x0 = *(const float4*)&x1[ob];
    float4 x1v = *(const float4*)&x1[ob + 4];
    float4 gb0 = *(const float4*)&gat_b[h0];
    float4 gb1 = *(const float4*)&gat_b[h0 + 4];
    float rv[8];
    rv[0] = x0.x + ac[0] * linv + gb0.x;
    rv[1] = x0.y + ac[1] * linv + gb0.y;
    rv[2] = x0.z + ac[2] * linv + gb0.z;
    rv[3] = x0.w + ac[3] * linv + gb0.w;
    rv[4] = x1v.x + ac[4] * linv + gb1.x;
    rv[5] = x1v.y + ac[5] * linv + gb1.y;
    rv[6] = x1v.z + ac[6] * linv + gb1.z;
    rv[7] = x1v.w + ac[7] * linv + gb1.w;
    float s1 = 0.f, s2v = 0.f;
#pragma unroll
    for (int j = 0; j < 8; ++j) { s1 += rv[j]; s2v += rv[j] * rv[j]; }
#pragma unroll
    for (int mm = 1; mm < 16; mm <<= 1) {
        s1 += __shfl_xor(s1, mm);
        s2v += __shfl_xor(s2v, mm);
    }
    float mean = s1 * (1.f / 128.f);
    float var = s2v * (1.f / 128.f) - mean * mean;
    float rs = rsqrtf(var + LN_EPS);
    float4 g20 = *(const float4*)&ln2_g[h0];
    float4 g21 = *(const float4*)&ln2_g[h0 + 4];
    float4 b20 = *(const float4*)&ln2_b[h0];
    float4 b21 = *(const float4*)&ln2_b[h0 + 4];
    f32x4 o0, o1;
    o0.x = (rv[0] - mean) * rs * g20.x + b20.x;
    o0.y = (rv[1] - mean) * rs * g20.y + b20.y;
    o0.z = (rv[2] - mean) * rs * g20.z + b20.z;
    o0.w = (rv[3] - mean) * rs * g20.w + b20.w;
    o1.x = (rv[4] - mean) * rs * g21.x + b21.x;
    o1.y = (rv[5] - mean) * rs * g21.y + b21.y;
    o1.z = (rv[6] - mean) * rs * g21.z + b21.z;
    o1.w = (rv[7] - mean) * rs * g21.w + b21.w;
    __builtin_nontemporal_store(o0, (f32x4*)&out[ob]);
    __builtin_nontemporal_store(o1, (f32x4*)&out[ob + 4]);
}

extern "C" void kernel_launch(void* const* d_in, const int* in_sizes, int n_in,
                              void* d_out, int out_size, void* d_ws, size_t ws_size,
                              hipStream_t stream) {
    const float* x         = (const float*)d_in[0];
    const int*   ei        = (const int*)d_in[1];
    const float* edge_attr = (const float*)d_in[2];
    const float* conv_w    = (const float*)d_in[3];
    const float* conv_b    = (const float*)d_in[4];
    const float* ln1_g     = (const float*)d_in[5];
    const float* ln1_b     = (const float*)d_in[6];
    const float* Wl        = (const float*)d_in[7];
    const float* Wr        = (const float*)d_in[8];
    const float* We        = (const float*)d_in[9];
    const float* att       = (const float*)d_in[10];
    const float* gat_b     = (const float*)d_in[11];
    const float* ln2_g     = (const float*)d_in[12];
    const float* ln2_b     = (const float*)d_in[13];
    float* out = (float*)d_out;

    const int* src = ei;
    const int* dst = ei + E_EDGES;

    // workspace layout
    float* x1   = (float*)d_ws;                 // 4,096,000 f32  [n][t][h]
    u16*   glb  = (u16*)(x1 + 4096000);         // 4,096,000 bf16 [g][n][h]
    u16*   grb  = glb + 4096000;                // 4,096,000 bf16 [g][n][h]
    u16*   eeb  = grb + 4096000;                // 2,176,000 bf16
    float* la   = (float*)(eeb + 2176000);      // 16,000 f32 (unused, layout kept)
    int* ibase  = (int*)(la + 16000);
    int* cnt    = ibase;                        // 1000
    int* cnt2   = ibase + 1000;                 // 1000 (unused)
    int* offs   = ibase + 2000;                 // 1001
    int* csr    = ibase + 3001;                 // 16000 (ends 19001; pad to 19008)
    short* wc   = (short*)(ibase + 19008);      // 49152 shorts (16B aligned)
    short* wg   = wc + 49152;                   // 32768 shorts

    k_prep<<<81, 1024, 0, stream>>>(conv_w, Wl, Wr, dst, wc, wg, cnt, offs, csr);
    k_graphprep<<<N_NODES + (E_EDGES + 1) / 2, 256, 0, stream>>>(edge_attr, We, csr, offs,
                                                                 cnt, eeb);
    k_temporal<<<N_NODES, 256, 0, stream>>>(x, wc, wg, conv_b, ln1_g, ln1_b, x1, glb, grb);
    k_gat<<<4 * N_NODES, 128, 0, stream>>>(glb, grb, eeb, src, csr, offs, cnt,
                                           att, gat_b, x1, ln2_g, ln2_b, out);
}

// Round 12
// 84.472 us; speedup vs baseline: 4.1863x; 1.0012x over previous
//
#include <hip/hip_runtime.h>
#include <math.h>

#define N_NODES 1000
#define T_STEPS 32
#define H_DIM   128
#define E_EDGES 16000
#define ED_DIM  16
#define G_GRAPHS 32
#define EP_EDGES (E_EDGES + N_NODES)
#define NEG_SLOPE 0.2f
#define LN_EPS 1e-5f

typedef __attribute__((ext_vector_type(8))) short bf16x8;
typedef __attribute__((ext_vector_type(16))) float f32x16;
typedef __attribute__((ext_vector_type(4))) float f32x4;
typedef __attribute__((ext_vector_type(4))) unsigned u32x4;
typedef unsigned short u16;

__device__ inline short f2bf(float f) {  // RNE f32 -> bf16
    unsigned u = __float_as_uint(f);
    u = (u + 0x7FFFu + ((u >> 16) & 1u)) >> 16;
    return (short)u;
}
__device__ inline float bflo(unsigned u) { return __uint_as_float(u << 16); }
__device__ inline float bfhi(unsigned u) { return __uint_as_float(u & 0xFFFF0000u); }

// ---------- L1: pack weights (blocks 0-79) + full CSR build (block 80, LDS atomics) ----------
__global__ __launch_bounds__(1024) void k_prep(
    const float* __restrict__ conv_w, const float* __restrict__ Wl,
    const float* __restrict__ Wr, const int* __restrict__ dst,
    short* __restrict__ wc, short* __restrict__ wg,
    int* __restrict__ cnt, int* __restrict__ offs, int* __restrict__ csr) {
    int b = blockIdx.x;
    if (b < 80) {
        int i = b * 1024 + threadIdx.x;  // 0..81919
        if (i < 4 * 24 * 64 * 8) {
            int r = i & 7, lane = (i >> 3) & 63;
            int t = i >> 9;
            int kstep = t % 24, ct = t / 24;
            int k = kstep >> 3, hs = kstep & 7;
            int hi = hs * 16 + ((lane >> 5) << 3) + r;
            int o = ct * 32 + (lane & 31);
            wc[i] = f2bf(conv_w[(o * H_DIM + hi) * 3 + k]);
        } else {
            int j = i - 4 * 24 * 64 * 8;  // < 32768
            int r = j & 7, lane = (j >> 3) & 63;
            int ks = (j >> 9) & 7, ct = j >> 12;
            int hi = ks * 16 + ((lane >> 5) << 3) + r;
            int o = ct * 32 + (lane & 31);
            wg[j] = f2bf(o < H_DIM ? Wl[hi * H_DIM + o] : Wr[hi * H_DIM + o - H_DIM]);
        }
        return;
    }
    // block 80: count + exclusive scan + placement, all in one block
    __shared__ int sm[1024];
    __shared__ int sl[1024];
    int t = threadIdx.x;
    sm[t] = 0;
    __syncthreads();
    for (int e = t; e < E_EDGES; e += 1024) atomicAdd(&sm[dst[e]], 1);
    __syncthreads();
    int v = (t < N_NODES) ? sm[t] : 0;
    if (t < N_NODES) cnt[t] = v;
    for (int s = 1; s < 1024; s <<= 1) {
        __syncthreads();
        int a = (t >= s) ? sm[t - s] : 0;
        __syncthreads();
        sm[t] += a;
    }
    __syncthreads();
    if (t < N_NODES) offs[t + 1] = sm[t];
    if (t == 0) offs[0] = 0;
    sl[t] = sm[t] - v;  // exclusive prefix = running slot pointer
    __syncthreads();
    for (int e = t; e < E_EDGES; e += 1024) {
        int d = dst[e];
        int s = atomicAdd(&sl[d], 1);
        csr[s] = e;  // order nondeterministic; sorted in k_graphprep
    }
}

// ---------- L2: per-node CSR sort + loop_attr (LDS) + self-loop ee (blocks 0-999);
//               real-edge ee (blocks 1000-8999) ----------
__global__ __launch_bounds__(256) void k_graphprep(
    const float* __restrict__ edge_attr, const float* __restrict__ We,
    int* __restrict__ csr, const int* __restrict__ offs, const int* __restrict__ cnt,
    u16* __restrict__ ee) {
    int b = blockIdx.x;
    int tid = threadIdx.x;
    if (b < N_NODES) {
        __shared__ int buf[128];
        __shared__ float laf[16];
        int n = b;
        int off = offs[n], deg = cnt[n];
        bool fast = (deg <= 64);
        if (fast) {
            if (tid < 64) {
                int v = (tid < deg) ? csr[off + tid] : 0x7FFFFFFF;
                int rank = 0;
#pragma unroll
                for (int j = 0; j < 64; ++j) {
                    int vj = __shfl(v, j);
                    rank += (vj < v) ? 1 : 0;
                }
                if (tid < deg) buf[rank] = v;
            }
        } else {
            for (int i = tid; i < deg && i < 128; i += 256) buf[i] = csr[off + i];
        }
        __syncthreads();
        if (!fast && tid == 0) {
            int dd = deg < 128 ? deg : 128;
            for (int i = 1; i < dd; ++i) {
                int key = buf[i], j = i - 1;
                while (j >= 0 && buf[j] > key) { buf[j + 1] = buf[j]; --j; }
                buf[j + 1] = key;
            }
        }
        __syncthreads();
        if (tid < deg && tid < 128) csr[off + tid] = buf[tid];
        // loop_attr mean (lanes 0-63), kept in LDS
        if (tid < 64) {
            int q = tid >> 4, f = tid & 15;
            float a = 0.f;
            for (int i = q; i < deg; i += 4) a += edge_attr[buf[i] * ED_DIM + f];
            a += __shfl_xor(a, 16);
            a += __shfl_xor(a, 32);
            if (tid < 16) laf[tid] = a / fmaxf((float)deg, 1.0f);
        }
        __syncthreads();
        if (tid < H_DIM) {
            float acc = 0.f;
#pragma unroll
            for (int f = 0; f < ED_DIM; ++f) acc += laf[f] * We[f * H_DIM + tid];
            ee[(size_t)(E_EDGES + n) * H_DIM + tid] = (u16)f2bf(acc);
        }
    } else {
        int e = (b - N_NODES) * 2 + (tid >> 7);
        int h = tid & 127;
        if (e >= E_EDGES) return;
        const float* ea = &edge_attr[e * ED_DIM];
        float acc = 0.f;
#pragma unroll
        for (int f = 0; f < ED_DIM; ++f) acc += ea[f] * We[f * H_DIM + h];
        ee[(size_t)e * H_DIM + h] = (u16)f2bf(acc);
    }
}

// ---------- fused temporal: conv (MFMA) + residual + LN1 + gl/gr (MFMA); all outputs bf16,
//            epilogue stores coalesced via LDS re-staging ----------
__global__ __launch_bounds__(256) void k_temporal(
    const float* __restrict__ x, const short* __restrict__ wc, const short* __restrict__ wg,
    const float* __restrict__ conv_b, const float* __restrict__ ln1_g,
    const float* __restrict__ ln1_b, u16* __restrict__ x1b,
    u16* __restrict__ gl, u16* __restrict__ gr) {
    __shared__ __align__(16) short xb[34 * 136];  // bf16; row r = x[r-1][.], rows 0 & 33 zero
    __shared__ __align__(16) float yb[32 * 136];  // f32 conv out; reused as u16[2][32][136]
    int n = blockIdx.x;
    int tid = threadIdx.x;
    int w = tid >> 6, lane = tid & 63;
    int arow = lane & 31;        // MFMA A row (t)
    int aks = (lane >> 5) << 3;  // k-slice base within 16

    // phase 0: x -> bf16 transposed-in-time LDS with halo rows
    {
        const float4* xs4 = (const float4*)(x + (size_t)n * T_STEPS * H_DIM);
        for (int i4 = tid; i4 < T_STEPS * H_DIM / 4; i4 += 256) {
            float4 v = xs4[i4];
            int t = i4 >> 5, h = (i4 * 4) & 127;
            uint2 pp;
            pp.x = (unsigned)(unsigned short)f2bf(v.x) | ((unsigned)(unsigned short)f2bf(v.y) << 16);
            pp.y = (unsigned)(unsigned short)f2bf(v.z) | ((unsigned)(unsigned short)f2bf(v.w) << 16);
            *(uint2*)&xb[(t + 1) * 136 + h] = pp;
        }
        if (tid < 68) {
            ((unsigned*)xb)[tid] = 0u;
            ((unsigned*)(xb + 33 * 136))[tid] = 0u;
        }
    }
    __syncthreads();

    // phase 1: conv = MFMA GEMM, Y[32][128], K=384 (kk = k*128 + hi); wave owns o-tile 32w
    f32x16 acc = {};
    for (int kk = 0; kk < 3; ++kk) {
#pragma unroll
        for (int hs = 0; hs < 8; ++hs) {
            int kstep = kk * 8 + hs;
            bf16x8 a = *(const bf16x8*)&xb[(arow + kk) * 136 + hs * 16 + aks];
            bf16x8 b = *(const bf16x8*)&wc[((w * 24 + kstep) * 64 + lane) * 8];
            acc = __builtin_amdgcn_mfma_f32_32x32x16_bf16(a, b, acc, 0, 0, 0);
        }
    }
    {
        int oc = w * 32 + (lane & 31);
        float cb = conv_b[oc];
#pragma unroll
        for (int r = 0; r < 16; ++r) {
            int t = (r & 3) + 8 * (r >> 2) + 4 * (lane >> 5);
            yb[t * 136 + oc] = acc[r] + cb;
        }
    }
    __syncthreads();

    // phase 2: residual + LN1 -> bf16 x1 into xb rows 0..31 (in LDS only)
    for (int t = w; t < T_STEPS; t += 4) {
        float r0 = x[((size_t)n * T_STEPS + t) * H_DIM + lane] + yb[t * 136 + lane];
        float r1 = x[((size_t)n * T_STEPS + t) * H_DIM + lane + 64] + yb[t * 136 + lane + 64];
        float s = r0 + r1, s2 = r0 * r0 + r1 * r1;
#pragma unroll
        for (int mm = 1; mm < 64; mm <<= 1) {
            s += __shfl_xor(s, mm);
            s2 += __shfl_xor(s2, mm);
        }
        float mean = s * (1.f / 128.f);
        float var = s2 * (1.f / 128.f) - mean * mean;
        float rs = rsqrtf(var + LN_EPS);
        float o0 = (r0 - mean) * rs * ln1_g[lane] + ln1_b[lane];
        float o1 = (r1 - mean) * rs * ln1_g[lane + 64] + ln1_b[lane + 64];
        xb[t * 136 + lane] = f2bf(o0);
        xb[t * 136 + lane + 64] = f2bf(o1);
    }
    __syncthreads();

    // x1 (bf16) copy-out: coalesced uint4 row chunks (xb rows are 16B-aligned, stride 272B)
    for (int c = tid; c < 512; c += 256) {
        int t = c >> 4, p = c & 15;
        u32x4 v = *(const u32x4*)&xb[t * 136 + p * 8];
        *(u32x4*)&x1b[((size_t)n * T_STEPS + t) * H_DIM + p * 8] = v;
    }

    // phase 3: gl/gr = MFMA GEMM [32x128]x[128x256]
    f32x16 cl = {}, cr = {};
#pragma unroll
    for (int ks = 0; ks < 8; ++ks) {
        bf16x8 a = *(const bf16x8*)&xb[arow * 136 + ks * 16 + aks];
        bf16x8 b0 = *(const bf16x8*)&wg[(((2 * w) * 8 + ks) * 64 + lane) * 8];
        bf16x8 b1 = *(const bf16x8*)&wg[(((2 * w + 1) * 8 + ks) * 64 + lane) * 8];
        cl = __builtin_amdgcn_mfma_f32_32x32x16_bf16(a, b0, cl, 0, 0, 0);
        cr = __builtin_amdgcn_mfma_f32_32x32x16_bf16(a, b1, cr, 0, 0, 0);
    }
    // stage bf16 into LDS (reuse yb as u16[2][32][136]), then coalesced uint4 stores
    __syncthreads();  // yb f32 reads done (phase 2)
    {
        u16* st = (u16*)yb;
        int m = w >> 1;                       // 0 -> gl, 1 -> gr
        int c0 = (w & 1) * 64 + (lane & 31);  // col within matrix
#pragma unroll
        for (int r = 0; r < 16; ++r) {
            int t = (r & 3) + 8 * (r >> 2) + 4 * (lane >> 5);
            st[(m * 32 + t) * 136 + c0] = (u16)f2bf(cl[r]);
            st[(m * 32 + t) * 136 + c0 + 32] = (u16)f2bf(cr[r]);
        }
    }
    __syncthreads();
    {
        const u16* st = (const u16*)yb;
        for (int c = tid; c < 1024; c += 256) {
            int m = c >> 9, t = (c >> 4) & 31, p = c & 15;
            u32x4 v = *(const u32x4*)&st[(m * 32 + t) * 136 + p * 8];
            u16* d = m ? gr : gl;
            *(u32x4*)&d[((size_t)t * N_NODES + n) * H_DIM + p * 8] = v;
        }
    }
}

// ---------- GATv2: block=(n, 8 graphs q+4j), lane=(g-slot, head, d-octet) serial-d ----------
// Branchless always-rescale online softmax; ee loads nontemporal (pure stream per XCD).
__global__ __launch_bounds__(128) void k_gat(
    const u16* __restrict__ gl, const u16* __restrict__ gr, const u16* __restrict__ ee,
    const int* __restrict__ src_arr, const int* __restrict__ csr,
    const int* __restrict__ offs, const int* __restrict__ cnt,
    const float* __restrict__ att, const float* __restrict__ gat_b,
    const u16* __restrict__ x1b, const float* __restrict__ ln2_g,
    const float* __restrict__ ln2_b, float* __restrict__ out) {
    int bid = blockIdx.x;        // bid = n*4 + q
    int q = bid & 3;
    int n = bid >> 2;
    int tid = threadIdx.x;
    int gs = tid >> 4;
    int r = tid & 15;
    int h0 = ((r >> 2) << 5) + ((r & 3) << 3);  // head*32 + octet*8
    int g = q + 4 * gs;

    __shared__ int es[64], ss[64];
    int off = offs[n], deg = cnt[n];
    int tot = deg + 1;  // + self-loop (last)

    // per-lane constants
    float av[8], grv[8];
    {
        float4 a0 = *(const float4*)&att[h0];
        float4 a1 = *(const float4*)&att[h0 + 4];
        av[0] = a0.x; av[1] = a0.y; av[2] = a0.z; av[3] = a0.w;
        av[4] = a1.x; av[5] = a1.y; av[6] = a1.z; av[7] = a1.w;
        u32x4 g4 = *(const u32x4*)&gr[((size_t)g * N_NODES + n) * H_DIM + h0];
        grv[0] = bflo(g4.x); grv[1] = bfhi(g4.x); grv[2] = bflo(g4.y); grv[3] = bfhi(g4.y);
        grv[4] = bflo(g4.z); grv[5] = bfhi(g4.z); grv[6] = bflo(g4.w); grv[7] = bfhi(g4.w);
    }
    const u16* glg = gl + (size_t)g * N_NODES * H_DIM + h0;
    const u16* eeh = ee + h0;

    float m = -INFINITY, l = 0.f;
    float ac[8] = {0.f, 0.f, 0.f, 0.f, 0.f, 0.f, 0.f, 0.f};

    for (int base = 0; base < tot; base += 64) {
        int c = min(64, tot - base);
        __syncthreads();
        if (tid < c) {
            int i = base + tid;
            int e = (i < deg) ? csr[off + i] : (E_EDGES + n);
            es[tid] = e;
            ss[tid] = (i < deg) ? src_arr[e] : n;
        }
        __syncthreads();
        u32x4 gv4 = *(const u32x4*)&glg[(size_t)ss[0] * H_DIM];
        u32x4 ev4 = __builtin_nontemporal_load((const u32x4*)&eeh[(size_t)es[0] * H_DIM]);
        for (int i = 0; i < c; ++i) {
            u32x4 gc = gv4, ec = ev4;
            if (i + 1 < c) {
                gv4 = *(const u32x4*)&glg[(size_t)ss[i + 1] * H_DIM];
                ev4 = __builtin_nontemporal_load((const u32x4*)&eeh[(size_t)es[i + 1] * H_DIM]);
            }
            float gv[8];
            gv[0] = bflo(gc.x); gv[1] = bfhi(gc.x); gv[2] = bflo(gc.y); gv[3] = bfhi(gc.y);
            gv[4] = bflo(gc.z); gv[5] = bfhi(gc.z); gv[6] = bflo(gc.w); gv[7] = bfhi(gc.w);
            float p = 0.f;
#pragma unroll
            for (int j = 0; j < 8; ++j) {
                float evj = (j & 1) ? bfhi(((const unsigned*)&ec)[j >> 1])
                                    : bflo(((const unsigned*)&ec)[j >> 1]);
                float sf = gv[j] + grv[j] + evj;
                sf = fmaxf(sf, NEG_SLOPE * sf);  // leaky_relu for slope<1
                p = fmaf(sf, av[j], p);
            }
            p += __shfl_xor(p, 1);
            p += __shfl_xor(p, 2);
            // branchless online softmax: sc==1.0 exactly when p<=m; first iter exp(-inf)=0
            float mn = fmaxf(m, p);
            float sc = __expf(m - mn);
            float wq = __expf(p - mn);
            l = l * sc + wq;
#pragma unroll
            for (int j = 0; j < 8; ++j) ac[j] = ac[j] * sc + wq * gv[j];
            m = mn;
        }
    }

    // epilogue: residual (bf16 x1) + LN2; reduce over the 16 lanes of this graph slot
    float linv = 1.0f / l;
    size_t ob = ((size_t)n * T_STEPS + g) * H_DIM + h0;
    float4 gb0 = *(const float4*)&gat_b[h0];
    float4 gb1 = *(const float4*)&gat_b[h0 + 4];
    u32x4 xv = *(const u32x4*)&x1b[ob];
    float xr[8];
    xr[0] = bflo(xv.x); xr[1] = bfhi(xv.x); xr[2] = bflo(xv.y); xr[3] = bfhi(xv.y);
    xr[4] = bflo(xv.z); xr[5] = bfhi(xv.z); xr[6] = bflo(xv.w); xr[7] = bfhi(xv.w);
    float gbv[8] = {gb0.x, gb0.y, gb0.z, gb0.w, gb1.x, gb1.y, gb1.z, gb1.w};
    float rv[8];
    float s1 = 0.f, s2v = 0.f;
#pragma unroll
    for (int j = 0; j < 8; ++j) {
        rv[j] = xr[j] + ac[j] * linv + gbv[j];
        s1 += rv[j];
        s2v += rv[j] * rv[j];
    }
#pragma unroll
    for (int mm = 1; mm < 16; mm <<= 1) {
        s1 += __shfl_xor(s1, mm);
        s2v += __shfl_xor(s2v, mm);
    }
    float mean = s1 * (1.f / 128.f);
    float var = s2v * (1.f / 128.f) - mean * mean;
    float rs = rsqrtf(var + LN_EPS);
    float4 g20 = *(const float4*)&ln2_g[h0];
    float4 g21 = *(const float4*)&ln2_g[h0 + 4];
    float4 b20 = *(const float4*)&ln2_b[h0];
    float4 b21 = *(const float4*)&ln2_b[h0 + 4];
    f32x4 o0, o1;
    o0.x = (rv[0] - mean) * rs * g20.x + b20.x;
    o0.y = (rv[1] - mean) * rs * g20.y + b20.y;
    o0.z = (rv[2] - mean) * rs * g20.z + b20.z;
    o0.w = (rv[3] - mean) * rs * g20.w + b20.w;
    o1.x = (rv[4] - mean) * rs * g21.x + b21.x;
    o1.y = (rv[5] - mean) * rs * g21.y + b21.y;
    o1.z = (rv[6] - mean) * rs * g21.z + b21.z;
    o1.w = (rv[7] - mean) * rs * g21.w + b21.w;
    __builtin_nontemporal_store(o0, (f32x4*)&out[ob]);
    __builtin_nontemporal_store(o1, (f32x4*)&out[ob + 4]);
}

extern "C" void kernel_launch(void* const* d_in, const int* in_sizes, int n_in,
                              void* d_out, int out_size, void* d_ws, size_t ws_size,
                              hipStream_t stream) {
    const float* x         = (const float*)d_in[0];
    const int*   ei        = (const int*)d_in[1];
    const float* edge_attr = (const float*)d_in[2];
    const float* conv_w    = (const float*)d_in[3];
    const float* conv_b    = (const float*)d_in[4];
    const float* ln1_g     = (const float*)d_in[5];
    const float* ln1_b     = (const float*)d_in[6];
    const float* Wl        = (const float*)d_in[7];
    const float* Wr        = (const float*)d_in[8];
    const float* We        = (const float*)d_in[9];
    const float* att       = (const float*)d_in[10];
    const float* gat_b     = (const float*)d_in[11];
    const float* ln2_g     = (const float*)d_in[12];
    const float* ln2_b     = (const float*)d_in[13];
    float* out = (float*)d_out;

    const int* src = ei;
    const int* dst = ei + E_EDGES;

    // workspace layout (all bf16 activations)
    u16* x1b    = (u16*)d_ws;                   // 4,096,000 bf16 [n][t][h]
    u16* glb    = x1b + 4096000;                // 4,096,000 bf16 [g][n][h]
    u16* grb    = glb + 4096000;                // 4,096,000 bf16 [g][n][h]
    u16* eeb    = grb + 4096000;                // 2,176,000 bf16
    int* ibase  = (int*)(eeb + 2176000);
    int* cnt    = ibase;                        // 1000
    int* offs   = ibase + 1000;                 // 1001
    int* csr    = ibase + 2001;                 // 16000 (ends 18001; pad to 18008)
    short* wc   = (short*)(ibase + 18008);      // 49152 shorts (16B aligned)
    short* wg   = wc + 49152;                   // 32768 shorts

    k_prep<<<81, 1024, 0, stream>>>(conv_w, Wl, Wr, dst, wc, wg, cnt, offs, csr);
    k_graphprep<<<N_NODES + (E_EDGES + 1) / 2, 256, 0, stream>>>(edge_attr, We, csr, offs,
                                                                 cnt, eeb);
    k_temporal<<<N_NODES, 256, 0, stream>>>(x, wc, wg, conv_b, ln1_g, ln1_b, x1b, glb, grb);
    k_gat<<<4 * N_NODES, 128, 0, stream>>>(glb, grb, eeb, src, csr, offs, cnt,
                                           att, gat_b, x1b, ln2_g, ln2_b, out);
}

// Round 13
// 76.618 us; speedup vs baseline: 4.6154x; 1.1025x over previous
//
#include <hip/hip_runtime.h>
#include <math.h>

#define N_NODES 1000
#define T_STEPS 32
#define H_DIM   128
#define E_EDGES 16000
#define ED_DIM  16
#define G_GRAPHS 32
#define EP_EDGES (E_EDGES + N_NODES)
#define NEG_SLOPE 0.2f
#define LN_EPS 1e-5f
#define CSR_CAP 128

typedef __attribute__((ext_vector_type(8))) short bf16x8;
typedef __attribute__((ext_vector_type(16))) float f32x16;
typedef __attribute__((ext_vector_type(4))) float f32x4;
typedef __attribute__((ext_vector_type(4))) unsigned u32x4;
typedef unsigned short u16;

__device__ inline short f2bf(float f) {  // RNE f32 -> bf16
    unsigned u = __float_as_uint(f);
    u = (u + 0x7FFFu + ((u >> 16) & 1u)) >> 16;
    return (short)u;
}
__device__ inline float bflo(unsigned u) { return __uint_as_float(u << 16); }
__device__ inline float bfhi(unsigned u) { return __uint_as_float(u & 0xFFFF0000u); }

// ---------- L1: pack weights (blocks 0-79) + parallel CSR place (blocks 80-95) ----------
// cnt pre-zeroed by memset. Fixed-capacity CSR csr[n][128] -> no scan, no offsets.
// Slot order nondeterministic; k_fuse's rank-sort restores ascending edge order.
__global__ __launch_bounds__(1024) void k_prep(
    const float* __restrict__ conv_w, const float* __restrict__ Wl,
    const float* __restrict__ Wr, const int* __restrict__ dst,
    short* __restrict__ wc, short* __restrict__ wg,
    int* __restrict__ cnt, int* __restrict__ csr) {
    int b = blockIdx.x;
    if (b < 80) {
        int i = b * 1024 + threadIdx.x;  // 0..81919
        if (i < 4 * 24 * 64 * 8) {
            int r = i & 7, lane = (i >> 3) & 63;
            int t = i >> 9;
            int kstep = t % 24, ct = t / 24;
            int k = kstep >> 3, hs = kstep & 7;
            int hi = hs * 16 + ((lane >> 5) << 3) + r;
            int o = ct * 32 + (lane & 31);
            wc[i] = f2bf(conv_w[(o * H_DIM + hi) * 3 + k]);
        } else {
            int j = i - 4 * 24 * 64 * 8;  // < 32768
            int r = j & 7, lane = (j >> 3) & 63;
            int ks = (j >> 9) & 7, ct = j >> 12;
            int hi = ks * 16 + ((lane >> 5) << 3) + r;
            int o = ct * 32 + (lane & 31);
            wg[j] = f2bf(o < H_DIM ? Wl[hi * H_DIM + o] : Wr[hi * H_DIM + o - H_DIM]);
        }
        return;
    }
    int e = (b - 80) * 1024 + threadIdx.x;
    if (e < E_EDGES) {
        int d = dst[e];
        int slot = atomicAdd(&cnt[d], 1);
        if (slot < CSR_CAP) csr[d * CSR_CAP + slot] = e;
    }
}

// ---------- L2 fused: temporal (blocks 0-999) | CSR sort + loop_attr + self-ee (1000-1999)
//            | edge ee (2000-9999) ----------
__global__ __launch_bounds__(256) void k_fuse(
    const float* __restrict__ x, const short* __restrict__ wc, const short* __restrict__ wg,
    const float* __restrict__ conv_b, const float* __restrict__ ln1_g,
    const float* __restrict__ ln1_b, const float* __restrict__ edge_attr,
    const float* __restrict__ We, int* __restrict__ csr, const int* __restrict__ cnt,
    u16* __restrict__ x1b, u16* __restrict__ gl, u16* __restrict__ gr,
    u16* __restrict__ ee) {
    __shared__ __align__(16) short xb[34 * 136];
    __shared__ __align__(16) float yb[32 * 136];
    __shared__ int buf[CSR_CAP];
    __shared__ float laf[16];
    int b = blockIdx.x;
    int tid = threadIdx.x;

    if (b >= 2000) {  // ---- edge ee ----
        int e = (b - 2000) * 2 + (tid >> 7);
        int h = tid & 127;
        if (e >= E_EDGES) return;
        const float* ea = &edge_attr[e * ED_DIM];
        float acc = 0.f;
#pragma unroll
        for (int f = 0; f < ED_DIM; ++f) acc += ea[f] * We[f * H_DIM + h];
        ee[(size_t)e * H_DIM + h] = (u16)f2bf(acc);
        return;
    }
    if (b >= 1000) {  // ---- per-node sort + loop_attr + self-loop ee ----
        int n = b - 1000;
        int off = n * CSR_CAP, deg = cnt[n];
        bool fast = (deg <= 64);
        if (fast) {
            if (tid < 64) {
                int v = (tid < deg) ? csr[off + tid] : 0x7FFFFFFF;
                int rank = 0;
#pragma unroll
                for (int j = 0; j < 64; ++j) {
                    int vj = __shfl(v, j);
                    rank += (vj < v) ? 1 : 0;
                }
                if (tid < deg) buf[rank] = v;
            }
        } else {
            for (int i = tid; i < deg && i < CSR_CAP; i += 256) buf[i] = csr[off + i];
        }
        __syncthreads();
        if (!fast && tid == 0) {
            int dd = deg < CSR_CAP ? deg : CSR_CAP;
            for (int i = 1; i < dd; ++i) {
                int key = buf[i], j = i - 1;
                while (j >= 0 && buf[j] > key) { buf[j + 1] = buf[j]; --j; }
                buf[j + 1] = key;
            }
        }
        __syncthreads();
        if (tid < deg && tid < CSR_CAP) csr[off + tid] = buf[tid];
        if (tid < 64) {
            int q = tid >> 4, f = tid & 15;
            float a = 0.f;
            for (int i = q; i < deg; i += 4) a += edge_attr[buf[i] * ED_DIM + f];
            a += __shfl_xor(a, 16);
            a += __shfl_xor(a, 32);
            if (tid < 16) laf[tid] = a / fmaxf((float)deg, 1.0f);
        }
        __syncthreads();
        if (tid < H_DIM) {
            float acc = 0.f;
#pragma unroll
            for (int f = 0; f < ED_DIM; ++f) acc += laf[f] * We[f * H_DIM + tid];
            ee[(size_t)(E_EDGES + n) * H_DIM + tid] = (u16)f2bf(acc);
        }
        return;
    }

    // ---- temporal: conv (MFMA) + residual + LN1 + gl/gr (MFMA), bf16 outputs ----
    int n = b;
    int w = tid >> 6, lane = tid & 63;
    int arow = lane & 31;
    int aks = (lane >> 5) << 3;

    {
        const float4* xs4 = (const float4*)(x + (size_t)n * T_STEPS * H_DIM);
        for (int i4 = tid; i4 < T_STEPS * H_DIM / 4; i4 += 256) {
            float4 v = xs4[i4];
            int t = i4 >> 5, h = (i4 * 4) & 127;
            uint2 pp;
            pp.x = (unsigned)(unsigned short)f2bf(v.x) | ((unsigned)(unsigned short)f2bf(v.y) << 16);
            pp.y = (unsigned)(unsigned short)f2bf(v.z) | ((unsigned)(unsigned short)f2bf(v.w) << 16);
            *(uint2*)&xb[(t + 1) * 136 + h] = pp;
        }
        if (tid < 68) {
            ((unsigned*)xb)[tid] = 0u;
            ((unsigned*)(xb + 33 * 136))[tid] = 0u;
        }
    }
    __syncthreads();

    f32x16 acc = {};
    for (int kk = 0; kk < 3; ++kk) {
#pragma unroll
        for (int hs = 0; hs < 8; ++hs) {
            int kstep = kk * 8 + hs;
            bf16x8 a = *(const bf16x8*)&xb[(arow + kk) * 136 + hs * 16 + aks];
            bf16x8 bb = *(const bf16x8*)&wc[((w * 24 + kstep) * 64 + lane) * 8];
            acc = __builtin_amdgcn_mfma_f32_32x32x16_bf16(a, bb, acc, 0, 0, 0);
        }
    }
    {
        int oc = w * 32 + (lane & 31);
        float cb = conv_b[oc];
#pragma unroll
        for (int r = 0; r < 16; ++r) {
            int t = (r & 3) + 8 * (r >> 2) + 4 * (lane >> 5);
            yb[t * 136 + oc] = acc[r] + cb;
        }
    }
    __syncthreads();

    for (int t = w; t < T_STEPS; t += 4) {
        float r0 = x[((size_t)n * T_STEPS + t) * H_DIM + lane] + yb[t * 136 + lane];
        float r1 = x[((size_t)n * T_STEPS + t) * H_DIM + lane + 64] + yb[t * 136 + lane + 64];
        float s = r0 + r1, s2 = r0 * r0 + r1 * r1;
#pragma unroll
        for (int mm = 1; mm < 64; mm <<= 1) {
            s += __shfl_xor(s, mm);
            s2 += __shfl_xor(s2, mm);
        }
        float mean = s * (1.f / 128.f);
        float var = s2 * (1.f / 128.f) - mean * mean;
        float rs = rsqrtf(var + LN_EPS);
        float o0 = (r0 - mean) * rs * ln1_g[lane] + ln1_b[lane];
        float o1 = (r1 - mean) * rs * ln1_g[lane + 64] + ln1_b[lane + 64];
        xb[t * 136 + lane] = f2bf(o0);
        xb[t * 136 + lane + 64] = f2bf(o1);
    }
    __syncthreads();

    for (int c = tid; c < 512; c += 256) {
        int t = c >> 4, p = c & 15;
        u32x4 v = *(const u32x4*)&xb[t * 136 + p * 8];
        *(u32x4*)&x1b[((size_t)n * T_STEPS + t) * H_DIM + p * 8] = v;
    }

    f32x16 cl = {}, cr = {};
#pragma unroll
    for (int ks = 0; ks < 8; ++ks) {
        bf16x8 a = *(const bf16x8*)&xb[arow * 136 + ks * 16 + aks];
        bf16x8 b0 = *(const bf16x8*)&wg[(((2 * w) * 8 + ks) * 64 + lane) * 8];
        bf16x8 b1 = *(const bf16x8*)&wg[(((2 * w + 1) * 8 + ks) * 64 + lane) * 8];
        cl = __builtin_amdgcn_mfma_f32_32x32x16_bf16(a, b0, cl, 0, 0, 0);
        cr = __builtin_amdgcn_mfma_f32_32x32x16_bf16(a, b1, cr, 0, 0, 0);
    }
    __syncthreads();
    {
        u16* st = (u16*)yb;
        int m = w >> 1;
        int c0 = (w & 1) * 64 + (lane & 31);
#pragma unroll
        for (int r = 0; r < 16; ++r) {
            int t = (r & 3) + 8 * (r >> 2) + 4 * (lane >> 5);
            st[(m * 32 + t) * 136 + c0] = (u16)f2bf(cl[r]);
            st[(m * 32 + t) * 136 + c0 + 32] = (u16)f2bf(cr[r]);
        }
    }
    __syncthreads();
    {
        const u16* st = (const u16*)yb;
        for (int c = tid; c < 1024; c += 256) {
            int m = c >> 9, t = (c >> 4) & 31, p = c & 15;
            u32x4 v = *(const u32x4*)&st[(m * 32 + t) * 136 + p * 8];
            u16* d = m ? gr : gl;
            *(u32x4*)&d[((size_t)t * N_NODES + n) * H_DIM + p * 8] = v;
        }
    }
}

// ---------- GATv2: block=(n, 8 graphs q+4j); 4-deep software-pipelined gather ----------
__global__ __launch_bounds__(128) void k_gat(
    const u16* __restrict__ gl, const u16* __restrict__ gr, const u16* __restrict__ ee,
    const int* __restrict__ src_arr, const int* __restrict__ csr,
    const int* __restrict__ cnt, const float* __restrict__ att,
    const float* __restrict__ gat_b, const u16* __restrict__ x1b,
    const float* __restrict__ ln2_g, const float* __restrict__ ln2_b,
    float* __restrict__ out) {
    int bid = blockIdx.x;        // bid = n*4 + q
    int q = bid & 3;
    int n = bid >> 2;
    int tid = threadIdx.x;
    int gs = tid >> 4;
    int r = tid & 15;
    int h0 = ((r >> 2) << 5) + ((r & 3) << 3);  // head*32 + octet*8
    int g = q + 4 * gs;

    __shared__ int es[64], ss[64];
    int off = n * CSR_CAP, deg = cnt[n];
    int tot = deg + 1;  // + self-loop (last)

    float av[8], grv[8];
    {
        float4 a0 = *(const float4*)&att[h0];
        float4 a1 = *(const float4*)&att[h0 + 4];
        av[0] = a0.x; av[1] = a0.y; av[2] = a0.z; av[3] = a0.w;
        av[4] = a1.x; av[5] = a1.y; av[6] = a1.z; av[7] = a1.w;
        u32x4 g4 = *(const u32x4*)&gr[((size_t)g * N_NODES + n) * H_DIM + h0];
        grv[0] = bflo(g4.x); grv[1] = bfhi(g4.x); grv[2] = bflo(g4.y); grv[3] = bfhi(g4.y);
        grv[4] = bflo(g4.z); grv[5] = bfhi(g4.z); grv[6] = bflo(g4.w); grv[7] = bfhi(g4.w);
    }
    const u16* glg = gl + (size_t)g * N_NODES * H_DIM + h0;
    const u16* eeh = ee + h0;

    // prefetch residual early (used only in epilogue)
    size_t ob = ((size_t)n * T_STEPS + g) * H_DIM + h0;
    u32x4 xv = __builtin_nontemporal_load((const u32x4*)&x1b[ob]);

    float m = -INFINITY, l = 0.f;
    float ac[8] = {0.f, 0.f, 0.f, 0.f, 0.f, 0.f, 0.f, 0.f};

    auto LDQ = [&](u32x4& G, u32x4& E, int idx) {
        int s_ = ss[idx], e_ = es[idx];
        G = *(const u32x4*)&glg[(size_t)s_ * H_DIM];
        E = __builtin_nontemporal_load((const u32x4*)&eeh[(size_t)e_ * H_DIM]);
    };
    auto PROC = [&](u32x4 gc, u32x4 ec) {
        float gvv[8];
        gvv[0] = bflo(gc.x); gvv[1] = bfhi(gc.x); gvv[2] = bflo(gc.y); gvv[3] = bfhi(gc.y);
        gvv[4] = bflo(gc.z); gvv[5] = bfhi(gc.z); gvv[6] = bflo(gc.w); gvv[7] = bfhi(gc.w);
        float evv[8];
        evv[0] = bflo(ec.x); evv[1] = bfhi(ec.x); evv[2] = bflo(ec.y); evv[3] = bfhi(ec.y);
        evv[4] = bflo(ec.z); evv[5] = bfhi(ec.z); evv[6] = bflo(ec.w); evv[7] = bfhi(ec.w);
        float p = 0.f;
#pragma unroll
        for (int j = 0; j < 8; ++j) {
            float sf = gvv[j] + grv[j] + evv[j];
            sf = fmaxf(sf, NEG_SLOPE * sf);  // leaky_relu for slope<1
            p = fmaf(sf, av[j], p);
        }
        p += __shfl_xor(p, 1);
        p += __shfl_xor(p, 2);
        float mn = fmaxf(m, p);
        float sc = __expf(m - mn);   // ==1.0 exactly when p<=m
        float wq = __expf(p - mn);
        l = l * sc + wq;
#pragma unroll
        for (int j = 0; j < 8; ++j) ac[j] = ac[j] * sc + wq * gvv[j];
        m = mn;
    };

    for (int base = 0; base < tot; base += 64) {
        int c = min(64, tot - base);
        __syncthreads();
        if (tid < c) {
            int i = base + tid;
            int e = (i < deg) ? csr[off + i] : (E_EDGES + n);
            es[tid] = e;
            ss[tid] = (i < deg) ? src_arr[e] : n;
        }
        __syncthreads();
        int c1 = c - 1;
        u32x4 gA, eA, gB, eB, gC, eC, gD, eD;
        LDQ(gA, eA, 0);
        LDQ(gB, eB, min(1, c1));
        LDQ(gC, eC, min(2, c1));
        LDQ(gD, eD, min(3, c1));
        for (int i = 0; i < c; i += 4) {
            u32x4 g0 = gA, e0 = eA, g1 = gB, e1 = eB;
            u32x4 g2 = gC, e2 = eC, g3 = gD, e3 = eD;
            LDQ(gA, eA, min(i + 4, c1));
            LDQ(gB, eB, min(i + 5, c1));
            LDQ(gC, eC, min(i + 6, c1));
            LDQ(gD, eD, min(i + 7, c1));
            PROC(g0, e0);
            if (i + 1 < c) PROC(g1, e1);
            if (i + 2 < c) PROC(g2, e2);
            if (i + 3 < c) PROC(g3, e3);
        }
    }

    // epilogue: residual (bf16 x1) + LN2; reduce over the 16 lanes of this graph slot
    float linv = 1.0f / l;
    float4 gb0 = *(const float4*)&gat_b[h0];
    float4 gb1 = *(const float4*)&gat_b[h0 + 4];
    float xr[8];
    xr[0] = bflo(xv.x); xr[1] = bfhi(xv.x); xr[2] = bflo(xv.y); xr[3] = bfhi(xv.y);
    xr[4] = bflo(xv.z); xr[5] = bfhi(xv.z); xr[6] = bflo(xv.w); xr[7] = bfhi(xv.w);
    float gbv[8] = {gb0.x, gb0.y, gb0.z, gb0.w, gb1.x, gb1.y, gb1.z, gb1.w};
    float rv[8];
    float s1 = 0.f, s2v = 0.f;
#pragma unroll
    for (int j = 0; j < 8; ++j) {
        rv[j] = xr[j] + ac[j] * linv + gbv[j];
        s1 += rv[j];
        s2v += rv[j] * rv[j];
    }
#pragma unroll
    for (int mm = 1; mm < 16; mm <<= 1) {
        s1 += __shfl_xor(s1, mm);
        s2v += __shfl_xor(s2v, mm);
    }
    float mean = s1 * (1.f / 128.f);
    float var = s2v * (1.f / 128.f) - mean * mean;
    float rs = rsqrtf(var + LN_EPS);
    float4 g20 = *(const float4*)&ln2_g[h0];
    float4 g21 = *(const float4*)&ln2_g[h0 + 4];
    float4 b20 = *(const float4*)&ln2_b[h0];
    float4 b21 = *(const float4*)&ln2_b[h0 + 4];
    f32x4 o0, o1;
    o0.x = (rv[0] - mean) * rs * g20.x + b20.x;
    o0.y = (rv[1] - mean) * rs * g20.y + b20.y;
    o0.z = (rv[2] - mean) * rs * g20.z + b20.z;
    o0.w = (rv[3] - mean) * rs * g20.w + b20.w;
    o1.x = (rv[4] - mean) * rs * g21.x + b21.x;
    o1.y = (rv[5] - mean) * rs * g21.y + b21.y;
    o1.z = (rv[6] - mean) * rs * g21.z + b21.z;
    o1.w = (rv[7] - mean) * rs * g21.w + b21.w;
    __builtin_nontemporal_store(o0, (f32x4*)&out[ob]);
    __builtin_nontemporal_store(o1, (f32x4*)&out[ob + 4]);
}

extern "C" void kernel_launch(void* const* d_in, const int* in_sizes, int n_in,
                              void* d_out, int out_size, void* d_ws, size_t ws_size,
                              hipStream_t stream) {
    const float* x         = (const float*)d_in[0];
    const int*   ei        = (const int*)d_in[1];
    const float* edge_attr = (const float*)d_in[2];
    const float* conv_w    = (const float*)d_in[3];
    const float* conv_b    = (const float*)d_in[4];
    const float* ln1_g     = (const float*)d_in[5];
    const float* ln1_b     = (const float*)d_in[6];
    const float* Wl        = (const float*)d_in[7];
    const float* Wr        = (const float*)d_in[8];
    const float* We        = (const float*)d_in[9];
    const float* att       = (const float*)d_in[10];
    const float* gat_b     = (const float*)d_in[11];
    const float* ln2_g     = (const float*)d_in[12];
    const float* ln2_b     = (const float*)d_in[13];
    float* out = (float*)d_out;

    const int* src = ei;
    const int* dst = ei + E_EDGES;

    // workspace layout (all bf16 activations)
    u16* x1b    = (u16*)d_ws;                   // 4,096,000 bf16 [n][t][h]
    u16* glb    = x1b + 4096000;                // 4,096,000 bf16 [g][n][h]
    u16* grb    = glb + 4096000;                // 4,096,000 bf16 [g][n][h]
    u16* eeb    = grb + 4096000;                // 2,176,000 bf16
    int* cnt    = (int*)(eeb + 2176000);        // 1000
    int* csr    = cnt + 1000;                   // 128,000 (fixed-cap CSR [n][128])
    short* wc   = (short*)(csr + 128000);       // 49152 shorts (16B aligned)
    short* wg   = wc + 49152;                   // 32768 shorts

    hipMemsetAsync(cnt, 0, N_NODES * sizeof(int), stream);
    k_prep<<<96, 1024, 0, stream>>>(conv_w, Wl, Wr, dst, wc, wg, cnt, csr);
    k_fuse<<<10000, 256, 0, stream>>>(x, wc, wg, conv_b, ln1_g, ln1_b, edge_attr, We,
                                      csr, cnt, x1b, glb, grb, eeb);
    k_gat<<<4 * N_NODES, 128, 0, stream>>>(glb, grb, eeb, src, csr, cnt,
                                           att, gat_b, x1b, ln2_g, ln2_b, out);
}